// Round 4
// baseline (581.479 us; speedup 1.0000x reference)
//
#include <hip/hip_runtime.h>

// Problem constants (complete bipartite proxy<->sample + self-loops)
#define PP 100    // proxies
#define NS 1024   // samples
#define NN 1124   // total nodes
#define DD 512    // feature dim
#define CC 100    // fc out dim
#define NTHR 256
#define GRID 512  // fused kernel grid (2 blocks/CU)

typedef _Float16 f16;
typedef _Float16 f16x8 __attribute__((ext_vector_type(8)));
typedef float    f32x4 __attribute__((ext_vector_type(4)));

__device__ __forceinline__ float lk(float v) { return v > 0.f ? v : 0.2f * v; }
__device__ __forceinline__ f16 hif(float v) { return (f16)v; }
__device__ __forceinline__ f16 lof(float v) { return (f16)(v - (float)((f16)v)); }

// All pointers bundled so the fused kernel takes one kernarg struct.
struct FA {
  const float *x, *prox, *W1, *as1, *ad1, *b1, *W2, *as2, *ad2, *b2, *fcw, *fcb;
  float *out, *h1, *ls1, *ld1, *ls2, *ld2, *v1s, *v1d, *v2s, *v2d;
  float *esS1, *izS1, *esS2, *izS2, *esP, *izP, *h2s;
  f16 *M1h, *M1l, *M2h, *M2l, *Es1h, *Es1l, *Es2h, *Es2l, *Eph, *Epl;
  f16 *xth, *xtl, *pth, *ptl, *W1th, *W1tl, *W2th, *W2tl, *fwth, *fwtl;
  f16 *h2h, *h2l, *h1pth, *h1ptl;
  unsigned *cnt, *gen;     // grid-barrier state (memset to 0 before launch)
};

// ---- hand-rolled grid barrier (sense via generation counter) -------------
// Device-scope atomics execute at the MALL (coherent point), so the relaxed
// spin observes remote updates despite non-coherent per-XCD L2s.
// __threadfence() provides the L2 writeback (release) / invalidate (acquire).
__device__ __forceinline__ void gbar(unsigned* cnt, unsigned* gen, unsigned nb)
{
  __syncthreads();
  if (threadIdx.x == 0) {
    unsigned g = __hip_atomic_load(gen, __ATOMIC_RELAXED, __HIP_MEMORY_SCOPE_AGENT);
    __threadfence();                                   // release prior writes
    unsigned a = __hip_atomic_fetch_add(cnt, 1u, __ATOMIC_RELAXED,
                                        __HIP_MEMORY_SCOPE_AGENT);
    if (a == nb - 1u) {
      __hip_atomic_store(cnt, 0u, __ATOMIC_RELAXED, __HIP_MEMORY_SCOPE_AGENT);
      __hip_atomic_store(gen, g + 1u, __ATOMIC_RELEASE, __HIP_MEMORY_SCOPE_AGENT);
    } else {
      while (__hip_atomic_load(gen, __ATOMIC_RELAXED,
                               __HIP_MEMORY_SCOPE_AGENT) == g)
        __builtin_amdgcn_s_sleep(1);
    }
    __threadfence();                                   // acquire remote writes
  }
  __syncthreads();
}

// =================== MFMA split-f16 GEMM core =============================
// acc[2][2] += A[row0.., K] @ B  where A given as (Ah,Al) row-major [*,K],
// B given TRANSPOSED as (Bth,Btl) row-major [*,K] (row = output col).
// Block tile 64x64, 4 waves of 32x32 (2x2 frags 16x16), BK=32, K % 32 == 0.
// C = Ah*Bh + Al*Bh + Ah*Bl  (split-f16, fp32 accumulate; al*bl dropped).
// lds: f16[4*64*40] (rows padded to 40 halves -> 16B-aligned, spread banks).
__device__ __forceinline__ void mgemm_core(
    const f16* __restrict__ Ah, const f16* __restrict__ Al,
    const f16* __restrict__ Bth, const f16* __restrict__ Btl,
    int K, int row0, int col0, f16* __restrict__ lds, f32x4 acc[2][2])
{
  const int t = threadIdx.x;
  const int lane = t & 63, w = t >> 6;
  const int wr = w >> 1, wc = w & 1;
  f16* Ash = lds;
  f16* Asl = lds + 2560;
  f16* Bsh = lds + 5120;
  f16* Bsl = lds + 7680;
  const int srow = t >> 2, su = t & 3;                 // staging: row, 8-half unit
  const size_t aoff = (size_t)(row0 + srow) * K + su * 8;
  const size_t boff = (size_t)(col0 + srow) * K + su * 8;
  const int lw = srow * 40 + su * 8;
  f32x4 pa0 = *(const f32x4*)(Ah + aoff);
  f32x4 pa1 = *(const f32x4*)(Al + aoff);
  f32x4 pb0 = *(const f32x4*)(Bth + boff);
  f32x4 pb1 = *(const f32x4*)(Btl + boff);
  const int fra = wr * 32 + (lane & 15);               // A frag row (local)
  const int frb = wc * 32 + (lane & 15);               // B frag col (local)
  const int fu  = (lane >> 4) * 8;                     // k offset within BK
  for (int kt = 32; kt <= K; kt += 32) {
    *(f32x4*)(Ash + lw) = pa0;
    *(f32x4*)(Asl + lw) = pa1;
    *(f32x4*)(Bsh + lw) = pb0;
    *(f32x4*)(Bsl + lw) = pb1;
    __syncthreads();
    if (kt < K) {                                      // prefetch next tile
      pa0 = *(const f32x4*)(Ah + aoff + kt);
      pa1 = *(const f32x4*)(Al + aoff + kt);
      pb0 = *(const f32x4*)(Bth + boff + kt);
      pb1 = *(const f32x4*)(Btl + boff + kt);
    }
    f16x8 ah[2], al[2], bh[2], bl[2];
#pragma unroll
    for (int m = 0; m < 2; ++m) {
      ah[m] = *(const f16x8*)(Ash + (fra + m * 16) * 40 + fu);
      al[m] = *(const f16x8*)(Asl + (fra + m * 16) * 40 + fu);
    }
#pragma unroll
    for (int n = 0; n < 2; ++n) {
      bh[n] = *(const f16x8*)(Bsh + (frb + n * 16) * 40 + fu);
      bl[n] = *(const f16x8*)(Bsl + (frb + n * 16) * 40 + fu);
    }
#pragma unroll
    for (int m = 0; m < 2; ++m)
#pragma unroll
      for (int n = 0; n < 2; ++n) {
        acc[m][n] = __builtin_amdgcn_mfma_f32_16x16x32_f16(ah[m], bh[n], acc[m][n], 0, 0, 0);
        acc[m][n] = __builtin_amdgcn_mfma_f32_16x16x32_f16(al[m], bh[n], acc[m][n], 0, 0, 0);
        acc[m][n] = __builtin_amdgcn_mfma_f32_16x16x32_f16(ah[m], bl[n], acc[m][n], 0, 0, 0);
      }
    __syncthreads();
  }
}

// C/D frag mapping (HW-verified): col = lane&15, row = (lane>>4)*4 + q.

// ======== 64x64 transpose+split tile (fp32 in -> f16 hi/lo transposed) =====
__device__ __forceinline__ void cvt_tile(
    const float* __restrict__ in, int R, int Cin,
    f16* __restrict__ oh, f16* __restrict__ ol, int ldo,
    int ti, int tj, f16 (*th)[72], f16 (*tl)[72])
{
  const int t = threadIdx.x;
#pragma unroll
  for (int p = 0; p < 4; ++p) {
    const int f = t + p * 256;
    const int i = f >> 4, j4 = (f & 15) * 4;
    const int gi = ti * 64 + i, gj = tj * 64 + j4;
    float4 v = make_float4(0.f, 0.f, 0.f, 0.f);
    if (gi < R && gj + 3 < Cin) v = *(const float4*)(in + (size_t)gi * Cin + gj);
    th[i][j4 + 0] = hif(v.x); tl[i][j4 + 0] = lof(v.x);
    th[i][j4 + 1] = hif(v.y); tl[i][j4 + 1] = lof(v.y);
    th[i][j4 + 2] = hif(v.z); tl[i][j4 + 2] = lof(v.z);
    th[i][j4 + 3] = hif(v.w); tl[i][j4 + 3] = lof(v.w);
  }
  __syncthreads();
#pragma unroll
  for (int p = 0; p < 2; ++p) {
    const int f = t + p * 256;
    const int j = f >> 3, i8 = (f & 7) * 8;
    f16x8 vh, vl;
#pragma unroll
    for (int e = 0; e < 8; ++e) { vh[e] = th[i8 + e][j]; vl[e] = tl[i8 + e][j]; }
    const size_t o = (size_t)(tj * 64 + j) * ldo + ti * 64 + i8;
    *(f16x8*)(oh + o) = vh;
    *(f16x8*)(ol + o) = vl;
  }
}

// ===== phase bodies (shared by fused kernel and fallback wrappers) =========

// prep: u in [0,544). transposes/splits + weight-side matvecs.
__device__ void dv_prep(int u, const FA& a, f16 (*th)[72], f16 (*tl)[72])
{
  if (u < 64) {
    cvt_tile(a.W1, 512, 512, a.W1th, a.W1tl, 512, u >> 3, u & 7, th, tl);
  } else if (u < 128) {
    cvt_tile(a.W2, 512, 512, a.W2th, a.W2tl, 512, (u - 64) >> 3, (u - 64) & 7, th, tl);
  } else if (u < 256) {
    cvt_tile(a.x, NS, 512, a.xth, a.xtl, NS, (u - 128) >> 3, (u - 128) & 7, th, tl);
  } else if (u < 272) {
    cvt_tile(a.prox, PP, 512, a.pth, a.ptl, 128, (u - 256) >> 3, (u - 256) & 7, th, tl);
  } else if (u < 288) {
    cvt_tile(a.fcw, 512, CC, a.fwth, a.fwtl, 512, (u - 272) >> 1, (u - 272) & 1, th, tl);
  } else {
    const int wid  = (u - 288) * 4 + (threadIdx.x >> 6);   // 0..1023
    const int lane = threadIdx.x & 63;
    const int r = wid & 511;
    const bool l1 = (wid < 512);
    const float* W = l1 ? a.W1 : a.W2;
    const float4* a4 = (const float4*)(l1 ? a.as1 : a.as2);
    const float4* b4 = (const float4*)(l1 ? a.ad1 : a.ad2);
    const float4* w4 = (const float4*)(W + (size_t)r * DD);
    float4 w0 = w4[lane], w1 = w4[lane + 64];
    float4 a0 = a4[lane], a1 = a4[lane + 64];
    float4 b0 = b4[lane], b1 = b4[lane + 64];
    float s1 = w0.x * a0.x + w0.y * a0.y + w0.z * a0.z + w0.w * a0.w
             + w1.x * a1.x + w1.y * a1.y + w1.z * a1.z + w1.w * a1.w;
    float s2 = w0.x * b0.x + w0.y * b0.y + w0.z * b0.z + w0.w * b0.w
             + w1.x * b1.x + w1.y * b1.y + w1.z * b1.z + w1.w * b1.w;
#pragma unroll
    for (int off = 32; off > 0; off >>= 1) {
      s1 += __shfl_down(s1, off);
      s2 += __shfl_down(s2, off);
    }
    if (lane == 0) {
      (l1 ? a.v1s : a.v2s)[r] = s1;
      (l1 ? a.v1d : a.v2d)[r] = s2;
    }
  }
}

// logits: ls[r]=row_r.vs, ld[r]=row_r.vd (one wave per row; u in [0,281))
__device__ void dv_lvec(int u, const float* A0, const float* A1, int split,
                        const float* vs, const float* vd, float* ls, float* ld)
{
  const int r    = u * 4 + (threadIdx.x >> 6);
  const int lane = threadIdx.x & 63;
  if (r >= NN) return;
  const float* row = (r < split) ? A0 + (size_t)r * DD : A1 + (size_t)(r - split) * DD;
  const float4* r4 = (const float4*)row;
  const float4* s4 = (const float4*)vs;
  const float4* d4 = (const float4*)vd;
  float4 v0 = r4[lane], v1 = r4[lane + 64];
  float4 a0 = s4[lane], a1 = s4[lane + 64];
  float4 b0 = d4[lane], b1 = d4[lane + 64];
  float s1 = v0.x * a0.x + v0.y * a0.y + v0.z * a0.z + v0.w * a0.w
           + v1.x * a1.x + v1.y * a1.y + v1.z * a1.z + v1.w * a1.w;
  float s2 = v0.x * b0.x + v0.y * b0.y + v0.z * b0.z + v0.w * b0.w
           + v1.x * b1.x + v1.y * b1.y + v1.z * b1.z + v1.w * b1.w;
#pragma unroll
  for (int off = 32; off > 0; off >>= 1) {
    s1 += __shfl_down(s1, off);
    s2 += __shfl_down(s2, off);
  }
  if (lane == 0) { ls[r] = s1; ld[r] = s2; }
}

// softmax weights -> split f16. u in [0,384): [0,256) sample quads,
// [256,384) proxy rows (i >= PP rows zero-fill the Ep k-pad).
__device__ void dv_alpha(int u, const float* ls, const float* ld,
                         f16* Esh, f16* Esl, float* esS, float* izS,
                         f16* Eph, f16* Epl, float* esP, float* izP, float* red)
{
  const int t = threadIdx.x;
  if (u < 256) {
    const int lane = t & 63;
    const int i = u * 4 + (t >> 6);              // sample dst
    const float ldi = ld[PP + i];
    float e0 = lk(ls[lane] + ldi);               // lane < 100 always
    float e1 = (lane < PP - 64) ? lk(ls[lane + 64] + ldi) : -1e30f;
    const float eself = lk(ls[PP + i] + ldi);
    float m = fmaxf(fmaxf(e0, e1), eself);
#pragma unroll
    for (int off = 1; off < 64; off <<= 1) m = fmaxf(m, __shfl_xor(m, off));
    float x0 = __expf(e0 - m);
    float x1 = (lane < PP - 64) ? __expf(e1 - m) : 0.f;
    float z = x0 + x1;
#pragma unroll
    for (int off = 1; off < 64; off <<= 1) z += __shfl_xor(z, off);
    Esh[(size_t)i * 128 + lane]      = hif(x0);
    Esl[(size_t)i * 128 + lane]      = lof(x0);
    Esh[(size_t)i * 128 + 64 + lane] = hif(x1);
    Esl[(size_t)i * 128 + 64 + lane] = lof(x1);
    if (lane == 0) {
      float xs = __expf(eself - m);
      esS[i] = xs;
      izS[i] = 1.f / (z + xs);
    }
  } else {
    const int i = u - 256;                       // proxy dst (or k-pad row)
    if (i >= PP) {                               // zero-fill pad rows 100..127
#pragma unroll
      for (int q = 0; q < 4; ++q) {
        Eph[(size_t)i * NS + t + q * 256] = (f16)0.f;
        Epl[(size_t)i * NS + t + q * 256] = (f16)0.f;
      }
      return;
    }
    const float ldi = ld[i];
    const float eself = lk(ls[i] + ldi);
    float e[4];
#pragma unroll
    for (int q = 0; q < 4; ++q) e[q] = lk(ls[PP + t + q * 256] + ldi);
    float m = fmaxf(fmaxf(fmaxf(e[0], e[1]), fmaxf(e[2], e[3])), eself);
#pragma unroll
    for (int off = 1; off < 64; off <<= 1) m = fmaxf(m, __shfl_xor(m, off));
    if ((t & 63) == 0) red[t >> 6] = m;
    __syncthreads();
    m = fmaxf(fmaxf(red[0], red[1]), fmaxf(red[2], red[3]));
    __syncthreads();
    float xq[4], z = 0.f;
#pragma unroll
    for (int q = 0; q < 4; ++q) { xq[q] = __expf(e[q] - m); z += xq[q]; }
#pragma unroll
    for (int off = 1; off < 64; off <<= 1) z += __shfl_xor(z, off);
    if ((t & 63) == 0) red[t >> 6] = z;
    __syncthreads();
#pragma unroll
    for (int q = 0; q < 4; ++q) {
      Eph[(size_t)i * NS + t + q * 256] = hif(xq[q]);
      Epl[(size_t)i * NS + t + q * 256] = lof(xq[q]);
    }
    if (t == 0) {
      float xs = __expf(eself - m);
      esP[i] = xs;
      izP[i] = 1.f / (red[0] + red[1] + red[2] + red[3] + xs);
    }
  }
}

// layer-1 aggregation: u in [0,144): [0,128) sample tiles, [128,144) proxy.
__device__ void dv_agg1(int u, const FA& a, f16* lds)
{
  f32x4 acc[2][2] = {};
  const int t = threadIdx.x, lane = t & 63, w = t >> 6, wr = w >> 1, wc = w & 1;
  if (u < 128) {
    // M1_samp[1024,512] = Es1[1024,128] @ prox(pad 128), epi self = x
    const int row0 = (u >> 3) * 64, col0 = (u & 7) * 64;
    mgemm_core(a.Es1h, a.Es1l, a.pth, a.ptl, 128, row0, col0, lds, acc);
#pragma unroll
    for (int m = 0; m < 2; ++m)
#pragma unroll
      for (int q = 0; q < 4; ++q) {
        const int r = row0 + wr * 32 + m * 16 + (lane >> 4) * 4 + q;
        const float e = a.esS1[r], z = a.izS1[r];
#pragma unroll
        for (int n = 0; n < 2; ++n) {
          const int c = col0 + wc * 32 + n * 16 + (lane & 15);
          const float v = (acc[m][n][q] + e * a.x[(size_t)r * DD + c]) * z;
          const size_t o = (size_t)(PP + r) * DD + c;
          a.M1h[o] = hif(v); a.M1l[o] = lof(v);
        }
      }
  } else {
    // M1_prox[100,512] = Ep[100(pad128),1024] @ x, epi self = prox
    const int b2 = u - 128;
    const int row0 = (b2 >> 3) * 64, col0 = (b2 & 7) * 64;
    mgemm_core(a.Eph, a.Epl, a.xth, a.xtl, NS, row0, col0, lds, acc);
#pragma unroll
    for (int m = 0; m < 2; ++m)
#pragma unroll
      for (int q = 0; q < 4; ++q) {
        const int r = row0 + wr * 32 + m * 16 + (lane >> 4) * 4 + q;
        if (r < PP) {
          const float e = a.esP[r], z = a.izP[r];
#pragma unroll
          for (int n = 0; n < 2; ++n) {
            const int c = col0 + wc * 32 + n * 16 + (lane & 15);
            const float v = (acc[m][n][q] + e * a.prox[(size_t)r * DD + c]) * z;
            const size_t o = (size_t)r * DD + c;
            a.M1h[o] = hif(v); a.M1l[o] = lof(v);
          }
        }
      }
  }
}

// h1 = relu(M1@W1 + b1); also emit split-transposed proxy rows. u in [0,144)
__device__ void dv_h1(int u, const FA& a, f16* lds)
{
  f32x4 acc[2][2] = {};
  const int t = threadIdx.x, lane = t & 63, w = t >> 6, wr = w >> 1, wc = w & 1;
  const int row0 = (u >> 3) * 64, col0 = (u & 7) * 64;
  mgemm_core(a.M1h, a.M1l, a.W1th, a.W1tl, DD, row0, col0, lds, acc);
#pragma unroll
  for (int m = 0; m < 2; ++m)
#pragma unroll
    for (int q = 0; q < 4; ++q) {
      const int r = row0 + wr * 32 + m * 16 + (lane >> 4) * 4 + q;
      if (r >= NN) continue;
#pragma unroll
      for (int n = 0; n < 2; ++n) {
        const int c = col0 + wc * 32 + n * 16 + (lane & 15);
        const float v = fmaxf(acc[m][n][q] + a.b1[c], 0.f);
        a.h1[(size_t)r * DD + c] = v;
        if (r < 128) {                       // B of agg2: zero-fill k-pad rows
          const size_t o = (size_t)c * 128 + r;
          f16 hh = (f16)0.f, ll = (f16)0.f;
          if (r < PP) { hh = hif(v); ll = lof(v); }
          a.h1pth[o] = hh; a.h1ptl[o] = ll;
        }
      }
    }
}

// layer-2 aggregation (sample dsts only). u in [0,128)
__device__ void dv_agg2(int u, const FA& a, f16* lds)
{
  f32x4 acc[2][2] = {};
  const int t = threadIdx.x, lane = t & 63, w = t >> 6, wr = w >> 1, wc = w & 1;
  const int row0 = (u >> 3) * 64, col0 = (u & 7) * 64;
  mgemm_core(a.Es2h, a.Es2l, a.h1pth, a.h1ptl, 128, row0, col0, lds, acc);
#pragma unroll
  for (int m = 0; m < 2; ++m)
#pragma unroll
    for (int q = 0; q < 4; ++q) {
      const int r = row0 + wr * 32 + m * 16 + (lane >> 4) * 4 + q;
      const float e = a.esS2[r], z = a.izS2[r];
#pragma unroll
      for (int n = 0; n < 2; ++n) {
        const int c = col0 + wc * 32 + n * 16 + (lane & 15);
        const float v = (acc[m][n][q] + e * a.h1[(size_t)(PP + r) * DD + c]) * z;
        const size_t o = (size_t)r * DD + c;
        a.M2h[o] = hif(v); a.M2l[o] = lof(v);
      }
    }
}

// h2 = relu(M2@W2 + b2) -> d_out (fp32) + split for fc. u in [0,128)
__device__ void dv_h2(int u, const FA& a, f16* lds)
{
  f32x4 acc[2][2] = {};
  const int t = threadIdx.x, lane = t & 63, w = t >> 6, wr = w >> 1, wc = w & 1;
  const int row0 = (u >> 3) * 64, col0 = (u & 7) * 64;
  mgemm_core(a.M2h, a.M2l, a.W2th, a.W2tl, DD, row0, col0, lds, acc);
#pragma unroll
  for (int m = 0; m < 2; ++m)
#pragma unroll
    for (int q = 0; q < 4; ++q) {
      const int r = row0 + wr * 32 + m * 16 + (lane >> 4) * 4 + q;
#pragma unroll
      for (int n = 0; n < 2; ++n) {
        const int c = col0 + wc * 32 + n * 16 + (lane & 15);
        const float v = fmaxf(acc[m][n][q] + a.b2[c], 0.f);
        const size_t o = (size_t)r * DD + c;
        a.h2s[o] = v;
        a.h2h[o] = hif(v); a.h2l[o] = lof(v);
      }
    }
}

// preds = h2 @ fcw + fcb. u in [0,32)
__device__ void dv_fc(int u, const FA& a, f16* lds)
{
  f32x4 acc[2][2] = {};
  const int t = threadIdx.x, lane = t & 63, w = t >> 6, wr = w >> 1, wc = w & 1;
  const int row0 = (u >> 1) * 64, col0 = (u & 1) * 64;
  mgemm_core(a.h2h, a.h2l, a.fwth, a.fwtl, DD, row0, col0, lds, acc);
#pragma unroll
  for (int m = 0; m < 2; ++m)
#pragma unroll
    for (int q = 0; q < 4; ++q) {
      const int r = row0 + wr * 32 + m * 16 + (lane >> 4) * 4 + q;
#pragma unroll
      for (int n = 0; n < 2; ++n) {
        const int c = col0 + wc * 32 + n * 16 + (lane & 15);
        if (c < CC) a.out[(size_t)r * CC + c] = acc[m][n][q] + a.fcb[c];
      }
    }
}

// =================== fused kernel (custom grid barrier) ====================
__global__ __launch_bounds__(NTHR) void fused_k(FA a)
{
  __shared__ __align__(16) f16 lds[10240];
  __shared__ float red[4];
  f16 (*th)[72] = (f16(*)[72])lds;
  f16 (*tl)[72] = (f16(*)[72])(lds + 4608);
  const unsigned nb = gridDim.x;

  for (int u = blockIdx.x; u < 544; u += gridDim.x) {   // P0 prep
    dv_prep(u, a, th, tl);
    __syncthreads();
  }
  gbar(a.cnt, a.gen, nb);
  for (int u = blockIdx.x; u < 281; u += gridDim.x)     // P1 lvec1
    dv_lvec(u, a.prox, a.x, PP, a.v1s, a.v1d, a.ls1, a.ld1);
  gbar(a.cnt, a.gen, nb);
  for (int u = blockIdx.x; u < 384; u += gridDim.x) {   // P2 alpha1
    dv_alpha(u, a.ls1, a.ld1, a.Es1h, a.Es1l, a.esS1, a.izS1,
             a.Eph, a.Epl, a.esP, a.izP, red);
    __syncthreads();
  }
  gbar(a.cnt, a.gen, nb);
  for (int u = blockIdx.x; u < 144; u += gridDim.x)     // P3 agg1
    dv_agg1(u, a, lds);
  gbar(a.cnt, a.gen, nb);
  for (int u = blockIdx.x; u < 144; u += gridDim.x)     // P4 h1
    dv_h1(u, a, lds);
  gbar(a.cnt, a.gen, nb);
  for (int u = blockIdx.x; u < 281; u += gridDim.x)     // P5 lvec2
    dv_lvec(u, a.h1, a.h1, NN, a.v2s, a.v2d, a.ls2, a.ld2);
  gbar(a.cnt, a.gen, nb);
  for (int u = blockIdx.x; u < 256; u += gridDim.x) {   // P6 alpha2 (samples)
    dv_alpha(u, a.ls2, a.ld2, a.Es2h, a.Es2l, a.esS2, a.izS2,
             a.Eph, a.Epl, a.esP, a.izP, red);
    __syncthreads();
  }
  gbar(a.cnt, a.gen, nb);
  for (int u = blockIdx.x; u < 128; u += gridDim.x)     // P7 agg2
    dv_agg2(u, a, lds);
  gbar(a.cnt, a.gen, nb);
  for (int u = blockIdx.x; u < 128; u += gridDim.x)     // P8 h2
    dv_h2(u, a, lds);
  gbar(a.cnt, a.gen, nb);
  for (int u = blockIdx.x; u < 32; u += gridDim.x)      // P9 fc
    dv_fc(u, a, lds);
}

// =================== fallback (non-cooperative) wrappers ===================
__global__ __launch_bounds__(NTHR) void prep_k(FA a) {
  __shared__ f16 th[64][72];
  __shared__ f16 tl[64][72];
  dv_prep(blockIdx.x, a, th, tl);
}
__global__ __launch_bounds__(NTHR) void lvec_k(FA a, int layer) {
  if (layer == 1) dv_lvec(blockIdx.x, a.prox, a.x, PP, a.v1s, a.v1d, a.ls1, a.ld1);
  else            dv_lvec(blockIdx.x, a.h1, a.h1, NN, a.v2s, a.v2d, a.ls2, a.ld2);
}
__global__ __launch_bounds__(NTHR) void alpha_k(FA a, int layer) {
  __shared__ float red[4];
  if (layer == 1)
    dv_alpha(blockIdx.x, a.ls1, a.ld1, a.Es1h, a.Es1l, a.esS1, a.izS1,
             a.Eph, a.Epl, a.esP, a.izP, red);
  else
    dv_alpha(blockIdx.x, a.ls2, a.ld2, a.Es2h, a.Es2l, a.esS2, a.izS2,
             a.Eph, a.Epl, a.esP, a.izP, red);
}
__global__ __launch_bounds__(NTHR) void agg1_k(FA a) {
  __shared__ __align__(16) f16 lds[10240];
  dv_agg1(blockIdx.x, a, lds);
}
__global__ __launch_bounds__(NTHR) void h1_k(FA a) {
  __shared__ __align__(16) f16 lds[10240];
  dv_h1(blockIdx.x, a, lds);
}
__global__ __launch_bounds__(NTHR) void agg2_k(FA a) {
  __shared__ __align__(16) f16 lds[10240];
  dv_agg2(blockIdx.x, a, lds);
}
__global__ __launch_bounds__(NTHR) void h2_k(FA a) {
  __shared__ __align__(16) f16 lds[10240];
  dv_h2(blockIdx.x, a, lds);
}
__global__ __launch_bounds__(NTHR) void fc_k(FA a) {
  __shared__ __align__(16) f16 lds[10240];
  dv_fc(blockIdx.x, a, lds);
}

extern "C" void kernel_launch(void* const* d_in, const int* in_sizes, int n_in,
                              void* d_out, int out_size, void* d_ws, size_t ws_size,
                              hipStream_t stream)
{
  FA a;
  a.x    = (const float*)d_in[0];
  a.prox = (const float*)d_in[1];
  a.W1   = (const float*)d_in[2];
  a.as1  = (const float*)d_in[3];
  a.ad1  = (const float*)d_in[4];
  a.b1   = (const float*)d_in[5];
  a.W2   = (const float*)d_in[6];
  a.as2  = (const float*)d_in[7];
  a.ad2  = (const float*)d_in[8];
  a.b2   = (const float*)d_in[9];
  a.fcw  = (const float*)d_in[10];
  a.fcb  = (const float*)d_in[11];
  a.out  = (float*)d_out;

  // fp32 workspace
  float* F = (float*)d_ws;
  a.h1   = F; F += (size_t)NN * DD;
  a.ls1  = F; F += 1152;
  a.ld1  = F; F += 1152;
  a.ls2  = F; F += 1152;
  a.ld2  = F; F += 1152;
  a.v1s  = F; F += DD;
  a.v1d  = F; F += DD;
  a.v2s  = F; F += DD;
  a.v2d  = F; F += DD;
  a.esS1 = F; F += NS;
  a.izS1 = F; F += NS;
  a.esS2 = F; F += NS;
  a.izS2 = F; F += NS;
  a.esP  = F; F += 128;
  a.izP  = F; F += 128;
  // grid-barrier state (16 dwords; zeroed via memset node each iteration)
  unsigned* sync = (unsigned*)F; F += 16;
  a.cnt = sync;
  a.gen = sync + 1;
  // f16 split workspace (all bases 16B aligned; sizes multiples of 8 halves)
  f16* H = (f16*)F;
  a.M1h  = H; H += (size_t)1152 * DD;   // rows: 100 prox + 1024 samp + pad
  a.M1l  = H; H += (size_t)1152 * DD;
  a.M2h  = H; H += (size_t)NS * DD;
  a.M2l  = H; H += (size_t)NS * DD;
  a.Es1h = H; H += (size_t)NS * 128;
  a.Es1l = H; H += (size_t)NS * 128;
  a.Es2h = H; H += (size_t)NS * 128;
  a.Es2l = H; H += (size_t)NS * 128;
  a.Eph  = H; H += (size_t)128 * NS;
  a.Epl  = H; H += (size_t)128 * NS;
  a.xth  = H; H += (size_t)DD * NS;     // x^T  [512][1024]
  a.xtl  = H; H += (size_t)DD * NS;
  a.pth  = H; H += (size_t)DD * 128;    // prox^T [512][128] (k-pad zeroed)
  a.ptl  = H; H += (size_t)DD * 128;
  a.W1th = H; H += (size_t)DD * DD;     // W1^T [512][512]
  a.W1tl = H; H += (size_t)DD * DD;
  a.W2th = H; H += (size_t)DD * DD;
  a.W2tl = H; H += (size_t)DD * DD;
  a.fwth = H; H += (size_t)128 * DD;    // fcw^T [128][512] (k-pad zeroed)
  a.fwtl = H; H += (size_t)128 * DD;
  a.h2h  = H; H += (size_t)NS * DD;
  a.h2l  = H; H += (size_t)NS * DD;
  a.h1pth = H; H += (size_t)DD * 128;   // h1 proxy rows ^T [512][128]
  a.h1ptl = H; H += (size_t)DD * 128;
  a.h2s  = a.out + (size_t)NS * CC;     // layer-2 sample out in d_out

  // zero the barrier state (workspace is poisoned between iterations)
  hipMemsetAsync((void*)sync, 0, 64, stream);

  dim3 blk(NTHR);
  void* params[] = { (void*)&a };
  hipError_t err = hipLaunchCooperativeKernel(
      (const void*)fused_k, dim3(GRID), blk, params, 0, stream);
  if (err != hipSuccess) {
    // fallback: original 10-launch sequence (same math)
    prep_k <<<dim3(544), blk, 0, stream>>>(a);
    lvec_k <<<dim3(281), blk, 0, stream>>>(a, 1);
    alpha_k<<<dim3(384), blk, 0, stream>>>(a, 1);
    agg1_k <<<dim3(144), blk, 0, stream>>>(a);
    h1_k   <<<dim3(144), blk, 0, stream>>>(a);
    lvec_k <<<dim3(281), blk, 0, stream>>>(a, 2);
    alpha_k<<<dim3(256), blk, 0, stream>>>(a, 2);
    agg2_k <<<dim3(128), blk, 0, stream>>>(a);
    h2_k   <<<dim3(128), blk, 0, stream>>>(a);
    fc_k   <<<dim3(32),  blk, 0, stream>>>(a);
  }
}

// Round 5
// 305.048 us; speedup vs baseline: 1.9062x; 1.9062x over previous
//
#include <hip/hip_runtime.h>

// Problem constants (complete bipartite proxy<->sample + self-loops)
#define PP 100    // proxies
#define NS 1024   // samples
#define NN 1124   // total nodes
#define DD 512    // feature dim
#define CC 100    // fc out dim
#define NTHR 256
#define GRID 256  // fused kernel grid (1 block/CU)
#define NGRP 8    // barrier tree fan-in groups
#define GRPSZ (GRID / NGRP)   // 32 blocks per group

typedef _Float16 f16;
typedef _Float16 f16x8 __attribute__((ext_vector_type(8)));
typedef float    f32x4 __attribute__((ext_vector_type(4)));

__device__ __forceinline__ float lk(float v) { return v > 0.f ? v : 0.2f * v; }
__device__ __forceinline__ f16 hif(float v) { return (f16)v; }
__device__ __forceinline__ f16 lof(float v) { return (f16)(v - (float)((f16)v)); }

// All pointers bundled so the fused kernel takes one kernarg struct.
struct FA {
  const float *x, *prox, *W1, *as1, *ad1, *b1, *W2, *as2, *ad2, *b2, *fcw, *fcb;
  float *out, *h1, *ls1, *ld1, *ls2, *ld2, *v1s, *v1d, *v2s, *v2d;
  float *esS1, *izS1, *esS2, *izS2, *esP, *izP, *h2s;
  f16 *M1h, *M1l, *M2h, *M2l, *Es1h, *Es1l, *Es2h, *Es2l, *Eph, *Epl;
  f16 *xth, *xtl, *pth, *ptl, *W1th, *W1tl, *W2th, *W2tl, *fwth, *fwtl;
  f16 *h2h, *h2l, *h1pth, *h1ptl;
  unsigned *bar;           // grid-barrier state (memset to 0 before launch)
};

// ---- two-level tree grid barrier (contention-minimized) -------------------
// State layout (dword indices; 128B line spacing between hot words):
//   grpCnt[g]  = bar[g*32]        g in [0,8)
//   rootCnt    = bar[256]
//   rootGen    = bar[288]
//   grpGen[g]  = bar[320 + g*32]
// Generation-counted: each block passes its local barrier index (1,2,3,...).
// Release/acquire via explicit __threadfence(); adds/loads relaxed agent-scope.
__device__ __forceinline__ void gbar(unsigned* bar, unsigned mygen)
{
  __syncthreads();
  if (threadIdx.x == 0) {
    const unsigned gid = blockIdx.x / GRPSZ;
    unsigned* grpCnt  = bar + gid * 32;
    unsigned* rootCnt = bar + 256;
    unsigned* rootGen = bar + 288;
    unsigned* grpGen  = bar + 320 + gid * 32;
    __threadfence();                                   // release prior writes
    unsigned a = __hip_atomic_fetch_add(grpCnt, 1u, __ATOMIC_RELAXED,
                                        __HIP_MEMORY_SCOPE_AGENT);
    if (a == GRPSZ - 1u) {                             // last in group
      __hip_atomic_store(grpCnt, 0u, __ATOMIC_RELAXED, __HIP_MEMORY_SCOPE_AGENT);
      unsigned r = __hip_atomic_fetch_add(rootCnt, 1u, __ATOMIC_RELAXED,
                                          __HIP_MEMORY_SCOPE_AGENT);
      if (r == NGRP - 1u) {                            // last group: release all
        __hip_atomic_store(rootCnt, 0u, __ATOMIC_RELAXED, __HIP_MEMORY_SCOPE_AGENT);
        __hip_atomic_store(rootGen, mygen, __ATOMIC_RELEASE, __HIP_MEMORY_SCOPE_AGENT);
      } else {
        while (__hip_atomic_load(rootGen, __ATOMIC_RELAXED,
                                 __HIP_MEMORY_SCOPE_AGENT) != mygen)
          __builtin_amdgcn_s_sleep(4);
      }
      __hip_atomic_store(grpGen, mygen, __ATOMIC_RELEASE, __HIP_MEMORY_SCOPE_AGENT);
    } else {
      while (__hip_atomic_load(grpGen, __ATOMIC_RELAXED,
                               __HIP_MEMORY_SCOPE_AGENT) != mygen)
        __builtin_amdgcn_s_sleep(4);
    }
    __threadfence();                                   // acquire remote writes
  }
  __syncthreads();
}

// =================== MFMA split-f16 GEMM core =============================
// acc[2][2] += A[row0.., K] @ B  where A given as (Ah,Al) row-major [*,K],
// B given TRANSPOSED as (Bth,Btl) row-major [*,K] (row = output col).
// Block tile 64x64, 4 waves of 32x32 (2x2 frags 16x16), BK=32, K % 32 == 0.
// C = Ah*Bh + Al*Bh + Ah*Bl  (split-f16, fp32 accumulate; al*bl dropped).
// lds: f16[4*64*40] (rows padded to 40 halves -> 16B-aligned, spread banks).
__device__ __forceinline__ void mgemm_core(
    const f16* __restrict__ Ah, const f16* __restrict__ Al,
    const f16* __restrict__ Bth, const f16* __restrict__ Btl,
    int K, int row0, int col0, f16* __restrict__ lds, f32x4 acc[2][2])
{
  const int t = threadIdx.x;
  const int lane = t & 63, w = t >> 6;
  const int wr = w >> 1, wc = w & 1;
  f16* Ash = lds;
  f16* Asl = lds + 2560;
  f16* Bsh = lds + 5120;
  f16* Bsl = lds + 7680;
  const int srow = t >> 2, su = t & 3;                 // staging: row, 8-half unit
  const size_t aoff = (size_t)(row0 + srow) * K + su * 8;
  const size_t boff = (size_t)(col0 + srow) * K + su * 8;
  const int lw = srow * 40 + su * 8;
  f32x4 pa0 = *(const f32x4*)(Ah + aoff);
  f32x4 pa1 = *(const f32x4*)(Al + aoff);
  f32x4 pb0 = *(const f32x4*)(Bth + boff);
  f32x4 pb1 = *(const f32x4*)(Btl + boff);
  const int fra = wr * 32 + (lane & 15);               // A frag row (local)
  const int frb = wc * 32 + (lane & 15);               // B frag col (local)
  const int fu  = (lane >> 4) * 8;                     // k offset within BK
  for (int kt = 32; kt <= K; kt += 32) {
    *(f32x4*)(Ash + lw) = pa0;
    *(f32x4*)(Asl + lw) = pa1;
    *(f32x4*)(Bsh + lw) = pb0;
    *(f32x4*)(Bsl + lw) = pb1;
    __syncthreads();
    if (kt < K) {                                      // prefetch next tile
      pa0 = *(const f32x4*)(Ah + aoff + kt);
      pa1 = *(const f32x4*)(Al + aoff + kt);
      pb0 = *(const f32x4*)(Bth + boff + kt);
      pb1 = *(const f32x4*)(Btl + boff + kt);
    }
    f16x8 ah[2], al[2], bh[2], bl[2];
#pragma unroll
    for (int m = 0; m < 2; ++m) {
      ah[m] = *(const f16x8*)(Ash + (fra + m * 16) * 40 + fu);
      al[m] = *(const f16x8*)(Asl + (fra + m * 16) * 40 + fu);
    }
#pragma unroll
    for (int n = 0; n < 2; ++n) {
      bh[n] = *(const f16x8*)(Bsh + (frb + n * 16) * 40 + fu);
      bl[n] = *(const f16x8*)(Bsl + (frb + n * 16) * 40 + fu);
    }
#pragma unroll
    for (int m = 0; m < 2; ++m)
#pragma unroll
      for (int n = 0; n < 2; ++n) {
        acc[m][n] = __builtin_amdgcn_mfma_f32_16x16x32_f16(ah[m], bh[n], acc[m][n], 0, 0, 0);
        acc[m][n] = __builtin_amdgcn_mfma_f32_16x16x32_f16(al[m], bh[n], acc[m][n], 0, 0, 0);
        acc[m][n] = __builtin_amdgcn_mfma_f32_16x16x32_f16(ah[m], bl[n], acc[m][n], 0, 0, 0);
      }
    __syncthreads();
  }
}

// C/D frag mapping (HW-verified): col = lane&15, row = (lane>>4)*4 + q.

// ======== 64x64 transpose+split tile (fp32 in -> f16 hi/lo transposed) =====
__device__ __forceinline__ void cvt_tile(
    const float* __restrict__ in, int R, int Cin,
    f16* __restrict__ oh, f16* __restrict__ ol, int ldo,
    int ti, int tj, f16 (*th)[72], f16 (*tl)[72])
{
  const int t = threadIdx.x;
#pragma unroll
  for (int p = 0; p < 4; ++p) {
    const int f = t + p * 256;
    const int i = f >> 4, j4 = (f & 15) * 4;
    const int gi = ti * 64 + i, gj = tj * 64 + j4;
    float4 v = make_float4(0.f, 0.f, 0.f, 0.f);
    if (gi < R && gj + 3 < Cin) v = *(const float4*)(in + (size_t)gi * Cin + gj);
    th[i][j4 + 0] = hif(v.x); tl[i][j4 + 0] = lof(v.x);
    th[i][j4 + 1] = hif(v.y); tl[i][j4 + 1] = lof(v.y);
    th[i][j4 + 2] = hif(v.z); tl[i][j4 + 2] = lof(v.z);
    th[i][j4 + 3] = hif(v.w); tl[i][j4 + 3] = lof(v.w);
  }
  __syncthreads();
#pragma unroll
  for (int p = 0; p < 2; ++p) {
    const int f = t + p * 256;
    const int j = f >> 3, i8 = (f & 7) * 8;
    f16x8 vh, vl;
#pragma unroll
    for (int e = 0; e < 8; ++e) { vh[e] = th[i8 + e][j]; vl[e] = tl[i8 + e][j]; }
    const size_t o = (size_t)(tj * 64 + j) * ldo + ti * 64 + i8;
    *(f16x8*)(oh + o) = vh;
    *(f16x8*)(ol + o) = vl;
  }
}

// ===== phase bodies (shared by fused kernel and fallback wrappers) =========

// prep: u in [0,544). transposes/splits + weight-side matvecs.
__device__ void dv_prep(int u, const FA& a, f16 (*th)[72], f16 (*tl)[72])
{
  if (u < 64) {
    cvt_tile(a.W1, 512, 512, a.W1th, a.W1tl, 512, u >> 3, u & 7, th, tl);
  } else if (u < 128) {
    cvt_tile(a.W2, 512, 512, a.W2th, a.W2tl, 512, (u - 64) >> 3, (u - 64) & 7, th, tl);
  } else if (u < 256) {
    cvt_tile(a.x, NS, 512, a.xth, a.xtl, NS, (u - 128) >> 3, (u - 128) & 7, th, tl);
  } else if (u < 272) {
    cvt_tile(a.prox, PP, 512, a.pth, a.ptl, 128, (u - 256) >> 3, (u - 256) & 7, th, tl);
  } else if (u < 288) {
    cvt_tile(a.fcw, 512, CC, a.fwth, a.fwtl, 512, (u - 272) >> 1, (u - 272) & 1, th, tl);
  } else {
    const int wid  = (u - 288) * 4 + (threadIdx.x >> 6);   // 0..1023
    const int lane = threadIdx.x & 63;
    const int r = wid & 511;
    const bool l1 = (wid < 512);
    const float* W = l1 ? a.W1 : a.W2;
    const float4* a4 = (const float4*)(l1 ? a.as1 : a.as2);
    const float4* b4 = (const float4*)(l1 ? a.ad1 : a.ad2);
    const float4* w4 = (const float4*)(W + (size_t)r * DD);
    float4 w0 = w4[lane], w1 = w4[lane + 64];
    float4 a0 = a4[lane], a1 = a4[lane + 64];
    float4 b0 = b4[lane], b1 = b4[lane + 64];
    float s1 = w0.x * a0.x + w0.y * a0.y + w0.z * a0.z + w0.w * a0.w
             + w1.x * a1.x + w1.y * a1.y + w1.z * a1.z + w1.w * a1.w;
    float s2 = w0.x * b0.x + w0.y * b0.y + w0.z * b0.z + w0.w * b0.w
             + w1.x * b1.x + w1.y * b1.y + w1.z * b1.z + w1.w * b1.w;
#pragma unroll
    for (int off = 32; off > 0; off >>= 1) {
      s1 += __shfl_down(s1, off);
      s2 += __shfl_down(s2, off);
    }
    if (lane == 0) {
      (l1 ? a.v1s : a.v2s)[r] = s1;
      (l1 ? a.v1d : a.v2d)[r] = s2;
    }
  }
}

// logits: ls[r]=row_r.vs, ld[r]=row_r.vd (one wave per row; u in [0,281))
__device__ void dv_lvec(int u, const float* A0, const float* A1, int split,
                        const float* vs, const float* vd, float* ls, float* ld)
{
  const int r    = u * 4 + (threadIdx.x >> 6);
  const int lane = threadIdx.x & 63;
  if (r >= NN) return;
  const float* row = (r < split) ? A0 + (size_t)r * DD : A1 + (size_t)(r - split) * DD;
  const float4* r4 = (const float4*)row;
  const float4* s4 = (const float4*)vs;
  const float4* d4 = (const float4*)vd;
  float4 v0 = r4[lane], v1 = r4[lane + 64];
  float4 a0 = s4[lane], a1 = s4[lane + 64];
  float4 b0 = d4[lane], b1 = d4[lane + 64];
  float s1 = v0.x * a0.x + v0.y * a0.y + v0.z * a0.z + v0.w * a0.w
           + v1.x * a1.x + v1.y * a1.y + v1.z * a1.z + v1.w * a1.w;
  float s2 = v0.x * b0.x + v0.y * b0.y + v0.z * b0.z + v0.w * b0.w
           + v1.x * b1.x + v1.y * b1.y + v1.z * b1.z + v1.w * b1.w;
#pragma unroll
  for (int off = 32; off > 0; off >>= 1) {
    s1 += __shfl_down(s1, off);
    s2 += __shfl_down(s2, off);
  }
  if (lane == 0) { ls[r] = s1; ld[r] = s2; }
}

// softmax weights -> split f16. u in [0,384): [0,256) sample quads,
// [256,384) proxy rows (i >= PP rows zero-fill the Ep k-pad).
__device__ void dv_alpha(int u, const float* ls, const float* ld,
                         f16* Esh, f16* Esl, float* esS, float* izS,
                         f16* Eph, f16* Epl, float* esP, float* izP, float* red)
{
  const int t = threadIdx.x;
  if (u < 256) {
    const int lane = t & 63;
    const int i = u * 4 + (t >> 6);              // sample dst
    const float ldi = ld[PP + i];
    float e0 = lk(ls[lane] + ldi);               // lane < 100 always
    float e1 = (lane < PP - 64) ? lk(ls[lane + 64] + ldi) : -1e30f;
    const float eself = lk(ls[PP + i] + ldi);
    float m = fmaxf(fmaxf(e0, e1), eself);
#pragma unroll
    for (int off = 1; off < 64; off <<= 1) m = fmaxf(m, __shfl_xor(m, off));
    float x0 = __expf(e0 - m);
    float x1 = (lane < PP - 64) ? __expf(e1 - m) : 0.f;
    float z = x0 + x1;
#pragma unroll
    for (int off = 1; off < 64; off <<= 1) z += __shfl_xor(z, off);
    Esh[(size_t)i * 128 + lane]      = hif(x0);
    Esl[(size_t)i * 128 + lane]      = lof(x0);
    Esh[(size_t)i * 128 + 64 + lane] = hif(x1);
    Esl[(size_t)i * 128 + 64 + lane] = lof(x1);
    if (lane == 0) {
      float xs = __expf(eself - m);
      esS[i] = xs;
      izS[i] = 1.f / (z + xs);
    }
  } else {
    const int i = u - 256;                       // proxy dst (or k-pad row)
    if (i >= PP) {                               // zero-fill pad rows 100..127
#pragma unroll
      for (int q = 0; q < 4; ++q) {
        Eph[(size_t)i * NS + t + q * 256] = (f16)0.f;
        Epl[(size_t)i * NS + t + q * 256] = (f16)0.f;
      }
      return;
    }
    const float ldi = ld[i];
    const float eself = lk(ls[i] + ldi);
    float e[4];
#pragma unroll
    for (int q = 0; q < 4; ++q) e[q] = lk(ls[PP + t + q * 256] + ldi);
    float m = fmaxf(fmaxf(fmaxf(e[0], e[1]), fmaxf(e[2], e[3])), eself);
#pragma unroll
    for (int off = 1; off < 64; off <<= 1) m = fmaxf(m, __shfl_xor(m, off));
    if ((t & 63) == 0) red[t >> 6] = m;
    __syncthreads();
    m = fmaxf(fmaxf(red[0], red[1]), fmaxf(red[2], red[3]));
    __syncthreads();
    float xq[4], z = 0.f;
#pragma unroll
    for (int q = 0; q < 4; ++q) { xq[q] = __expf(e[q] - m); z += xq[q]; }
#pragma unroll
    for (int off = 1; off < 64; off <<= 1) z += __shfl_xor(z, off);
    if ((t & 63) == 0) red[t >> 6] = z;
    __syncthreads();
#pragma unroll
    for (int q = 0; q < 4; ++q) {
      Eph[(size_t)i * NS + t + q * 256] = hif(xq[q]);
      Epl[(size_t)i * NS + t + q * 256] = lof(xq[q]);
    }
    if (t == 0) {
      float xs = __expf(eself - m);
      esP[i] = xs;
      izP[i] = 1.f / (red[0] + red[1] + red[2] + red[3] + xs);
    }
  }
}

// layer-1 aggregation: u in [0,144): [0,128) sample tiles, [128,144) proxy.
__device__ void dv_agg1(int u, const FA& a, f16* lds)
{
  f32x4 acc[2][2] = {};
  const int t = threadIdx.x, lane = t & 63, w = t >> 6, wr = w >> 1, wc = w & 1;
  if (u < 128) {
    // M1_samp[1024,512] = Es1[1024,128] @ prox(pad 128), epi self = x
    const int row0 = (u >> 3) * 64, col0 = (u & 7) * 64;
    mgemm_core(a.Es1h, a.Es1l, a.pth, a.ptl, 128, row0, col0, lds, acc);
#pragma unroll
    for (int m = 0; m < 2; ++m)
#pragma unroll
      for (int q = 0; q < 4; ++q) {
        const int r = row0 + wr * 32 + m * 16 + (lane >> 4) * 4 + q;
        const float e = a.esS1[r], z = a.izS1[r];
#pragma unroll
        for (int n = 0; n < 2; ++n) {
          const int c = col0 + wc * 32 + n * 16 + (lane & 15);
          const float v = (acc[m][n][q] + e * a.x[(size_t)r * DD + c]) * z;
          const size_t o = (size_t)(PP + r) * DD + c;
          a.M1h[o] = hif(v); a.M1l[o] = lof(v);
        }
      }
  } else {
    // M1_prox[100,512] = Ep[100(pad128),1024] @ x, epi self = prox
    const int b2 = u - 128;
    const int row0 = (b2 >> 3) * 64, col0 = (b2 & 7) * 64;
    mgemm_core(a.Eph, a.Epl, a.xth, a.xtl, NS, row0, col0, lds, acc);
#pragma unroll
    for (int m = 0; m < 2; ++m)
#pragma unroll
      for (int q = 0; q < 4; ++q) {
        const int r = row0 + wr * 32 + m * 16 + (lane >> 4) * 4 + q;
        if (r < PP) {
          const float e = a.esP[r], z = a.izP[r];
#pragma unroll
          for (int n = 0; n < 2; ++n) {
            const int c = col0 + wc * 32 + n * 16 + (lane & 15);
            const float v = (acc[m][n][q] + e * a.prox[(size_t)r * DD + c]) * z;
            const size_t o = (size_t)r * DD + c;
            a.M1h[o] = hif(v); a.M1l[o] = lof(v);
          }
        }
      }
  }
}

// h1 = relu(M1@W1 + b1); also emit split-transposed proxy rows. u in [0,144)
__device__ void dv_h1(int u, const FA& a, f16* lds)
{
  f32x4 acc[2][2] = {};
  const int t = threadIdx.x, lane = t & 63, w = t >> 6, wr = w >> 1, wc = w & 1;
  const int row0 = (u >> 3) * 64, col0 = (u & 7) * 64;
  mgemm_core(a.M1h, a.M1l, a.W1th, a.W1tl, DD, row0, col0, lds, acc);
#pragma unroll
  for (int m = 0; m < 2; ++m)
#pragma unroll
    for (int q = 0; q < 4; ++q) {
      const int r = row0 + wr * 32 + m * 16 + (lane >> 4) * 4 + q;
      if (r >= NN) continue;
#pragma unroll
      for (int n = 0; n < 2; ++n) {
        const int c = col0 + wc * 32 + n * 16 + (lane & 15);
        const float v = fmaxf(acc[m][n][q] + a.b1[c], 0.f);
        a.h1[(size_t)r * DD + c] = v;
        if (r < 128) {                       // B of agg2: zero-fill k-pad rows
          const size_t o = (size_t)c * 128 + r;
          f16 hh = (f16)0.f, ll = (f16)0.f;
          if (r < PP) { hh = hif(v); ll = lof(v); }
          a.h1pth[o] = hh; a.h1ptl[o] = ll;
        }
      }
    }
}

// layer-2 aggregation (sample dsts only). u in [0,128)
__device__ void dv_agg2(int u, const FA& a, f16* lds)
{
  f32x4 acc[2][2] = {};
  const int t = threadIdx.x, lane = t & 63, w = t >> 6, wr = w >> 1, wc = w & 1;
  const int row0 = (u >> 3) * 64, col0 = (u & 7) * 64;
  mgemm_core(a.Es2h, a.Es2l, a.h1pth, a.h1ptl, 128, row0, col0, lds, acc);
#pragma unroll
  for (int m = 0; m < 2; ++m)
#pragma unroll
    for (int q = 0; q < 4; ++q) {
      const int r = row0 + wr * 32 + m * 16 + (lane >> 4) * 4 + q;
      const float e = a.esS2[r], z = a.izS2[r];
#pragma unroll
      for (int n = 0; n < 2; ++n) {
        const int c = col0 + wc * 32 + n * 16 + (lane & 15);
        const float v = (acc[m][n][q] + e * a.h1[(size_t)(PP + r) * DD + c]) * z;
        const size_t o = (size_t)r * DD + c;
        a.M2h[o] = hif(v); a.M2l[o] = lof(v);
      }
    }
}

// h2 = relu(M2@W2 + b2) -> d_out (fp32) + split for fc. u in [0,128)
__device__ void dv_h2(int u, const FA& a, f16* lds)
{
  f32x4 acc[2][2] = {};
  const int t = threadIdx.x, lane = t & 63, w = t >> 6, wr = w >> 1, wc = w & 1;
  const int row0 = (u >> 3) * 64, col0 = (u & 7) * 64;
  mgemm_core(a.M2h, a.M2l, a.W2th, a.W2tl, DD, row0, col0, lds, acc);
#pragma unroll
  for (int m = 0; m < 2; ++m)
#pragma unroll
    for (int q = 0; q < 4; ++q) {
      const int r = row0 + wr * 32 + m * 16 + (lane >> 4) * 4 + q;
#pragma unroll
      for (int n = 0; n < 2; ++n) {
        const int c = col0 + wc * 32 + n * 16 + (lane & 15);
        const float v = fmaxf(acc[m][n][q] + a.b2[c], 0.f);
        const size_t o = (size_t)r * DD + c;
        a.h2s[o] = v;
        a.h2h[o] = hif(v); a.h2l[o] = lof(v);
      }
    }
}

// preds = h2 @ fcw + fcb. u in [0,32)
__device__ void dv_fc(int u, const FA& a, f16* lds)
{
  f32x4 acc[2][2] = {};
  const int t = threadIdx.x, lane = t & 63, w = t >> 6, wr = w >> 1, wc = w & 1;
  const int row0 = (u >> 1) * 64, col0 = (u & 1) * 64;
  mgemm_core(a.h2h, a.h2l, a.fwth, a.fwtl, DD, row0, col0, lds, acc);
#pragma unroll
  for (int m = 0; m < 2; ++m)
#pragma unroll
    for (int q = 0; q < 4; ++q) {
      const int r = row0 + wr * 32 + m * 16 + (lane >> 4) * 4 + q;
#pragma unroll
      for (int n = 0; n < 2; ++n) {
        const int c = col0 + wc * 32 + n * 16 + (lane & 15);
        if (c < CC) a.out[(size_t)r * CC + c] = acc[m][n][q] + a.fcb[c];
      }
    }
}

// =================== fused kernel (tree grid barrier) ======================
__global__ __launch_bounds__(NTHR) void fused_k(FA a)
{
  __shared__ __align__(16) f16 lds[10240];
  __shared__ float red[4];
  f16 (*th)[72] = (f16(*)[72])lds;
  f16 (*tl)[72] = (f16(*)[72])(lds + 4608);
  unsigned bg = 0;                                      // local barrier index

  for (int u = blockIdx.x; u < 544; u += gridDim.x) {   // P0 prep
    dv_prep(u, a, th, tl);
    __syncthreads();
  }
  gbar(a.bar, ++bg);
  for (int u = blockIdx.x; u < 281; u += gridDim.x)     // P1 lvec1
    dv_lvec(u, a.prox, a.x, PP, a.v1s, a.v1d, a.ls1, a.ld1);
  gbar(a.bar, ++bg);
  for (int u = blockIdx.x; u < 384; u += gridDim.x) {   // P2 alpha1
    dv_alpha(u, a.ls1, a.ld1, a.Es1h, a.Es1l, a.esS1, a.izS1,
             a.Eph, a.Epl, a.esP, a.izP, red);
    __syncthreads();
  }
  gbar(a.bar, ++bg);
  for (int u = blockIdx.x; u < 144; u += gridDim.x)     // P3 agg1
    dv_agg1(u, a, lds);
  gbar(a.bar, ++bg);
  for (int u = blockIdx.x; u < 144; u += gridDim.x)     // P4 h1
    dv_h1(u, a, lds);
  gbar(a.bar, ++bg);
  for (int u = blockIdx.x; u < 281; u += gridDim.x)     // P5 lvec2
    dv_lvec(u, a.h1, a.h1, NN, a.v2s, a.v2d, a.ls2, a.ld2);
  gbar(a.bar, ++bg);
  for (int u = blockIdx.x; u < 256; u += gridDim.x) {   // P6 alpha2 (samples)
    dv_alpha(u, a.ls2, a.ld2, a.Es2h, a.Es2l, a.esS2, a.izS2,
             a.Eph, a.Epl, a.esP, a.izP, red);
    __syncthreads();
  }
  gbar(a.bar, ++bg);
  for (int u = blockIdx.x; u < 128; u += gridDim.x)     // P7 agg2
    dv_agg2(u, a, lds);
  gbar(a.bar, ++bg);
  for (int u = blockIdx.x; u < 128; u += gridDim.x)     // P8 h2
    dv_h2(u, a, lds);
  gbar(a.bar, ++bg);
  for (int u = blockIdx.x; u < 32; u += gridDim.x)      // P9 fc
    dv_fc(u, a, lds);
}

// =================== fallback (non-cooperative) wrappers ===================
__global__ __launch_bounds__(NTHR) void prep_k(FA a) {
  __shared__ f16 th[64][72];
  __shared__ f16 tl[64][72];
  dv_prep(blockIdx.x, a, th, tl);
}
__global__ __launch_bounds__(NTHR) void lvec_k(FA a, int layer) {
  if (layer == 1) dv_lvec(blockIdx.x, a.prox, a.x, PP, a.v1s, a.v1d, a.ls1, a.ld1);
  else            dv_lvec(blockIdx.x, a.h1, a.h1, NN, a.v2s, a.v2d, a.ls2, a.ld2);
}
__global__ __launch_bounds__(NTHR) void alpha_k(FA a, int layer) {
  __shared__ float red[4];
  if (layer == 1)
    dv_alpha(blockIdx.x, a.ls1, a.ld1, a.Es1h, a.Es1l, a.esS1, a.izS1,
             a.Eph, a.Epl, a.esP, a.izP, red);
  else
    dv_alpha(blockIdx.x, a.ls2, a.ld2, a.Es2h, a.Es2l, a.esS2, a.izS2,
             a.Eph, a.Epl, a.esP, a.izP, red);
}
__global__ __launch_bounds__(NTHR) void agg1_k(FA a) {
  __shared__ __align__(16) f16 lds[10240];
  dv_agg1(blockIdx.x, a, lds);
}
__global__ __launch_bounds__(NTHR) void h1_k(FA a) {
  __shared__ __align__(16) f16 lds[10240];
  dv_h1(blockIdx.x, a, lds);
}
__global__ __launch_bounds__(NTHR) void agg2_k(FA a) {
  __shared__ __align__(16) f16 lds[10240];
  dv_agg2(blockIdx.x, a, lds);
}
__global__ __launch_bounds__(NTHR) void h2_k(FA a) {
  __shared__ __align__(16) f16 lds[10240];
  dv_h2(blockIdx.x, a, lds);
}
__global__ __launch_bounds__(NTHR) void fc_k(FA a) {
  __shared__ __align__(16) f16 lds[10240];
  dv_fc(blockIdx.x, a, lds);
}

extern "C" void kernel_launch(void* const* d_in, const int* in_sizes, int n_in,
                              void* d_out, int out_size, void* d_ws, size_t ws_size,
                              hipStream_t stream)
{
  FA a;
  a.x    = (const float*)d_in[0];
  a.prox = (const float*)d_in[1];
  a.W1   = (const float*)d_in[2];
  a.as1  = (const float*)d_in[3];
  a.ad1  = (const float*)d_in[4];
  a.b1   = (const float*)d_in[5];
  a.W2   = (const float*)d_in[6];
  a.as2  = (const float*)d_in[7];
  a.ad2  = (const float*)d_in[8];
  a.b2   = (const float*)d_in[9];
  a.fcw  = (const float*)d_in[10];
  a.fcb  = (const float*)d_in[11];
  a.out  = (float*)d_out;

  // fp32 workspace
  float* F = (float*)d_ws;
  a.h1   = F; F += (size_t)NN * DD;
  a.ls1  = F; F += 1152;
  a.ld1  = F; F += 1152;
  a.ls2  = F; F += 1152;
  a.ld2  = F; F += 1152;
  a.v1s  = F; F += DD;
  a.v1d  = F; F += DD;
  a.v2s  = F; F += DD;
  a.v2d  = F; F += DD;
  a.esS1 = F; F += NS;
  a.izS1 = F; F += NS;
  a.esS2 = F; F += NS;
  a.izS2 = F; F += NS;
  a.esP  = F; F += 128;
  a.izP  = F; F += 128;
  // grid-barrier state (640 dwords; zeroed via memset each iteration)
  unsigned* sync = (unsigned*)F; F += 640;
  a.bar = sync;
  // f16 split workspace (all bases 16B aligned; sizes multiples of 8 halves)
  f16* H = (f16*)F;
  a.M1h  = H; H += (size_t)1152 * DD;   // rows: 100 prox + 1024 samp + pad
  a.M1l  = H; H += (size_t)1152 * DD;
  a.M2h  = H; H += (size_t)NS * DD;
  a.M2l  = H; H += (size_t)NS * DD;
  a.Es1h = H; H += (size_t)NS * 128;
  a.Es1l = H; H += (size_t)NS * 128;
  a.Es2h = H; H += (size_t)NS * 128;
  a.Es2l = H; H += (size_t)NS * 128;
  a.Eph  = H; H += (size_t)128 * NS;
  a.Epl  = H; H += (size_t)128 * NS;
  a.xth  = H; H += (size_t)DD * NS;     // x^T  [512][1024]
  a.xtl  = H; H += (size_t)DD * NS;
  a.pth  = H; H += (size_t)DD * 128;    // prox^T [512][128] (k-pad zeroed)
  a.ptl  = H; H += (size_t)DD * 128;
  a.W1th = H; H += (size_t)DD * DD;     // W1^T [512][512]
  a.W1tl = H; H += (size_t)DD * DD;
  a.W2th = H; H += (size_t)DD * DD;
  a.W2tl = H; H += (size_t)DD * DD;
  a.fwth = H; H += (size_t)128 * DD;    // fcw^T [128][512] (k-pad zeroed)
  a.fwtl = H; H += (size_t)128 * DD;
  a.h2h  = H; H += (size_t)NS * DD;
  a.h2l  = H; H += (size_t)NS * DD;
  a.h1pth = H; H += (size_t)DD * 128;   // h1 proxy rows ^T [512][128]
  a.h1ptl = H; H += (size_t)DD * 128;
  a.h2s  = a.out + (size_t)NS * CC;     // layer-2 sample out in d_out

  // zero the barrier state (workspace is poisoned between iterations)
  hipMemsetAsync((void*)sync, 0, 640 * sizeof(unsigned), stream);

  dim3 blk(NTHR);
  void* params[] = { (void*)&a };
  hipError_t err = hipLaunchCooperativeKernel(
      (const void*)fused_k, dim3(GRID), blk, params, 0, stream);
  if (err != hipSuccess) {
    // fallback: original 10-launch sequence (same math)
    prep_k <<<dim3(544), blk, 0, stream>>>(a);
    lvec_k <<<dim3(281), blk, 0, stream>>>(a, 1);
    alpha_k<<<dim3(384), blk, 0, stream>>>(a, 1);
    agg1_k <<<dim3(144), blk, 0, stream>>>(a);
    h1_k   <<<dim3(144), blk, 0, stream>>>(a);
    lvec_k <<<dim3(281), blk, 0, stream>>>(a, 2);
    alpha_k<<<dim3(256), blk, 0, stream>>>(a, 2);
    agg2_k <<<dim3(128), blk, 0, stream>>>(a);
    h2_k   <<<dim3(128), blk, 0, stream>>>(a);
    fc_k   <<<dim3(32),  blk, 0, stream>>>(a);
  }
}

// Round 6
// 178.122 us; speedup vs baseline: 3.2645x; 1.7126x over previous
//
#include <hip/hip_runtime.h>

// Problem constants (complete bipartite proxy<->sample + self-loops)
#define PP 100    // proxies
#define NS 1024   // samples
#define NN 1124   // total nodes
#define DD 512    // feature dim
#define CC 100    // fc out dim
#define NTHR 256

typedef _Float16 f16;
typedef _Float16 f16x8 __attribute__((ext_vector_type(8)));
typedef float    f32x4 __attribute__((ext_vector_type(4)));

__device__ __forceinline__ float lk(float v) { return v > 0.f ? v : 0.2f * v; }
__device__ __forceinline__ f16 hif(float v) { return (f16)v; }
__device__ __forceinline__ f16 lof(float v) { return (f16)(v - (float)((f16)v)); }

// =================== MFMA split-f16 GEMM core =============================
// acc[2][2] += A[row0.., K] @ B ; A = (Ah,Al) row-major [*,K], B TRANSPOSED
// as (Bth,Btl) row-major [*,K] (row = output col). 64x64 tile, 4 waves of
// 32x32, BK=32. C = Ah*Bh + Al*Bh + Ah*Bl (fp32 acc; al*bl dropped).
__device__ __forceinline__ void mgemm_core(
    const f16* __restrict__ Ah, const f16* __restrict__ Al,
    const f16* __restrict__ Bth, const f16* __restrict__ Btl,
    int K, int row0, int col0, f16* __restrict__ lds, f32x4 acc[2][2])
{
  const int t = threadIdx.x;
  const int lane = t & 63, w = t >> 6;
  const int wr = w >> 1, wc = w & 1;
  f16* Ash = lds;
  f16* Asl = lds + 2560;
  f16* Bsh = lds + 5120;
  f16* Bsl = lds + 7680;
  const int srow = t >> 2, su = t & 3;
  const size_t aoff = (size_t)(row0 + srow) * K + su * 8;
  const size_t boff = (size_t)(col0 + srow) * K + su * 8;
  const int lw = srow * 40 + su * 8;
  f32x4 pa0 = *(const f32x4*)(Ah + aoff);
  f32x4 pa1 = *(const f32x4*)(Al + aoff);
  f32x4 pb0 = *(const f32x4*)(Bth + boff);
  f32x4 pb1 = *(const f32x4*)(Btl + boff);
  const int fra = wr * 32 + (lane & 15);
  const int frb = wc * 32 + (lane & 15);
  const int fu  = (lane >> 4) * 8;
  for (int kt = 32; kt <= K; kt += 32) {
    *(f32x4*)(Ash + lw) = pa0;
    *(f32x4*)(Asl + lw) = pa1;
    *(f32x4*)(Bsh + lw) = pb0;
    *(f32x4*)(Bsl + lw) = pb1;
    __syncthreads();
    if (kt < K) {
      pa0 = *(const f32x4*)(Ah + aoff + kt);
      pa1 = *(const f32x4*)(Al + aoff + kt);
      pb0 = *(const f32x4*)(Bth + boff + kt);
      pb1 = *(const f32x4*)(Btl + boff + kt);
    }
    f16x8 ah[2], al[2], bh[2], bl[2];
#pragma unroll
    for (int m = 0; m < 2; ++m) {
      ah[m] = *(const f16x8*)(Ash + (fra + m * 16) * 40 + fu);
      al[m] = *(const f16x8*)(Asl + (fra + m * 16) * 40 + fu);
    }
#pragma unroll
    for (int n = 0; n < 2; ++n) {
      bh[n] = *(const f16x8*)(Bsh + (frb + n * 16) * 40 + fu);
      bl[n] = *(const f16x8*)(Bsl + (frb + n * 16) * 40 + fu);
    }
#pragma unroll
    for (int m = 0; m < 2; ++m)
#pragma unroll
      for (int n = 0; n < 2; ++n) {
        acc[m][n] = __builtin_amdgcn_mfma_f32_16x16x32_f16(ah[m], bh[n], acc[m][n], 0, 0, 0);
        acc[m][n] = __builtin_amdgcn_mfma_f32_16x16x32_f16(al[m], bh[n], acc[m][n], 0, 0, 0);
        acc[m][n] = __builtin_amdgcn_mfma_f32_16x16x32_f16(ah[m], bl[n], acc[m][n], 0, 0, 0);
      }
    __syncthreads();
  }
}

// ============ fused softmax+aggregation GEMM ==============================
// A[r][k] = exp(lk(lsrc[k] + ld_r) - m_r) computed inline during staging
// (k >= kvalid or invalid row -> 0). m_r = lk(max(smax, ls_self_r) + ld_r)
// via monotonicity of leaky_relu. Per-row denominator z accumulated during
// staging; epilogue: out = (acc + es*self)*iz, split f16 write.
__device__ __forceinline__ void agg_core(
    const float* __restrict__ lsrc, int kvalid,
    const float* __restrict__ ldb, const float* __restrict__ lsb,
    const f16* __restrict__ Bth, const f16* __restrict__ Btl,
    int K, int row0, int col0, int rvalid,
    const float* __restrict__ selfv,
    f16* __restrict__ outh, f16* __restrict__ outl,
    f16* __restrict__ lds, float* __restrict__ fred)
{
  const int t = threadIdx.x, lane = t & 63, w = t >> 6;
  const int wr = w >> 1, wc = w & 1;
  f16* Ash = lds;
  f16* Asl = lds + 2560;
  f16* Bsh = lds + 5120;
  f16* Bsl = lds + 7680;
  float* zred = fred;          // [256]
  float* res  = fred + 256;    // [64] self exps
  float* riz  = fred + 320;    // [64] 1/denominator
  const int srow = t >> 2, su = t & 3;
  // block-uniform max over lsrc[0..kvalid)
  float sm = -1e30f;
  for (int k = t; k < kvalid; k += NTHR) sm = fmaxf(sm, lsrc[k]);
#pragma unroll
  for (int off = 1; off < 64; off <<= 1) sm = fmaxf(sm, __shfl_xor(sm, off));
  if (lane == 0) zred[w] = sm;
  __syncthreads();
  sm = fmaxf(fmaxf(zred[0], zred[1]), fmaxf(zred[2], zred[3]));
  __syncthreads();
  // per staging-row constants
  const bool rok = (row0 + srow) < rvalid;
  float ldr = 0.f, mr = 0.f;
  if (rok) {
    ldr = ldb[row0 + srow];
    mr  = lk(fmaxf(sm, lsb[row0 + srow]) + ldr);
  }
  const size_t boff = (size_t)(col0 + srow) * K + su * 8;
  const int lw = srow * 40 + su * 8;
  f32x4 pb0 = *(const f32x4*)(Bth + boff);
  f32x4 pb1 = *(const f32x4*)(Btl + boff);
  const int fra = wr * 32 + (lane & 15);
  const int frb = wc * 32 + (lane & 15);
  const int fu  = (lane >> 4) * 8;
  f32x4 acc[2][2] = {};
  float zacc = 0.f;
  for (int kt = 32; kt <= K; kt += 32) {
    f16x8 ae, al8;
    const int k0 = kt - 32 + su * 8;
#pragma unroll
    for (int j = 0; j < 8; ++j) {
      const int k = k0 + j;
      float f = 0.f;
      if (rok && k < kvalid) f = __expf(lk(lsrc[k] + ldr) - mr);
      zacc += f;
      ae[j]  = hif(f);
      al8[j] = lof(f);
    }
    *(f16x8*)(Ash + lw) = ae;
    *(f16x8*)(Asl + lw) = al8;
    *(f32x4*)(Bsh + lw) = pb0;
    *(f32x4*)(Bsl + lw) = pb1;
    __syncthreads();
    if (kt < K) {
      pb0 = *(const f32x4*)(Bth + boff + kt);
      pb1 = *(const f32x4*)(Btl + boff + kt);
    }
    f16x8 ah[2], alr[2], bh[2], bl[2];
#pragma unroll
    for (int m = 0; m < 2; ++m) {
      ah[m]  = *(const f16x8*)(Ash + (fra + m * 16) * 40 + fu);
      alr[m] = *(const f16x8*)(Asl + (fra + m * 16) * 40 + fu);
    }
#pragma unroll
    for (int n = 0; n < 2; ++n) {
      bh[n] = *(const f16x8*)(Bsh + (frb + n * 16) * 40 + fu);
      bl[n] = *(const f16x8*)(Bsl + (frb + n * 16) * 40 + fu);
    }
#pragma unroll
    for (int m = 0; m < 2; ++m)
#pragma unroll
      for (int n = 0; n < 2; ++n) {
        acc[m][n] = __builtin_amdgcn_mfma_f32_16x16x32_f16(ah[m],  bh[n], acc[m][n], 0, 0, 0);
        acc[m][n] = __builtin_amdgcn_mfma_f32_16x16x32_f16(alr[m], bh[n], acc[m][n], 0, 0, 0);
        acc[m][n] = __builtin_amdgcn_mfma_f32_16x16x32_f16(ah[m],  bl[n], acc[m][n], 0, 0, 0);
      }
    __syncthreads();
  }
  // per-row denominator, self exp, inverse
  zred[t] = zacc;
  __syncthreads();
  if (t < 64) {
    float z = zred[t * 4] + zred[t * 4 + 1] + zred[t * 4 + 2] + zred[t * 4 + 3];
    float es = 0.f, iz = 0.f;
    if (row0 + t < rvalid) {
      const float l2 = ldb[row0 + t], s2 = lsb[row0 + t];
      const float m2 = lk(fmaxf(sm, s2) + l2);
      es = __expf(lk(s2 + l2) - m2);
      iz = 1.f / (z + es);
    }
    res[t] = es; riz[t] = iz;
  }
  __syncthreads();
  // epilogue
#pragma unroll
  for (int m = 0; m < 2; ++m)
#pragma unroll
    for (int q = 0; q < 4; ++q) {
      const int rl = wr * 32 + m * 16 + (lane >> 4) * 4 + q;
      const int gr = row0 + rl;
      if (gr >= rvalid) continue;
      const float es = res[rl], iz = riz[rl];
#pragma unroll
      for (int n = 0; n < 2; ++n) {
        const int c = col0 + wc * 32 + n * 16 + (lane & 15);
        const float v = (acc[m][n][q] + es * selfv[(size_t)gr * DD + c]) * iz;
        outh[(size_t)gr * DD + c] = hif(v);
        outl[(size_t)gr * DD + c] = lof(v);
      }
    }
}

// ======== 64x64 transpose+split tile (fp32 in -> f16 hi/lo transposed) =====
__device__ __forceinline__ void cvt_tile(
    const float* __restrict__ in, int R, int Cin,
    f16* __restrict__ oh, f16* __restrict__ ol, int ldo,
    int ti, int tj, f16 (*th)[72], f16 (*tl)[72])
{
  const int t = threadIdx.x;
#pragma unroll
  for (int p = 0; p < 4; ++p) {
    const int f = t + p * 256;
    const int i = f >> 4, j4 = (f & 15) * 4;
    const int gi = ti * 64 + i, gj = tj * 64 + j4;
    float4 v = make_float4(0.f, 0.f, 0.f, 0.f);
    if (gi < R && gj + 3 < Cin) v = *(const float4*)(in + (size_t)gi * Cin + gj);
    th[i][j4 + 0] = hif(v.x); tl[i][j4 + 0] = lof(v.x);
    th[i][j4 + 1] = hif(v.y); tl[i][j4 + 1] = lof(v.y);
    th[i][j4 + 2] = hif(v.z); tl[i][j4 + 2] = lof(v.z);
    th[i][j4 + 3] = hif(v.w); tl[i][j4 + 3] = lof(v.w);
  }
  __syncthreads();
#pragma unroll
  for (int p = 0; p < 2; ++p) {
    const int f = t + p * 256;
    const int j = f >> 3, i8 = (f & 7) * 8;
    f16x8 vh, vl;
#pragma unroll
    for (int e = 0; e < 8; ++e) { vh[e] = th[i8 + e][j]; vl[e] = tl[i8 + e][j]; }
    const size_t o = (size_t)(tj * 64 + j) * ldo + ti * 64 + i8;
    *(f16x8*)(oh + o) = vh;
    *(f16x8*)(ol + o) = vl;
  }
}

// ===== K1: weight matvecs (v = W@a, both layers) + zero ls2/ld2 ============
__global__ __launch_bounds__(NTHR) void prep1_k(
    const float* __restrict__ W1, const float* __restrict__ W2,
    const float* __restrict__ as1, const float* __restrict__ ad1,
    const float* __restrict__ as2, const float* __restrict__ ad2,
    float* __restrict__ v1s, float* __restrict__ v1d,
    float* __restrict__ v2s, float* __restrict__ v2d,
    float* __restrict__ ls2, float* __restrict__ ld2)
{
  const int u = blockIdx.x;
  if (u < 256) {
    const int wid  = u * 4 + (threadIdx.x >> 6);   // 0..1023
    const int lane = threadIdx.x & 63;
    const int r = wid & 511;
    const bool l1 = (wid < 512);
    const float* W = l1 ? W1 : W2;
    const float4* a4 = (const float4*)(l1 ? as1 : as2);
    const float4* b4 = (const float4*)(l1 ? ad1 : ad2);
    const float4* w4 = (const float4*)(W + (size_t)r * DD);
    float4 w0 = w4[lane], w1 = w4[lane + 64];
    float4 a0 = a4[lane], a1 = a4[lane + 64];
    float4 b0 = b4[lane], b1 = b4[lane + 64];
    float s1 = w0.x * a0.x + w0.y * a0.y + w0.z * a0.z + w0.w * a0.w
             + w1.x * a1.x + w1.y * a1.y + w1.z * a1.z + w1.w * a1.w;
    float s2 = w0.x * b0.x + w0.y * b0.y + w0.z * b0.z + w0.w * b0.w
             + w1.x * b1.x + w1.y * b1.y + w1.z * b1.z + w1.w * b1.w;
#pragma unroll
    for (int off = 32; off > 0; off >>= 1) {
      s1 += __shfl_down(s1, off);
      s2 += __shfl_down(s2, off);
    }
    if (lane == 0) {
      (l1 ? v1s : v2s)[r] = s1;
      (l1 ? v1d : v2d)[r] = s2;
    }
  } else {
    for (int i = threadIdx.x; i < 1152; i += NTHR) { ls2[i] = 0.f; ld2[i] = 0.f; }
  }
}

// ===== K2: transposes/splits + layer-1 logits (needs v1 from K1) ==========
__global__ __launch_bounds__(NTHR) void prep2_k(
    const float* __restrict__ x, const float* __restrict__ prox,
    const float* __restrict__ W1, const float* __restrict__ W2,
    const float* __restrict__ fcw,
    const float* __restrict__ v1s, const float* __restrict__ v1d,
    f16* xth, f16* xtl, f16* pth, f16* ptl,
    f16* W1th, f16* W1tl, f16* W2th, f16* W2tl, f16* fwth, f16* fwtl,
    float* __restrict__ ls1, float* __restrict__ ld1)
{
  __shared__ f16 th[64][72];
  __shared__ f16 tl[64][72];
  const int b = blockIdx.x;
  if (b < 64) {
    cvt_tile(W1, 512, 512, W1th, W1tl, 512, b >> 3, b & 7, th, tl);
  } else if (b < 128) {
    cvt_tile(W2, 512, 512, W2th, W2tl, 512, (b - 64) >> 3, (b - 64) & 7, th, tl);
  } else if (b < 256) {
    cvt_tile(x, NS, 512, xth, xtl, NS, (b - 128) >> 3, (b - 128) & 7, th, tl);
  } else if (b < 272) {
    cvt_tile(prox, PP, 512, pth, ptl, 128, (b - 256) >> 3, (b - 256) & 7, th, tl);
  } else if (b < 288) {
    cvt_tile(fcw, 512, CC, fwth, fwtl, 512, (b - 272) >> 1, (b - 272) & 1, th, tl);
  } else {
    // layer-1 logits: one wave per node row
    const int r    = (b - 288) * 4 + (threadIdx.x >> 6);
    const int lane = threadIdx.x & 63;
    if (r >= NN) return;
    const float* row = (r < PP) ? prox + (size_t)r * DD
                                : x + (size_t)(r - PP) * DD;
    const float4* r4 = (const float4*)row;
    const float4* s4 = (const float4*)v1s;
    const float4* d4 = (const float4*)v1d;
    float4 v0 = r4[lane], v1 = r4[lane + 64];
    float4 a0 = s4[lane], a1 = s4[lane + 64];
    float4 b0 = d4[lane], b1 = d4[lane + 64];
    float s1 = v0.x * a0.x + v0.y * a0.y + v0.z * a0.z + v0.w * a0.w
             + v1.x * a1.x + v1.y * a1.y + v1.z * a1.z + v1.w * a1.w;
    float s2 = v0.x * b0.x + v0.y * b0.y + v0.z * b0.z + v0.w * b0.w
             + v1.x * b1.x + v1.y * b1.y + v1.z * b1.z + v1.w * b1.w;
#pragma unroll
    for (int off = 32; off > 0; off >>= 1) {
      s1 += __shfl_down(s1, off);
      s2 += __shfl_down(s2, off);
    }
    if (lane == 0) { ls1[r] = s1; ld1[r] = s2; }
  }
}

// ===== K3: layer-1 aggregation (softmax fused): [0,128) samp, [128,144) prox
__global__ __launch_bounds__(NTHR) void agg1x_k(
    const float* __restrict__ ls1, const float* __restrict__ ld1,
    const f16* __restrict__ pth, const f16* __restrict__ ptl,
    const f16* __restrict__ xth, const f16* __restrict__ xtl,
    const float* __restrict__ x, const float* __restrict__ prox,
    f16* __restrict__ M1h, f16* __restrict__ M1l)
{
  __shared__ __align__(16) f16 lds[10240];
  __shared__ float fred[384];
  const int b = blockIdx.x;
  if (b < 128) {
    // M1_samp = softmax_rows(exp over 100 proxies) @ prox^T, self = x
    const int row0 = (b >> 3) * 64, col0 = (b & 7) * 64;
    agg_core(ls1, PP, ld1 + PP, ls1 + PP, pth, ptl, 128, row0, col0, NS,
             x, M1h + (size_t)PP * DD, M1l + (size_t)PP * DD, lds, fred);
  } else {
    // M1_prox = softmax_rows(exp over 1024 samples) @ x^T, self = prox
    const int b2 = b - 128;
    const int row0 = (b2 >> 3) * 64, col0 = (b2 & 7) * 64;
    agg_core(ls1 + PP, NS, ld1, ls1, xth, xtl, NS, row0, col0, PP,
             prox, M1h, M1l, lds, fred);
  }
}

// ===== K4: h1 = relu(M1@W1 + b1); emit proxy^T splits; atomic layer-2 logits
__global__ __launch_bounds__(NTHR) void h1_k(
    const f16* __restrict__ M1h, const f16* __restrict__ M1l,
    const f16* __restrict__ W1th, const f16* __restrict__ W1tl,
    const float* __restrict__ b1,
    const float* __restrict__ v2s, const float* __restrict__ v2d,
    float* __restrict__ h1, f16* __restrict__ h1pth, f16* __restrict__ h1ptl,
    float* __restrict__ ls2, float* __restrict__ ld2)
{
  __shared__ __align__(16) f16 lds[10240];
  f32x4 acc[2][2] = {};
  const int t = threadIdx.x, lane = t & 63, w = t >> 6, wr = w >> 1, wc = w & 1;
  const int b = blockIdx.x;
  const int row0 = (b >> 3) * 64, col0 = (b & 7) * 64;
  mgemm_core(M1h, M1l, W1th, W1tl, DD, row0, col0, lds, acc);
  const int c0 = col0 + wc * 32 + (lane & 15);
  const int c1 = c0 + 16;
  const float vs0 = v2s[c0], vs1 = v2s[c1];
  const float vd0 = v2d[c0], vd1 = v2d[c1];
  const float bb0 = b1[c0],  bb1 = b1[c1];
#pragma unroll
  for (int m = 0; m < 2; ++m)
#pragma unroll
    for (int q = 0; q < 4; ++q) {
      const int r = row0 + wr * 32 + m * 16 + (lane >> 4) * 4 + q;
      if (r >= NN) continue;           // uniform within each 16-lane group
      float ps = 0.f, pd = 0.f;
#pragma unroll
      for (int n = 0; n < 2; ++n) {
        const int c = (n == 0) ? c0 : c1;
        const float v = fmaxf(acc[m][n][q] + (n == 0 ? bb0 : bb1), 0.f);
        h1[(size_t)r * DD + c] = v;
        ps += v * (n == 0 ? vs0 : vs1);
        pd += v * (n == 0 ? vd0 : vd1);
        if (r < 128) {                 // agg2 B operand: zero-fill k-pad rows
          const size_t o = (size_t)c * 128 + r;
          f16 hh = (f16)0.f, ll = (f16)0.f;
          if (r < PP) { hh = hif(v); ll = lof(v); }
          h1pth[o] = hh; h1ptl[o] = ll;
        }
      }
      // reduce the 16-lane group (same r) and accumulate layer-2 logits
#pragma unroll
      for (int off = 1; off < 16; off <<= 1) {
        ps += __shfl_xor(ps, off);
        pd += __shfl_xor(pd, off);
      }
      if ((lane & 15) == 0) {
        atomicAdd(&ls2[r], ps);
        atomicAdd(&ld2[r], pd);
      }
    }
}

// ===== K5: layer-2 aggregation (softmax fused; sample dsts only) ===========
__global__ __launch_bounds__(NTHR) void agg2x_k(
    const float* __restrict__ ls2, const float* __restrict__ ld2,
    const f16* __restrict__ h1pth, const f16* __restrict__ h1ptl,
    const float* __restrict__ h1,
    f16* __restrict__ M2h, f16* __restrict__ M2l)
{
  __shared__ __align__(16) f16 lds[10240];
  __shared__ float fred[384];
  const int b = blockIdx.x;
  const int row0 = (b >> 3) * 64, col0 = (b & 7) * 64;
  agg_core(ls2, PP, ld2 + PP, ls2 + PP, h1pth, h1ptl, 128, row0, col0, NS,
           h1 + (size_t)PP * DD, M2h, M2l, lds, fred);
}

// ===== K6: h2 = relu(M2@W2 + b2) -> d_out (fp32) + split for fc ============
__global__ __launch_bounds__(NTHR) void h2_k(
    const f16* __restrict__ M2h, const f16* __restrict__ M2l,
    const f16* __restrict__ W2th, const f16* __restrict__ W2tl,
    const float* __restrict__ b2, float* __restrict__ h2s,
    f16* __restrict__ h2h, f16* __restrict__ h2l)
{
  __shared__ __align__(16) f16 lds[10240];
  f32x4 acc[2][2] = {};
  const int t = threadIdx.x, lane = t & 63, w = t >> 6, wr = w >> 1, wc = w & 1;
  const int b = blockIdx.x;
  const int row0 = (b >> 3) * 64, col0 = (b & 7) * 64;
  mgemm_core(M2h, M2l, W2th, W2tl, DD, row0, col0, lds, acc);
#pragma unroll
  for (int m = 0; m < 2; ++m)
#pragma unroll
    for (int q = 0; q < 4; ++q) {
      const int r = row0 + wr * 32 + m * 16 + (lane >> 4) * 4 + q;
#pragma unroll
      for (int n = 0; n < 2; ++n) {
        const int c = col0 + wc * 32 + n * 16 + (lane & 15);
        const float v = fmaxf(acc[m][n][q] + b2[c], 0.f);
        const size_t o = (size_t)r * DD + c;
        h2s[o] = v;
        h2h[o] = hif(v); h2l[o] = lof(v);
      }
    }
}

// ===== K7: preds = h2 @ fcw + fcb ==========================================
__global__ __launch_bounds__(NTHR) void fc_k(
    const f16* __restrict__ h2h, const f16* __restrict__ h2l,
    const f16* __restrict__ fwth, const f16* __restrict__ fwtl,
    const float* __restrict__ fcb, float* __restrict__ out)
{
  __shared__ __align__(16) f16 lds[10240];
  f32x4 acc[2][2] = {};
  const int t = threadIdx.x, lane = t & 63, w = t >> 6, wr = w >> 1, wc = w & 1;
  const int b = blockIdx.x;
  const int row0 = (b >> 1) * 64, col0 = (b & 1) * 64;
  mgemm_core(h2h, h2l, fwth, fwtl, DD, row0, col0, lds, acc);
#pragma unroll
  for (int m = 0; m < 2; ++m)
#pragma unroll
    for (int q = 0; q < 4; ++q) {
      const int r = row0 + wr * 32 + m * 16 + (lane >> 4) * 4 + q;
#pragma unroll
      for (int n = 0; n < 2; ++n) {
        const int c = col0 + wc * 32 + n * 16 + (lane & 15);
        if (c < CC) out[(size_t)r * CC + c] = acc[m][n][q] + fcb[c];
      }
    }
}

extern "C" void kernel_launch(void* const* d_in, const int* in_sizes, int n_in,
                              void* d_out, int out_size, void* d_ws, size_t ws_size,
                              hipStream_t stream)
{
  const float* x    = (const float*)d_in[0];
  const float* prox = (const float*)d_in[1];
  const float* W1   = (const float*)d_in[2];
  const float* as1  = (const float*)d_in[3];
  const float* ad1  = (const float*)d_in[4];
  const float* b1   = (const float*)d_in[5];
  const float* W2   = (const float*)d_in[6];
  const float* as2  = (const float*)d_in[7];
  const float* ad2  = (const float*)d_in[8];
  const float* b2   = (const float*)d_in[9];
  const float* fcw  = (const float*)d_in[10];
  const float* fcb  = (const float*)d_in[11];
  float* out = (float*)d_out;

  // fp32 workspace
  float* F = (float*)d_ws;
  float* h1   = F; F += (size_t)NN * DD;
  float* ls1  = F; F += 1152;
  float* ld1  = F; F += 1152;
  float* ls2  = F; F += 1152;
  float* ld2  = F; F += 1152;
  float* v1s  = F; F += DD;
  float* v1d  = F; F += DD;
  float* v2s  = F; F += DD;
  float* v2d  = F; F += DD;
  // f16 split workspace (all bases 16B aligned; sizes multiples of 8 halves)
  f16* H = (f16*)F;
  f16* M1h  = H; H += (size_t)1152 * DD;   // rows: 100 prox + 1024 samp + pad
  f16* M1l  = H; H += (size_t)1152 * DD;
  f16* M2h  = H; H += (size_t)NS * DD;
  f16* M2l  = H; H += (size_t)NS * DD;
  f16* xth  = H; H += (size_t)DD * NS;     // x^T  [512][1024]
  f16* xtl  = H; H += (size_t)DD * NS;
  f16* pth  = H; H += (size_t)DD * 128;    // prox^T [512][128] (k-pad zeroed)
  f16* ptl  = H; H += (size_t)DD * 128;
  f16* W1th = H; H += (size_t)DD * DD;     // W1^T [512][512]
  f16* W1tl = H; H += (size_t)DD * DD;
  f16* W2th = H; H += (size_t)DD * DD;
  f16* W2tl = H; H += (size_t)DD * DD;
  f16* fwth = H; H += (size_t)128 * DD;    // fcw^T [128][512] (k-pad zeroed)
  f16* fwtl = H; H += (size_t)128 * DD;
  f16* h2h  = H; H += (size_t)NS * DD;
  f16* h2l  = H; H += (size_t)NS * DD;
  f16* h1pth = H; H += (size_t)DD * 128;   // h1 proxy rows ^T [512][128]
  f16* h1ptl = H; H += (size_t)DD * 128;
  float* h2s = out + (size_t)NS * CC;      // layer-2 sample out in d_out

  dim3 blk(NTHR);
  // K1: weight matvecs + zero ls2/ld2 accumulators
  prep1_k<<<dim3(257), blk, 0, stream>>>(W1, W2, as1, ad1, as2, ad2,
                                         v1s, v1d, v2s, v2d, ls2, ld2);
  // K2: transposes/splits + layer-1 logits
  prep2_k<<<dim3(569), blk, 0, stream>>>(x, prox, W1, W2, fcw, v1s, v1d,
      xth, xtl, pth, ptl, W1th, W1tl, W2th, W2tl, fwth, fwtl, ls1, ld1);
  // K3: layer-1 aggregation (softmax fused) -> M1 splits
  agg1x_k<<<dim3(144), blk, 0, stream>>>(ls1, ld1, pth, ptl, xth, xtl,
                                         x, prox, M1h, M1l);
  // K4: h1 = relu(M1@W1+b1) + proxy^T splits + atomic layer-2 logits
  h1_k<<<dim3(144), blk, 0, stream>>>(M1h, M1l, W1th, W1tl, b1, v2s, v2d,
                                      h1, h1pth, h1ptl, ls2, ld2);
  // K5: layer-2 aggregation (softmax fused) -> M2 splits
  agg2x_k<<<dim3(128), blk, 0, stream>>>(ls2, ld2, h1pth, h1ptl, h1, M2h, M2l);
  // K6: h2 = relu(M2@W2+b2) -> d_out (+ split)
  h2_k<<<dim3(128), blk, 0, stream>>>(M2h, M2l, W2th, W2tl, b2, h2s, h2h, h2l);
  // K7: preds = h2 @ fcw + fcb
  fc_k<<<dim3(32), blk, 0, stream>>>(h2h, h2l, fwth, fwtl, fcb, out);
}

// Round 7
// 157.247 us; speedup vs baseline: 3.6979x; 1.1328x over previous
//
#include <hip/hip_runtime.h>

// Problem constants (complete bipartite proxy<->sample + self-loops)
#define PP 100    // proxies
#define NS 1024   // samples
#define NN 1124   // total nodes
#define DD 512    // feature dim
#define CC 100    // fc out dim
#define NTHR 256

typedef _Float16 f16;
typedef _Float16 f16x8 __attribute__((ext_vector_type(8)));
typedef float    f32x4 __attribute__((ext_vector_type(4)));

__device__ __forceinline__ float lk(float v) { return v > 0.f ? v : 0.2f * v; }
__device__ __forceinline__ f16 hif(float v) { return (f16)v; }
__device__ __forceinline__ f16 lof(float v) { return (f16)(v - (float)((f16)v)); }

// =================== MFMA split-f16 GEMM core =============================
// acc[2][2] += A[row0.., K] @ B ; A = (Ah,Al) row-major [*,K], B TRANSPOSED
// as (Bth,Btl) row-major [*,K] (row = output col). 64x64 tile, 4 waves of
// 32x32, BK=32. C = Ah*Bh + Al*Bh + Ah*Bl (fp32 acc; al*bl dropped).
__device__ __forceinline__ void mgemm_core(
    const f16* __restrict__ Ah, const f16* __restrict__ Al,
    const f16* __restrict__ Bth, const f16* __restrict__ Btl,
    int K, int row0, int col0, f16* __restrict__ lds, f32x4 acc[2][2])
{
  const int t = threadIdx.x;
  const int lane = t & 63, w = t >> 6;
  const int wr = w >> 1, wc = w & 1;
  f16* Ash = lds;
  f16* Asl = lds + 2560;
  f16* Bsh = lds + 5120;
  f16* Bsl = lds + 7680;
  const int srow = t >> 2, su = t & 3;
  const size_t aoff = (size_t)(row0 + srow) * K + su * 8;
  const size_t boff = (size_t)(col0 + srow) * K + su * 8;
  const int lw = srow * 40 + su * 8;
  f32x4 pa0 = *(const f32x4*)(Ah + aoff);
  f32x4 pa1 = *(const f32x4*)(Al + aoff);
  f32x4 pb0 = *(const f32x4*)(Bth + boff);
  f32x4 pb1 = *(const f32x4*)(Btl + boff);
  const int fra = wr * 32 + (lane & 15);
  const int frb = wc * 32 + (lane & 15);
  const int fu  = (lane >> 4) * 8;
  for (int kt = 32; kt <= K; kt += 32) {
    *(f32x4*)(Ash + lw) = pa0;
    *(f32x4*)(Asl + lw) = pa1;
    *(f32x4*)(Bsh + lw) = pb0;
    *(f32x4*)(Bsl + lw) = pb1;
    __syncthreads();
    if (kt < K) {
      pa0 = *(const f32x4*)(Ah + aoff + kt);
      pa1 = *(const f32x4*)(Al + aoff + kt);
      pb0 = *(const f32x4*)(Bth + boff + kt);
      pb1 = *(const f32x4*)(Btl + boff + kt);
    }
    f16x8 ah[2], al[2], bh[2], bl[2];
#pragma unroll
    for (int m = 0; m < 2; ++m) {
      ah[m] = *(const f16x8*)(Ash + (fra + m * 16) * 40 + fu);
      al[m] = *(const f16x8*)(Asl + (fra + m * 16) * 40 + fu);
    }
#pragma unroll
    for (int n = 0; n < 2; ++n) {
      bh[n] = *(const f16x8*)(Bsh + (frb + n * 16) * 40 + fu);
      bl[n] = *(const f16x8*)(Bsl + (frb + n * 16) * 40 + fu);
    }
#pragma unroll
    for (int m = 0; m < 2; ++m)
#pragma unroll
      for (int n = 0; n < 2; ++n) {
        acc[m][n] = __builtin_amdgcn_mfma_f32_16x16x32_f16(ah[m], bh[n], acc[m][n], 0, 0, 0);
        acc[m][n] = __builtin_amdgcn_mfma_f32_16x16x32_f16(al[m], bh[n], acc[m][n], 0, 0, 0);
        acc[m][n] = __builtin_amdgcn_mfma_f32_16x16x32_f16(ah[m], bl[n], acc[m][n], 0, 0, 0);
      }
    __syncthreads();
  }
}

// ============ fused softmax+aggregation GEMM (SHORT-K sides only) ==========
// A[r][k] = exp(lk(lsrc[k] + ld_r) - m_r) computed inline during staging
// (k >= kvalid or invalid row -> 0). m_r = lk(max(smax, ls_self_r) + ld_r)
// via monotonicity of leaky_relu. Per-row denominator z accumulated during
// staging; epilogue: out = (acc + es*self)*iz, split f16 write.
__device__ __forceinline__ void agg_core(
    const float* __restrict__ lsrc, int kvalid,
    const float* __restrict__ ldb, const float* __restrict__ lsb,
    const f16* __restrict__ Bth, const f16* __restrict__ Btl,
    int K, int row0, int col0, int rvalid,
    const float* __restrict__ selfv,
    f16* __restrict__ outh, f16* __restrict__ outl,
    f16* __restrict__ lds, float* __restrict__ fred)
{
  const int t = threadIdx.x, lane = t & 63, w = t >> 6;
  const int wr = w >> 1, wc = w & 1;
  f16* Ash = lds;
  f16* Asl = lds + 2560;
  f16* Bsh = lds + 5120;
  f16* Bsl = lds + 7680;
  float* zred = fred;          // [256]
  float* res  = fred + 256;    // [64] self exps
  float* riz  = fred + 320;    // [64] 1/denominator
  const int srow = t >> 2, su = t & 3;
  // block-uniform max over lsrc[0..kvalid)
  float sm = -1e30f;
  for (int k = t; k < kvalid; k += NTHR) sm = fmaxf(sm, lsrc[k]);
#pragma unroll
  for (int off = 1; off < 64; off <<= 1) sm = fmaxf(sm, __shfl_xor(sm, off));
  if (lane == 0) zred[w] = sm;
  __syncthreads();
  sm = fmaxf(fmaxf(zred[0], zred[1]), fmaxf(zred[2], zred[3]));
  __syncthreads();
  // per staging-row constants
  const bool rok = (row0 + srow) < rvalid;
  float ldr = 0.f, mr = 0.f;
  if (rok) {
    ldr = ldb[row0 + srow];
    mr  = lk(fmaxf(sm, lsb[row0 + srow]) + ldr);
  }
  const size_t boff = (size_t)(col0 + srow) * K + su * 8;
  const int lw = srow * 40 + su * 8;
  f32x4 pb0 = *(const f32x4*)(Bth + boff);
  f32x4 pb1 = *(const f32x4*)(Btl + boff);
  const int fra = wr * 32 + (lane & 15);
  const int frb = wc * 32 + (lane & 15);
  const int fu  = (lane >> 4) * 8;
  f32x4 acc[2][2] = {};
  float zacc = 0.f;
  for (int kt = 32; kt <= K; kt += 32) {
    f16x8 ae, al8;
    const int k0 = kt - 32 + su * 8;
#pragma unroll
    for (int j = 0; j < 8; ++j) {
      const int k = k0 + j;
      float f = 0.f;
      if (rok && k < kvalid) f = __expf(lk(lsrc[k] + ldr) - mr);
      zacc += f;
      ae[j]  = hif(f);
      al8[j] = lof(f);
    }
    *(f16x8*)(Ash + lw) = ae;
    *(f16x8*)(Asl + lw) = al8;
    *(f32x4*)(Bsh + lw) = pb0;
    *(f32x4*)(Bsl + lw) = pb1;
    __syncthreads();
    if (kt < K) {
      pb0 = *(const f32x4*)(Bth + boff + kt);
      pb1 = *(const f32x4*)(Btl + boff + kt);
    }
    f16x8 ah[2], alr[2], bh[2], bl[2];
#pragma unroll
    for (int m = 0; m < 2; ++m) {
      ah[m]  = *(const f16x8*)(Ash + (fra + m * 16) * 40 + fu);
      alr[m] = *(const f16x8*)(Asl + (fra + m * 16) * 40 + fu);
    }
#pragma unroll
    for (int n = 0; n < 2; ++n) {
      bh[n] = *(const f16x8*)(Bsh + (frb + n * 16) * 40 + fu);
      bl[n] = *(const f16x8*)(Bsl + (frb + n * 16) * 40 + fu);
    }
#pragma unroll
    for (int m = 0; m < 2; ++m)
#pragma unroll
      for (int n = 0; n < 2; ++n) {
        acc[m][n] = __builtin_amdgcn_mfma_f32_16x16x32_f16(ah[m],  bh[n], acc[m][n], 0, 0, 0);
        acc[m][n] = __builtin_amdgcn_mfma_f32_16x16x32_f16(alr[m], bh[n], acc[m][n], 0, 0, 0);
        acc[m][n] = __builtin_amdgcn_mfma_f32_16x16x32_f16(ah[m],  bl[n], acc[m][n], 0, 0, 0);
      }
    __syncthreads();
  }
  // per-row denominator, self exp, inverse
  zred[t] = zacc;
  __syncthreads();
  if (t < 64) {
    float z = zred[t * 4] + zred[t * 4 + 1] + zred[t * 4 + 2] + zred[t * 4 + 3];
    float es = 0.f, iz = 0.f;
    if (row0 + t < rvalid) {
      const float l2 = ldb[row0 + t], s2 = lsb[row0 + t];
      const float m2 = lk(fmaxf(sm, s2) + l2);
      es = __expf(lk(s2 + l2) - m2);
      iz = 1.f / (z + es);
    }
    res[t] = es; riz[t] = iz;
  }
  __syncthreads();
  // epilogue
#pragma unroll
  for (int m = 0; m < 2; ++m)
#pragma unroll
    for (int q = 0; q < 4; ++q) {
      const int rl = wr * 32 + m * 16 + (lane >> 4) * 4 + q;
      const int gr = row0 + rl;
      if (gr >= rvalid) continue;
      const float es = res[rl], iz = riz[rl];
#pragma unroll
      for (int n = 0; n < 2; ++n) {
        const int c = col0 + wc * 32 + n * 16 + (lane & 15);
        const float v = (acc[m][n][q] + es * selfv[(size_t)gr * DD + c]) * iz;
        outh[(size_t)gr * DD + c] = hif(v);
        outl[(size_t)gr * DD + c] = lof(v);
      }
    }
}

// ======== 64x64 transpose+split tile (fp32 in -> f16 hi/lo transposed) =====
__device__ __forceinline__ void cvt_tile(
    const float* __restrict__ in, int R, int Cin,
    f16* __restrict__ oh, f16* __restrict__ ol, int ldo,
    int ti, int tj, f16 (*th)[72], f16 (*tl)[72])
{
  const int t = threadIdx.x;
#pragma unroll
  for (int p = 0; p < 4; ++p) {
    const int f = t + p * 256;
    const int i = f >> 4, j4 = (f & 15) * 4;
    const int gi = ti * 64 + i, gj = tj * 64 + j4;
    float4 v = make_float4(0.f, 0.f, 0.f, 0.f);
    if (gi < R && gj + 3 < Cin) v = *(const float4*)(in + (size_t)gi * Cin + gj);
    th[i][j4 + 0] = hif(v.x); tl[i][j4 + 0] = lof(v.x);
    th[i][j4 + 1] = hif(v.y); tl[i][j4 + 1] = lof(v.y);
    th[i][j4 + 2] = hif(v.z); tl[i][j4 + 2] = lof(v.z);
    th[i][j4 + 3] = hif(v.w); tl[i][j4 + 3] = lof(v.w);
  }
  __syncthreads();
#pragma unroll
  for (int p = 0; p < 2; ++p) {
    const int f = t + p * 256;
    const int j = f >> 3, i8 = (f & 7) * 8;
    f16x8 vh, vl;
#pragma unroll
    for (int e = 0; e < 8; ++e) { vh[e] = th[i8 + e][j]; vl[e] = tl[i8 + e][j]; }
    const size_t o = (size_t)(tj * 64 + j) * ldo + ti * 64 + i8;
    *(f16x8*)(oh + o) = vh;
    *(f16x8*)(ol + o) = vl;
  }
}

// ===== K1: weight matvecs (v = W@a, both layers) + zero ls2/ld2 ============
__global__ __launch_bounds__(NTHR) void prep1_k(
    const float* __restrict__ W1, const float* __restrict__ W2,
    const float* __restrict__ as1, const float* __restrict__ ad1,
    const float* __restrict__ as2, const float* __restrict__ ad2,
    float* __restrict__ v1s, float* __restrict__ v1d,
    float* __restrict__ v2s, float* __restrict__ v2d,
    float* __restrict__ ls2, float* __restrict__ ld2)
{
  const int u = blockIdx.x;
  if (u < 256) {
    const int wid  = u * 4 + (threadIdx.x >> 6);   // 0..1023
    const int lane = threadIdx.x & 63;
    const int r = wid & 511;
    const bool l1 = (wid < 512);
    const float* W = l1 ? W1 : W2;
    const float4* a4 = (const float4*)(l1 ? as1 : as2);
    const float4* b4 = (const float4*)(l1 ? ad1 : ad2);
    const float4* w4 = (const float4*)(W + (size_t)r * DD);
    float4 w0 = w4[lane], w1 = w4[lane + 64];
    float4 a0 = a4[lane], a1 = a4[lane + 64];
    float4 b0 = b4[lane], b1 = b4[lane + 64];
    float s1 = w0.x * a0.x + w0.y * a0.y + w0.z * a0.z + w0.w * a0.w
             + w1.x * a1.x + w1.y * a1.y + w1.z * a1.z + w1.w * a1.w;
    float s2 = w0.x * b0.x + w0.y * b0.y + w0.z * b0.z + w0.w * b0.w
             + w1.x * b1.x + w1.y * b1.y + w1.z * b1.z + w1.w * b1.w;
#pragma unroll
    for (int off = 32; off > 0; off >>= 1) {
      s1 += __shfl_down(s1, off);
      s2 += __shfl_down(s2, off);
    }
    if (lane == 0) {
      (l1 ? v1s : v2s)[r] = s1;
      (l1 ? v1d : v2d)[r] = s2;
    }
  } else {
    for (int i = threadIdx.x; i < 1152; i += NTHR) { ls2[i] = 0.f; ld2[i] = 0.f; }
  }
}

// ===== K2: transposes/splits + layer-1 logits (needs v1 from K1) ==========
__global__ __launch_bounds__(NTHR) void prep2_k(
    const float* __restrict__ x, const float* __restrict__ prox,
    const float* __restrict__ W1, const float* __restrict__ W2,
    const float* __restrict__ fcw,
    const float* __restrict__ v1s, const float* __restrict__ v1d,
    f16* xth, f16* xtl, f16* pth, f16* ptl,
    f16* W1th, f16* W1tl, f16* W2th, f16* W2tl, f16* fwth, f16* fwtl,
    float* __restrict__ ls1, float* __restrict__ ld1)
{
  __shared__ f16 th[64][72];
  __shared__ f16 tl[64][72];
  const int b = blockIdx.x;
  if (b < 64) {
    cvt_tile(W1, 512, 512, W1th, W1tl, 512, b >> 3, b & 7, th, tl);
  } else if (b < 128) {
    cvt_tile(W2, 512, 512, W2th, W2tl, 512, (b - 64) >> 3, (b - 64) & 7, th, tl);
  } else if (b < 256) {
    cvt_tile(x, NS, 512, xth, xtl, NS, (b - 128) >> 3, (b - 128) & 7, th, tl);
  } else if (b < 272) {
    cvt_tile(prox, PP, 512, pth, ptl, 128, (b - 256) >> 3, (b - 256) & 7, th, tl);
  } else if (b < 288) {
    cvt_tile(fcw, 512, CC, fwth, fwtl, 512, (b - 272) >> 1, (b - 272) & 1, th, tl);
  } else {
    // layer-1 logits: one wave per node row
    const int r    = (b - 288) * 4 + (threadIdx.x >> 6);
    const int lane = threadIdx.x & 63;
    if (r >= NN) return;
    const float* row = (r < PP) ? prox + (size_t)r * DD
                                : x + (size_t)(r - PP) * DD;
    const float4* r4 = (const float4*)row;
    const float4* s4 = (const float4*)v1s;
    const float4* d4 = (const float4*)v1d;
    float4 v0 = r4[lane], v1 = r4[lane + 64];
    float4 a0 = s4[lane], a1 = s4[lane + 64];
    float4 b0 = d4[lane], b1 = d4[lane + 64];
    float s1 = v0.x * a0.x + v0.y * a0.y + v0.z * a0.z + v0.w * a0.w
             + v1.x * a1.x + v1.y * a1.y + v1.z * a1.z + v1.w * a1.w;
    float s2 = v0.x * b0.x + v0.y * b0.y + v0.z * b0.z + v0.w * b0.w
             + v1.x * b1.x + v1.y * b1.y + v1.z * b1.z + v1.w * b1.w;
#pragma unroll
    for (int off = 32; off > 0; off >>= 1) {
      s1 += __shfl_down(s1, off);
      s2 += __shfl_down(s2, off);
    }
    if (lane == 0) { ls1[r] = s1; ld1[r] = s2; }
  }
}

// ===== K3: proxy softmax weights -> split f16 Ep + esP/izP =================
// block i in [0,128): proxy dst i; i >= PP rows zero-fill the Ep k-pad.
__global__ __launch_bounds__(NTHR) void ep_k(
    const float* __restrict__ ls, const float* __restrict__ ld,
    f16* __restrict__ Eph, f16* __restrict__ Epl,
    float* __restrict__ esP, float* __restrict__ izP)
{
  const int t = threadIdx.x;
  const int i = blockIdx.x;
  if (i >= PP) {                               // zero-fill pad rows 100..127
#pragma unroll
    for (int q = 0; q < 4; ++q) {
      Eph[(size_t)i * NS + t + q * 256] = (f16)0.f;
      Epl[(size_t)i * NS + t + q * 256] = (f16)0.f;
    }
    return;
  }
  __shared__ float red[4];
  const float ldi = ld[i];
  const float eself = lk(ls[i] + ldi);
  float e[4];
#pragma unroll
  for (int q = 0; q < 4; ++q) e[q] = lk(ls[PP + t + q * 256] + ldi);
  float m = fmaxf(fmaxf(fmaxf(e[0], e[1]), fmaxf(e[2], e[3])), eself);
#pragma unroll
  for (int off = 1; off < 64; off <<= 1) m = fmaxf(m, __shfl_xor(m, off));
  if ((t & 63) == 0) red[t >> 6] = m;
  __syncthreads();
  m = fmaxf(fmaxf(red[0], red[1]), fmaxf(red[2], red[3]));
  __syncthreads();
  float xq[4], z = 0.f;
#pragma unroll
  for (int q = 0; q < 4; ++q) { xq[q] = __expf(e[q] - m); z += xq[q]; }
#pragma unroll
  for (int off = 1; off < 64; off <<= 1) z += __shfl_xor(z, off);
  if ((t & 63) == 0) red[t >> 6] = z;
  __syncthreads();
#pragma unroll
  for (int q = 0; q < 4; ++q) {
    Eph[(size_t)i * NS + t + q * 256] = hif(xq[q]);
    Epl[(size_t)i * NS + t + q * 256] = lof(xq[q]);
  }
  if (t == 0) {
    float xs = __expf(eself - m);
    esP[i] = xs;
    izP[i] = 1.f / (red[0] + red[1] + red[2] + red[3] + xs);
  }
}

// ===== K4: layer-1 aggregation: [0,128) samples (fused SM), [128,144) proxy
__global__ __launch_bounds__(NTHR) void agg1x_k(
    const float* __restrict__ ls1, const float* __restrict__ ld1,
    const f16* __restrict__ pth, const f16* __restrict__ ptl,
    const f16* __restrict__ Eph, const f16* __restrict__ Epl,
    const f16* __restrict__ xth, const f16* __restrict__ xtl,
    const float* __restrict__ x, const float* __restrict__ prox,
    const float* __restrict__ esP, const float* __restrict__ izP,
    f16* __restrict__ M1h, f16* __restrict__ M1l)
{
  __shared__ __align__(16) f16 lds[10240];
  __shared__ float fred[384];
  const int b = blockIdx.x;
  if (b < 128) {
    // M1_samp = softmax_rows(exp over 100 proxies) @ prox^T, self = x
    const int row0 = (b >> 3) * 64, col0 = (b & 7) * 64;
    agg_core(ls1, PP, ld1 + PP, ls1 + PP, pth, ptl, 128, row0, col0, NS,
             x, M1h + (size_t)PP * DD, M1l + (size_t)PP * DD, lds, fred);
  } else {
    // M1_prox[100,512] = Ep[100(pad128),1024] @ x, epi self = prox
    f32x4 acc[2][2] = {};
    const int t = threadIdx.x, lane = t & 63, w = t >> 6, wr = w >> 1, wc = w & 1;
    const int b2 = b - 128;
    const int row0 = (b2 >> 3) * 64, col0 = (b2 & 7) * 64;
    mgemm_core(Eph, Epl, xth, xtl, NS, row0, col0, lds, acc);
#pragma unroll
    for (int m = 0; m < 2; ++m)
#pragma unroll
      for (int q = 0; q < 4; ++q) {
        const int r = row0 + wr * 32 + m * 16 + (lane >> 4) * 4 + q;
        if (r < PP) {
          const float e = esP[r], z = izP[r];
#pragma unroll
          for (int n = 0; n < 2; ++n) {
            const int c = col0 + wc * 32 + n * 16 + (lane & 15);
            const float v = (acc[m][n][q] + e * prox[(size_t)r * DD + c]) * z;
            const size_t o = (size_t)r * DD + c;
            M1h[o] = hif(v); M1l[o] = lof(v);
          }
        }
      }
  }
}

// ===== K5: h1 = relu(M1@W1 + b1); emit proxy^T splits; atomic layer-2 logits
__global__ __launch_bounds__(NTHR) void h1_k(
    const f16* __restrict__ M1h, const f16* __restrict__ M1l,
    const f16* __restrict__ W1th, const f16* __restrict__ W1tl,
    const float* __restrict__ b1,
    const float* __restrict__ v2s, const float* __restrict__ v2d,
    float* __restrict__ h1, f16* __restrict__ h1pth, f16* __restrict__ h1ptl,
    float* __restrict__ ls2, float* __restrict__ ld2)
{
  __shared__ __align__(16) f16 lds[10240];
  f32x4 acc[2][2] = {};
  const int t = threadIdx.x, lane = t & 63, w = t >> 6, wr = w >> 1, wc = w & 1;
  const int b = blockIdx.x;
  const int row0 = (b >> 3) * 64, col0 = (b & 7) * 64;
  mgemm_core(M1h, M1l, W1th, W1tl, DD, row0, col0, lds, acc);
  const int c0 = col0 + wc * 32 + (lane & 15);
  const int c1 = c0 + 16;
  const float vs0 = v2s[c0], vs1 = v2s[c1];
  const float vd0 = v2d[c0], vd1 = v2d[c1];
  const float bb0 = b1[c0],  bb1 = b1[c1];
#pragma unroll
  for (int m = 0; m < 2; ++m)
#pragma unroll
    for (int q = 0; q < 4; ++q) {
      const int r = row0 + wr * 32 + m * 16 + (lane >> 4) * 4 + q;
      if (r >= NN) continue;           // uniform within each 16-lane group
      float ps = 0.f, pd = 0.f;
#pragma unroll
      for (int n = 0; n < 2; ++n) {
        const int c = (n == 0) ? c0 : c1;
        const float v = fmaxf(acc[m][n][q] + (n == 0 ? bb0 : bb1), 0.f);
        h1[(size_t)r * DD + c] = v;
        ps += v * (n == 0 ? vs0 : vs1);
        pd += v * (n == 0 ? vd0 : vd1);
        if (r < 128) {                 // agg2 B operand: zero-fill k-pad rows
          const size_t o = (size_t)c * 128 + r;
          f16 hh = (f16)0.f, ll = (f16)0.f;
          if (r < PP) { hh = hif(v); ll = lof(v); }
          h1pth[o] = hh; h1ptl[o] = ll;
        }
      }
      // reduce the 16-lane group (same r) and accumulate layer-2 logits
#pragma unroll
      for (int off = 1; off < 16; off <<= 1) {
        ps += __shfl_xor(ps, off);
        pd += __shfl_xor(pd, off);
      }
      if ((lane & 15) == 0) {
        atomicAdd(&ls2[r], ps);
        atomicAdd(&ld2[r], pd);
      }
    }
}

// ===== K6: layer-2 aggregation (softmax fused; sample dsts only) ===========
__global__ __launch_bounds__(NTHR) void agg2x_k(
    const float* __restrict__ ls2, const float* __restrict__ ld2,
    const f16* __restrict__ h1pth, const f16* __restrict__ h1ptl,
    const float* __restrict__ h1,
    f16* __restrict__ M2h, f16* __restrict__ M2l)
{
  __shared__ __align__(16) f16 lds[10240];
  __shared__ float fred[384];
  const int b = blockIdx.x;
  const int row0 = (b >> 3) * 64, col0 = (b & 7) * 64;
  agg_core(ls2, PP, ld2 + PP, ls2 + PP, h1pth, h1ptl, 128, row0, col0, NS,
           h1 + (size_t)PP * DD, M2h, M2l, lds, fred);
}

// ===== K7: h2 = relu(M2@W2 + b2) -> d_out (fp32) + split for fc ============
__global__ __launch_bounds__(NTHR) void h2_k(
    const f16* __restrict__ M2h, const f16* __restrict__ M2l,
    const f16* __restrict__ W2th, const f16* __restrict__ W2tl,
    const float* __restrict__ b2, float* __restrict__ h2s,
    f16* __restrict__ h2h, f16* __restrict__ h2l)
{
  __shared__ __align__(16) f16 lds[10240];
  f32x4 acc[2][2] = {};
  const int t = threadIdx.x, lane = t & 63, w = t >> 6, wr = w >> 1, wc = w & 1;
  const int b = blockIdx.x;
  const int row0 = (b >> 3) * 64, col0 = (b & 7) * 64;
  mgemm_core(M2h, M2l, W2th, W2tl, DD, row0, col0, lds, acc);
#pragma unroll
  for (int m = 0; m < 2; ++m)
#pragma unroll
    for (int q = 0; q < 4; ++q) {
      const int r = row0 + wr * 32 + m * 16 + (lane >> 4) * 4 + q;
#pragma unroll
      for (int n = 0; n < 2; ++n) {
        const int c = col0 + wc * 32 + n * 16 + (lane & 15);
        const float v = fmaxf(acc[m][n][q] + b2[c], 0.f);
        const size_t o = (size_t)r * DD + c;
        h2s[o] = v;
        h2h[o] = hif(v); h2l[o] = lof(v);
      }
    }
}

// ===== K8: preds = h2 @ fcw + fcb ==========================================
__global__ __launch_bounds__(NTHR) void fc_k(
    const f16* __restrict__ h2h, const f16* __restrict__ h2l,
    const f16* __restrict__ fwth, const f16* __restrict__ fwtl,
    const float* __restrict__ fcb, float* __restrict__ out)
{
  __shared__ __align__(16) f16 lds[10240];
  f32x4 acc[2][2] = {};
  const int t = threadIdx.x, lane = t & 63, w = t >> 6, wr = w >> 1, wc = w & 1;
  const int b = blockIdx.x;
  const int row0 = (b >> 1) * 64, col0 = (b & 1) * 64;
  mgemm_core(h2h, h2l, fwth, fwtl, DD, row0, col0, lds, acc);
#pragma unroll
  for (int m = 0; m < 2; ++m)
#pragma unroll
    for (int q = 0; q < 4; ++q) {
      const int r = row0 + wr * 32 + m * 16 + (lane >> 4) * 4 + q;
#pragma unroll
      for (int n = 0; n < 2; ++n) {
        const int c = col0 + wc * 32 + n * 16 + (lane & 15);
        if (c < CC) out[(size_t)r * CC + c] = acc[m][n][q] + fcb[c];
      }
    }
}

extern "C" void kernel_launch(void* const* d_in, const int* in_sizes, int n_in,
                              void* d_out, int out_size, void* d_ws, size_t ws_size,
                              hipStream_t stream)
{
  const float* x    = (const float*)d_in[0];
  const float* prox = (const float*)d_in[1];
  const float* W1   = (const float*)d_in[2];
  const float* as1  = (const float*)d_in[3];
  const float* ad1  = (const float*)d_in[4];
  const float* b1   = (const float*)d_in[5];
  const float* W2   = (const float*)d_in[6];
  const float* as2  = (const float*)d_in[7];
  const float* ad2  = (const float*)d_in[8];
  const float* b2   = (const float*)d_in[9];
  const float* fcw  = (const float*)d_in[10];
  const float* fcb  = (const float*)d_in[11];
  float* out = (float*)d_out;

  // fp32 workspace
  float* F = (float*)d_ws;
  float* h1   = F; F += (size_t)NN * DD;
  float* ls1  = F; F += 1152;
  float* ld1  = F; F += 1152;
  float* ls2  = F; F += 1152;
  float* ld2  = F; F += 1152;
  float* v1s  = F; F += DD;
  float* v1d  = F; F += DD;
  float* v2s  = F; F += DD;
  float* v2d  = F; F += DD;
  float* esP  = F; F += 128;
  float* izP  = F; F += 128;
  // f16 split workspace (all bases 16B aligned; sizes multiples of 8 halves)
  f16* H = (f16*)F;
  f16* M1h  = H; H += (size_t)1152 * DD;   // rows: 100 prox + 1024 samp + pad
  f16* M1l  = H; H += (size_t)1152 * DD;
  f16* M2h  = H; H += (size_t)NS * DD;
  f16* M2l  = H; H += (size_t)NS * DD;
  f16* Eph  = H; H += (size_t)128 * NS;    // proxy exps [128][1024] (pad 0)
  f16* Epl  = H; H += (size_t)128 * NS;
  f16* xth  = H; H += (size_t)DD * NS;     // x^T  [512][1024]
  f16* xtl  = H; H += (size_t)DD * NS;
  f16* pth  = H; H += (size_t)DD * 128;    // prox^T [512][128] (k-pad zeroed)
  f16* ptl  = H; H += (size_t)DD * 128;
  f16* W1th = H; H += (size_t)DD * DD;     // W1^T [512][512]
  f16* W1tl = H; H += (size_t)DD * DD;
  f16* W2th = H; H += (size_t)DD * DD;
  f16* W2tl = H; H += (size_t)DD * DD;
  f16* fwth = H; H += (size_t)128 * DD;    // fcw^T [128][512] (k-pad zeroed)
  f16* fwtl = H; H += (size_t)128 * DD;
  f16* h2h  = H; H += (size_t)NS * DD;
  f16* h2l  = H; H += (size_t)NS * DD;
  f16* h1pth = H; H += (size_t)DD * 128;   // h1 proxy rows ^T [512][128]
  f16* h1ptl = H; H += (size_t)DD * 128;
  float* h2s = out + (size_t)NS * CC;      // layer-2 sample out in d_out

  dim3 blk(NTHR);
  // K1: weight matvecs + zero ls2/ld2 accumulators
  prep1_k<<<dim3(257), blk, 0, stream>>>(W1, W2, as1, ad1, as2, ad2,
                                         v1s, v1d, v2s, v2d, ls2, ld2);
  // K2: transposes/splits + layer-1 logits
  prep2_k<<<dim3(569), blk, 0, stream>>>(x, prox, W1, W2, fcw, v1s, v1d,
      xth, xtl, pth, ptl, W1th, W1tl, W2th, W2tl, fwth, fwtl, ls1, ld1);
  // K3: proxy softmax exps (split) + esP/izP
  ep_k<<<dim3(128), blk, 0, stream>>>(ls1, ld1, Eph, Epl, esP, izP);
  // K4: layer-1 aggregation -> M1 splits
  agg1x_k<<<dim3(144), blk, 0, stream>>>(ls1, ld1, pth, ptl, Eph, Epl,
                                         xth, xtl, x, prox, esP, izP, M1h, M1l);
  // K5: h1 = relu(M1@W1+b1) + proxy^T splits + atomic layer-2 logits
  h1_k<<<dim3(144), blk, 0, stream>>>(M1h, M1l, W1th, W1tl, b1, v2s, v2d,
                                      h1, h1pth, h1ptl, ls2, ld2);
  // K6: layer-2 aggregation (softmax fused) -> M2 splits
  agg2x_k<<<dim3(128), blk, 0, stream>>>(ls2, ld2, h1pth, h1ptl, h1, M2h, M2l);
  // K7: h2 = relu(M2@W2+b2) -> d_out (+ split)
  h2_k<<<dim3(128), blk, 0, stream>>>(M2h, M2l, W2th, W2tl, b2, h2s, h2h, h2l);
  // K8: preds = h2 @ fcw + fcb
  fc_k<<<dim3(32), blk, 0, stream>>>(h2h, h2l, fwth, fwtl, fcb, out);
}

// Round 8
// 152.485 us; speedup vs baseline: 3.8134x; 1.0312x over previous
//
#include <hip/hip_runtime.h>

// Problem constants (complete bipartite proxy<->sample + self-loops)
#define PP 100    // proxies
#define NS 1024   // samples
#define NN 1124   // total nodes
#define DD 512    // feature dim
#define CC 100    // fc out dim
#define NTHR 256

typedef _Float16 f16;
typedef _Float16 f16x8 __attribute__((ext_vector_type(8)));
typedef float    f32x4 __attribute__((ext_vector_type(4)));

__device__ __forceinline__ float lk(float v) { return v > 0.f ? v : 0.2f * v; }
__device__ __forceinline__ f16 hif(float v) { return (f16)v; }
__device__ __forceinline__ f16 lof(float v) { return (f16)(v - (float)((f16)v)); }

// LDS buffer layout (halves): buf k at lds + k*10240;
// sections within buf: Ash=0, Asl=2560, Bsh=5120, Bsl=7680 (rows of 40)

// =================== MFMA split-f16 GEMM core (double-buffered) ===========
// acc[2][2] += A[row0.., K] @ B ; A = (Ah,Al) row-major [*,K], B TRANSPOSED
// as (Bth,Btl) row-major [*,K] (row = output col). 64x64 tile, 4 waves of
// 32x32, BK=32. C = Ah*Bh + Al*Bh + Ah*Bl (fp32 acc; al*bl dropped).
// One __syncthreads per K-step: iteration i reads buf[i&1], writes next
// chunk to buf[(i+1)&1] (safe: that buf was last read before prev barrier).
__device__ __forceinline__ void mgemm_core(
    const f16* __restrict__ Ah, const f16* __restrict__ Al,
    const f16* __restrict__ Bth, const f16* __restrict__ Btl,
    int K, int row0, int col0, f16* __restrict__ lds, f32x4 acc[2][2])
{
  const int t = threadIdx.x;
  const int lane = t & 63, w = t >> 6;
  const int wr = w >> 1, wc = w & 1;
  const int srow = t >> 2, su = t & 3;
  const size_t aoff = (size_t)(row0 + srow) * K + su * 8;
  const size_t boff = (size_t)(col0 + srow) * K + su * 8;
  const int lw = srow * 40 + su * 8;
  const int fra = wr * 32 + (lane & 15);
  const int frb = wc * 32 + (lane & 15);
  const int fu  = (lane >> 4) * 8;
  f32x4 pa0 = *(const f32x4*)(Ah + aoff);
  f32x4 pa1 = *(const f32x4*)(Al + aoff);
  f32x4 pb0 = *(const f32x4*)(Bth + boff);
  f32x4 pb1 = *(const f32x4*)(Btl + boff);
  *(f32x4*)(lds + 0    + lw) = pa0;
  *(f32x4*)(lds + 2560 + lw) = pa1;
  *(f32x4*)(lds + 5120 + lw) = pb0;
  *(f32x4*)(lds + 7680 + lw) = pb1;
  if (K > 32) {                        // prefetch chunk 1
    pa0 = *(const f32x4*)(Ah + aoff + 32);
    pa1 = *(const f32x4*)(Al + aoff + 32);
    pb0 = *(const f32x4*)(Bth + boff + 32);
    pb1 = *(const f32x4*)(Btl + boff + 32);
  }
  __syncthreads();
  int cur = 0;
  for (int kt = 32; kt <= K; kt += 32) {
    f16* rb = lds + cur * 10240;
    f16* wb = lds + (cur ^ 1) * 10240;
    f16x8 ah[2], al[2], bh[2], bl[2];
#pragma unroll
    for (int m = 0; m < 2; ++m) {
      ah[m] = *(const f16x8*)(rb + (fra + m * 16) * 40 + fu);
      al[m] = *(const f16x8*)(rb + 2560 + (fra + m * 16) * 40 + fu);
    }
#pragma unroll
    for (int n = 0; n < 2; ++n) {
      bh[n] = *(const f16x8*)(rb + 5120 + (frb + n * 16) * 40 + fu);
      bl[n] = *(const f16x8*)(rb + 7680 + (frb + n * 16) * 40 + fu);
    }
    if (kt < K) {                      // stage chunk (kt/32) into other buf
      *(f32x4*)(wb + 0    + lw) = pa0;
      *(f32x4*)(wb + 2560 + lw) = pa1;
      *(f32x4*)(wb + 5120 + lw) = pb0;
      *(f32x4*)(wb + 7680 + lw) = pb1;
      if (kt + 32 < K) {               // prefetch chunk (kt/32 + 1)
        pa0 = *(const f32x4*)(Ah + aoff + kt + 32);
        pa1 = *(const f32x4*)(Al + aoff + kt + 32);
        pb0 = *(const f32x4*)(Bth + boff + kt + 32);
        pb1 = *(const f32x4*)(Btl + boff + kt + 32);
      }
    }
#pragma unroll
    for (int m = 0; m < 2; ++m)
#pragma unroll
      for (int n = 0; n < 2; ++n) {
        acc[m][n] = __builtin_amdgcn_mfma_f32_16x16x32_f16(ah[m], bh[n], acc[m][n], 0, 0, 0);
        acc[m][n] = __builtin_amdgcn_mfma_f32_16x16x32_f16(al[m], bh[n], acc[m][n], 0, 0, 0);
        acc[m][n] = __builtin_amdgcn_mfma_f32_16x16x32_f16(ah[m], bl[n], acc[m][n], 0, 0, 0);
      }
    __syncthreads();
    cur ^= 1;
  }
}

// ============ fused softmax+aggregation GEMM (double-buffered) =============
// A[r][k] = exp(lk(lsrc[k] + ld_r) - m_r) computed at staging time from
// REGISTER-PREFETCHED lsrc chunks (k >= kvalid or invalid row -> 0).
// m_r = lk(max(smax, ls_self_r) + ld_r) via leaky_relu monotonicity.
// Per-row denominator z accumulated during staging; epilogue:
// out = (acc + es*self)*iz, split f16 write.
__device__ __forceinline__ void agg_core(
    const float* __restrict__ lsrc, int kvalid,
    const float* __restrict__ ldb, const float* __restrict__ lsb,
    const f16* __restrict__ Bth, const f16* __restrict__ Btl,
    int K, int row0, int col0, int rvalid,
    const float* __restrict__ selfv,
    f16* __restrict__ outh, f16* __restrict__ outl,
    f16* __restrict__ lds, float* __restrict__ fred)
{
  const int t = threadIdx.x, lane = t & 63, w = t >> 6;
  const int wr = w >> 1, wc = w & 1;
  float* zred = fred;          // [256]
  float* res  = fred + 256;    // [64] self exps
  float* riz  = fred + 320;    // [64] 1/denominator
  const int srow = t >> 2, su = t & 3;
  // block-uniform max over lsrc[0..kvalid)
  float sm = -1e30f;
  for (int k = t; k < kvalid; k += NTHR) sm = fmaxf(sm, lsrc[k]);
#pragma unroll
  for (int off = 1; off < 64; off <<= 1) sm = fmaxf(sm, __shfl_xor(sm, off));
  if (lane == 0) zred[w] = sm;
  __syncthreads();
  sm = fmaxf(fmaxf(zred[0], zred[1]), fmaxf(zred[2], zred[3]));
  __syncthreads();
  // per staging-row constants
  const bool rok = (row0 + srow) < rvalid;
  float ldr = 0.f, mr = 0.f;
  if (rok) {
    ldr = ldb[row0 + srow];
    mr  = lk(fmaxf(sm, lsb[row0 + srow]) + ldr);
  }
  const size_t boff = (size_t)(col0 + srow) * K + su * 8;
  const int lw = srow * 40 + su * 8;
  const int fra = wr * 32 + (lane & 15);
  const int frb = wc * 32 + (lane & 15);
  const int fu  = (lane >> 4) * 8;
  f32x4 acc[2][2] = {};
  float zacc = 0.f;
  // chunk 0: load lsrc + B regs, exp at store time
  f32x4 pl0 = *(const f32x4*)(lsrc + su * 8);       // k = su*8 .. +3
  f32x4 pl1 = *(const f32x4*)(lsrc + su * 8 + 4);   // k = su*8+4 .. +7
  f32x4 pb0 = *(const f32x4*)(Bth + boff);
  f32x4 pb1 = *(const f32x4*)(Btl + boff);
  {
    f16x8 ae, al8;
#pragma unroll
    for (int j = 0; j < 8; ++j) {
      const int k = su * 8 + j;
      const float lv = (j < 4) ? pl0[j] : pl1[j - 4];
      float f = 0.f;
      if (rok && k < kvalid) f = __expf(lk(lv + ldr) - mr);
      zacc += f;
      ae[j] = hif(f); al8[j] = lof(f);
    }
    *(f16x8*)(lds + 0    + lw) = ae;
    *(f16x8*)(lds + 2560 + lw) = al8;
    *(f32x4*)(lds + 5120 + lw) = pb0;
    *(f32x4*)(lds + 7680 + lw) = pb1;
  }
  if (K > 32) {                        // prefetch chunk 1
    pl0 = *(const f32x4*)(lsrc + 32 + su * 8);
    pl1 = *(const f32x4*)(lsrc + 32 + su * 8 + 4);
    pb0 = *(const f32x4*)(Bth + boff + 32);
    pb1 = *(const f32x4*)(Btl + boff + 32);
  }
  __syncthreads();
  int cur = 0;
  for (int kt = 32; kt <= K; kt += 32) {
    f16* rb = lds + cur * 10240;
    f16* wb = lds + (cur ^ 1) * 10240;
    f16x8 ah[2], alr[2], bh[2], bl[2];
#pragma unroll
    for (int m = 0; m < 2; ++m) {
      ah[m]  = *(const f16x8*)(rb + (fra + m * 16) * 40 + fu);
      alr[m] = *(const f16x8*)(rb + 2560 + (fra + m * 16) * 40 + fu);
    }
#pragma unroll
    for (int n = 0; n < 2; ++n) {
      bh[n] = *(const f16x8*)(rb + 5120 + (frb + n * 16) * 40 + fu);
      bl[n] = *(const f16x8*)(rb + 7680 + (frb + n * 16) * 40 + fu);
    }
    if (kt < K) {                      // stage chunk (kt/32): exp from regs
      f16x8 ae, al8;
      const int k0 = kt + su * 8;
#pragma unroll
      for (int j = 0; j < 8; ++j) {
        const int k = k0 + j;
        const float lv = (j < 4) ? pl0[j] : pl1[j - 4];
        float f = 0.f;
        if (rok && k < kvalid) f = __expf(lk(lv + ldr) - mr);
        zacc += f;
        ae[j] = hif(f); al8[j] = lof(f);
      }
      *(f16x8*)(wb + 0    + lw) = ae;
      *(f16x8*)(wb + 2560 + lw) = al8;
      *(f32x4*)(wb + 5120 + lw) = pb0;
      *(f32x4*)(wb + 7680 + lw) = pb1;
      if (kt + 32 < K) {               // prefetch next chunk
        pl0 = *(const f32x4*)(lsrc + kt + 32 + su * 8);
        pl1 = *(const f32x4*)(lsrc + kt + 32 + su * 8 + 4);
        pb0 = *(const f32x4*)(Bth + boff + kt + 32);
        pb1 = *(const f32x4*)(Btl + boff + kt + 32);
      }
    }
#pragma unroll
    for (int m = 0; m < 2; ++m)
#pragma unroll
      for (int n = 0; n < 2; ++n) {
        acc[m][n] = __builtin_amdgcn_mfma_f32_16x16x32_f16(ah[m],  bh[n], acc[m][n], 0, 0, 0);
        acc[m][n] = __builtin_amdgcn_mfma_f32_16x16x32_f16(alr[m], bh[n], acc[m][n], 0, 0, 0);
        acc[m][n] = __builtin_amdgcn_mfma_f32_16x16x32_f16(ah[m],  bl[n], acc[m][n], 0, 0, 0);
      }
    __syncthreads();
    cur ^= 1;
  }
  // per-row denominator, self exp, inverse
  zred[t] = zacc;
  __syncthreads();
  if (t < 64) {
    float z = zred[t * 4] + zred[t * 4 + 1] + zred[t * 4 + 2] + zred[t * 4 + 3];
    float es = 0.f, iz = 0.f;
    if (row0 + t < rvalid) {
      const float l2 = ldb[row0 + t], s2 = lsb[row0 + t];
      const float m2 = lk(fmaxf(sm, s2) + l2);
      es = __expf(lk(s2 + l2) - m2);
      iz = 1.f / (z + es);
    }
    res[t] = es; riz[t] = iz;
  }
  __syncthreads();
  // epilogue
#pragma unroll
  for (int m = 0; m < 2; ++m)
#pragma unroll
    for (int q = 0; q < 4; ++q) {
      const int rl = wr * 32 + m * 16 + (lane >> 4) * 4 + q;
      const int gr = row0 + rl;
      if (gr >= rvalid) continue;
      const float es = res[rl], iz = riz[rl];
#pragma unroll
      for (int n = 0; n < 2; ++n) {
        const int c = col0 + wc * 32 + n * 16 + (lane & 15);
        const float v = (acc[m][n][q] + es * selfv[(size_t)gr * DD + c]) * iz;
        outh[(size_t)gr * DD + c] = hif(v);
        outl[(size_t)gr * DD + c] = lof(v);
      }
    }
}

// ======== 64x64 transpose+split tile (fp32 in -> f16 hi/lo transposed) =====
__device__ __forceinline__ void cvt_tile(
    const float* __restrict__ in, int R, int Cin,
    f16* __restrict__ oh, f16* __restrict__ ol, int ldo,
    int ti, int tj, f16 (*th)[72], f16 (*tl)[72])
{
  const int t = threadIdx.x;
#pragma unroll
  for (int p = 0; p < 4; ++p) {
    const int f = t + p * 256;
    const int i = f >> 4, j4 = (f & 15) * 4;
    const int gi = ti * 64 + i, gj = tj * 64 + j4;
    float4 v = make_float4(0.f, 0.f, 0.f, 0.f);
    if (gi < R && gj + 3 < Cin) v = *(const float4*)(in + (size_t)gi * Cin + gj);
    th[i][j4 + 0] = hif(v.x); tl[i][j4 + 0] = lof(v.x);
    th[i][j4 + 1] = hif(v.y); tl[i][j4 + 1] = lof(v.y);
    th[i][j4 + 2] = hif(v.z); tl[i][j4 + 2] = lof(v.z);
    th[i][j4 + 3] = hif(v.w); tl[i][j4 + 3] = lof(v.w);
  }
  __syncthreads();
#pragma unroll
  for (int p = 0; p < 2; ++p) {
    const int f = t + p * 256;
    const int j = f >> 3, i8 = (f & 7) * 8;
    f16x8 vh, vl;
#pragma unroll
    for (int e = 0; e < 8; ++e) { vh[e] = th[i8 + e][j]; vl[e] = tl[i8 + e][j]; }
    const size_t o = (size_t)(tj * 64 + j) * ldo + ti * 64 + i8;
    *(f16x8*)(oh + o) = vh;
    *(f16x8*)(ol + o) = vl;
  }
}

// ===== K1: weight matvecs (v = W@a, both layers) + zero ls2/ld2 ============
__global__ __launch_bounds__(NTHR) void prep1_k(
    const float* __restrict__ W1, const float* __restrict__ W2,
    const float* __restrict__ as1, const float* __restrict__ ad1,
    const float* __restrict__ as2, const float* __restrict__ ad2,
    float* __restrict__ v1s, float* __restrict__ v1d,
    float* __restrict__ v2s, float* __restrict__ v2d,
    float* __restrict__ ls2, float* __restrict__ ld2)
{
  const int u = blockIdx.x;
  if (u < 256) {
    const int wid  = u * 4 + (threadIdx.x >> 6);   // 0..1023
    const int lane = threadIdx.x & 63;
    const int r = wid & 511;
    const bool l1 = (wid < 512);
    const float* W = l1 ? W1 : W2;
    const float4* a4 = (const float4*)(l1 ? as1 : as2);
    const float4* b4 = (const float4*)(l1 ? ad1 : ad2);
    const float4* w4 = (const float4*)(W + (size_t)r * DD);
    float4 w0 = w4[lane], w1 = w4[lane + 64];
    float4 a0 = a4[lane], a1 = a4[lane + 64];
    float4 b0 = b4[lane], b1 = b4[lane + 64];
    float s1 = w0.x * a0.x + w0.y * a0.y + w0.z * a0.z + w0.w * a0.w
             + w1.x * a1.x + w1.y * a1.y + w1.z * a1.z + w1.w * a1.w;
    float s2 = w0.x * b0.x + w0.y * b0.y + w0.z * b0.z + w0.w * b0.w
             + w1.x * b1.x + w1.y * b1.y + w1.z * b1.z + w1.w * b1.w;
#pragma unroll
    for (int off = 32; off > 0; off >>= 1) {
      s1 += __shfl_down(s1, off);
      s2 += __shfl_down(s2, off);
    }
    if (lane == 0) {
      (l1 ? v1s : v2s)[r] = s1;
      (l1 ? v1d : v2d)[r] = s2;
    }
  } else {
    for (int i = threadIdx.x; i < 1152; i += NTHR) { ls2[i] = 0.f; ld2[i] = 0.f; }
  }
}

// ===== K2: transposes/splits + layer-1 logits (needs v1 from K1) ==========
__global__ __launch_bounds__(NTHR) void prep2_k(
    const float* __restrict__ x, const float* __restrict__ prox,
    const float* __restrict__ W1, const float* __restrict__ W2,
    const float* __restrict__ fcw,
    const float* __restrict__ v1s, const float* __restrict__ v1d,
    f16* xth, f16* xtl, f16* pth, f16* ptl,
    f16* W1th, f16* W1tl, f16* W2th, f16* W2tl, f16* fwth, f16* fwtl,
    float* __restrict__ ls1, float* __restrict__ ld1)
{
  __shared__ f16 th[64][72];
  __shared__ f16 tl[64][72];
  const int b = blockIdx.x;
  if (b < 64) {
    cvt_tile(W1, 512, 512, W1th, W1tl, 512, b >> 3, b & 7, th, tl);
  } else if (b < 128) {
    cvt_tile(W2, 512, 512, W2th, W2tl, 512, (b - 64) >> 3, (b - 64) & 7, th, tl);
  } else if (b < 256) {
    cvt_tile(x, NS, 512, xth, xtl, NS, (b - 128) >> 3, (b - 128) & 7, th, tl);
  } else if (b < 272) {
    cvt_tile(prox, PP, 512, pth, ptl, 128, (b - 256) >> 3, (b - 256) & 7, th, tl);
  } else if (b < 288) {
    cvt_tile(fcw, 512, CC, fwth, fwtl, 512, (b - 272) >> 1, (b - 272) & 1, th, tl);
  } else {
    // layer-1 logits: one wave per node row
    const int r    = (b - 288) * 4 + (threadIdx.x >> 6);
    const int lane = threadIdx.x & 63;
    if (r >= NN) return;
    const float* row = (r < PP) ? prox + (size_t)r * DD
                                : x + (size_t)(r - PP) * DD;
    const float4* r4 = (const float4*)row;
    const float4* s4 = (const float4*)v1s;
    const float4* d4 = (const float4*)v1d;
    float4 v0 = r4[lane], v1 = r4[lane + 64];
    float4 a0 = s4[lane], a1 = s4[lane + 64];
    float4 b0 = d4[lane], b1 = d4[lane + 64];
    float s1 = v0.x * a0.x + v0.y * a0.y + v0.z * a0.z + v0.w * a0.w
             + v1.x * a1.x + v1.y * a1.y + v1.z * a1.z + v1.w * a1.w;
    float s2 = v0.x * b0.x + v0.y * b0.y + v0.z * b0.z + v0.w * b0.w
             + v1.x * b1.x + v1.y * b1.y + v1.z * b1.z + v1.w * b1.w;
#pragma unroll
    for (int off = 32; off > 0; off >>= 1) {
      s1 += __shfl_down(s1, off);
      s2 += __shfl_down(s2, off);
    }
    if (lane == 0) { ls1[r] = s1; ld1[r] = s2; }
  }
}

// ===== K3: layer-1 aggregation: [0,128) samples, [128,144) proxies (inline)
__global__ __launch_bounds__(NTHR) void agg1x_k(
    const float* __restrict__ ls1, const float* __restrict__ ld1,
    const f16* __restrict__ pth, const f16* __restrict__ ptl,
    const f16* __restrict__ xth, const f16* __restrict__ xtl,
    const float* __restrict__ x, const float* __restrict__ prox,
    f16* __restrict__ M1h, f16* __restrict__ M1l)
{
  __shared__ __align__(16) f16 lds[20480];
  __shared__ float fred[384];
  const int b = blockIdx.x;
  if (b < 128) {
    // M1_samp = softmax_rows(exp over 100 proxies) @ prox^T, self = x
    const int row0 = (b >> 3) * 64, col0 = (b & 7) * 64;
    agg_core(ls1, PP, ld1 + PP, ls1 + PP, pth, ptl, 128, row0, col0, NS,
             x, M1h + (size_t)PP * DD, M1l + (size_t)PP * DD, lds, fred);
  } else {
    // M1_prox = softmax_rows(exp over 1024 samples) @ x^T, self = prox
    const int b2 = b - 128;
    const int row0 = (b2 >> 3) * 64, col0 = (b2 & 7) * 64;
    agg_core(ls1 + PP, NS, ld1, ls1, xth, xtl, NS, row0, col0, PP,
             prox, M1h, M1l, lds, fred);
  }
}

// ===== K4: h1 = relu(M1@W1 + b1); emit proxy^T splits; atomic layer-2 logits
__global__ __launch_bounds__(NTHR) void h1_k(
    const f16* __restrict__ M1h, const f16* __restrict__ M1l,
    const f16* __restrict__ W1th, const f16* __restrict__ W1tl,
    const float* __restrict__ b1,
    const float* __restrict__ v2s, const float* __restrict__ v2d,
    float* __restrict__ h1, f16* __restrict__ h1pth, f16* __restrict__ h1ptl,
    float* __restrict__ ls2, float* __restrict__ ld2)
{
  __shared__ __align__(16) f16 lds[20480];
  f32x4 acc[2][2] = {};
  const int t = threadIdx.x, lane = t & 63, w = t >> 6, wr = w >> 1, wc = w & 1;
  const int b = blockIdx.x;
  const int row0 = (b >> 3) * 64, col0 = (b & 7) * 64;
  mgemm_core(M1h, M1l, W1th, W1tl, DD, row0, col0, lds, acc);
  const int c0 = col0 + wc * 32 + (lane & 15);
  const int c1 = c0 + 16;
  const float vs0 = v2s[c0], vs1 = v2s[c1];
  const float vd0 = v2d[c0], vd1 = v2d[c1];
  const float bb0 = b1[c0],  bb1 = b1[c1];
#pragma unroll
  for (int m = 0; m < 2; ++m)
#pragma unroll
    for (int q = 0; q < 4; ++q) {
      const int r = row0 + wr * 32 + m * 16 + (lane >> 4) * 4 + q;
      if (r >= NN) continue;           // uniform within each 16-lane group
      float ps = 0.f, pd = 0.f;
#pragma unroll
      for (int n = 0; n < 2; ++n) {
        const int c = (n == 0) ? c0 : c1;
        const float v = fmaxf(acc[m][n][q] + (n == 0 ? bb0 : bb1), 0.f);
        h1[(size_t)r * DD + c] = v;
        ps += v * (n == 0 ? vs0 : vs1);
        pd += v * (n == 0 ? vd0 : vd1);
        if (r < 128) {                 // agg2 B operand: zero-fill k-pad rows
          const size_t o = (size_t)c * 128 + r;
          f16 hh = (f16)0.f, ll = (f16)0.f;
          if (r < PP) { hh = hif(v); ll = lof(v); }
          h1pth[o] = hh; h1ptl[o] = ll;
        }
      }
      // reduce the 16-lane group (same r) and accumulate layer-2 logits
#pragma unroll
      for (int off = 1; off < 16; off <<= 1) {
        ps += __shfl_xor(ps, off);
        pd += __shfl_xor(pd, off);
      }
      if ((lane & 15) == 0) {
        atomicAdd(&ls2[r], ps);
        atomicAdd(&ld2[r], pd);
      }
    }
}

// ===== K5: layer-2 aggregation (softmax fused; sample dsts only) ===========
__global__ __launch_bounds__(NTHR) void agg2x_k(
    const float* __restrict__ ls2, const float* __restrict__ ld2,
    const f16* __restrict__ h1pth, const f16* __restrict__ h1ptl,
    const float* __restrict__ h1,
    f16* __restrict__ M2h, f16* __restrict__ M2l)
{
  __shared__ __align__(16) f16 lds[20480];
  __shared__ float fred[384];
  const int b = blockIdx.x;
  const int row0 = (b >> 3) * 64, col0 = (b & 7) * 64;
  agg_core(ls2, PP, ld2 + PP, ls2 + PP, h1pth, h1ptl, 128, row0, col0, NS,
           h1 + (size_t)PP * DD, M2h, M2l, lds, fred);
}

// ===== K6: h2 = relu(M2@W2 + b2) -> d_out (fp32) + split for fc ============
__global__ __launch_bounds__(NTHR) void h2_k(
    const f16* __restrict__ M2h, const f16* __restrict__ M2l,
    const f16* __restrict__ W2th, const f16* __restrict__ W2tl,
    const float* __restrict__ b2, float* __restrict__ h2s,
    f16* __restrict__ h2h, f16* __restrict__ h2l)
{
  __shared__ __align__(16) f16 lds[20480];
  f32x4 acc[2][2] = {};
  const int t = threadIdx.x, lane = t & 63, w = t >> 6, wr = w >> 1, wc = w & 1;
  const int b = blockIdx.x;
  const int row0 = (b >> 3) * 64, col0 = (b & 7) * 64;
  mgemm_core(M2h, M2l, W2th, W2tl, DD, row0, col0, lds, acc);
#pragma unroll
  for (int m = 0; m < 2; ++m)
#pragma unroll
    for (int q = 0; q < 4; ++q) {
      const int r = row0 + wr * 32 + m * 16 + (lane >> 4) * 4 + q;
#pragma unroll
      for (int n = 0; n < 2; ++n) {
        const int c = col0 + wc * 32 + n * 16 + (lane & 15);
        const float v = fmaxf(acc[m][n][q] + b2[c], 0.f);
        const size_t o = (size_t)r * DD + c;
        h2s[o] = v;
        h2h[o] = hif(v); h2l[o] = lof(v);
      }
    }
}

// ===== K7: preds = h2 @ fcw + fcb ==========================================
__global__ __launch_bounds__(NTHR) void fc_k(
    const f16* __restrict__ h2h, const f16* __restrict__ h2l,
    const f16* __restrict__ fwth, const f16* __restrict__ fwtl,
    const float* __restrict__ fcb, float* __restrict__ out)
{
  __shared__ __align__(16) f16 lds[20480];
  f32x4 acc[2][2] = {};
  const int t = threadIdx.x, lane = t & 63, w = t >> 6, wr = w >> 1, wc = w & 1;
  const int b = blockIdx.x;
  const int row0 = (b >> 1) * 64, col0 = (b & 1) * 64;
  mgemm_core(h2h, h2l, fwth, fwtl, DD, row0, col0, lds, acc);
#pragma unroll
  for (int m = 0; m < 2; ++m)
#pragma unroll
    for (int q = 0; q < 4; ++q) {
      const int r = row0 + wr * 32 + m * 16 + (lane >> 4) * 4 + q;
#pragma unroll
      for (int n = 0; n < 2; ++n) {
        const int c = col0 + wc * 32 + n * 16 + (lane & 15);
        if (c < CC) out[(size_t)r * CC + c] = acc[m][n][q] + fcb[c];
      }
    }
}

extern "C" void kernel_launch(void* const* d_in, const int* in_sizes, int n_in,
                              void* d_out, int out_size, void* d_ws, size_t ws_size,
                              hipStream_t stream)
{
  const float* x    = (const float*)d_in[0];
  const float* prox = (const float*)d_in[1];
  const float* W1   = (const float*)d_in[2];
  const float* as1  = (const float*)d_in[3];
  const float* ad1  = (const float*)d_in[4];
  const float* b1   = (const float*)d_in[5];
  const float* W2   = (const float*)d_in[6];
  const float* as2  = (const float*)d_in[7];
  const float* ad2  = (const float*)d_in[8];
  const float* b2   = (const float*)d_in[9];
  const float* fcw  = (const float*)d_in[10];
  const float* fcb  = (const float*)d_in[11];
  float* out = (float*)d_out;

  // fp32 workspace
  float* F = (float*)d_ws;
  float* h1   = F; F += (size_t)NN * DD;
  float* ls1  = F; F += 1152;
  float* ld1  = F; F += 1152;
  float* ls2  = F; F += 1152;
  float* ld2  = F; F += 1152;
  float* v1s  = F; F += DD;
  float* v1d  = F; F += DD;
  float* v2s  = F; F += DD;
  float* v2d  = F; F += DD;
  // f16 split workspace (all bases 16B aligned; sizes multiples of 8 halves)
  f16* H = (f16*)F;
  f16* M1h  = H; H += (size_t)1152 * DD;   // rows: 100 prox + 1024 samp + pad
  f16* M1l  = H; H += (size_t)1152 * DD;
  f16* M2h  = H; H += (size_t)NS * DD;
  f16* M2l  = H; H += (size_t)NS * DD;
  f16* xth  = H; H += (size_t)DD * NS;     // x^T  [512][1024]
  f16* xtl  = H; H += (size_t)DD * NS;
  f16* pth  = H; H += (size_t)DD * 128;    // prox^T [512][128] (k-pad zeroed)
  f16* ptl  = H; H += (size_t)DD * 128;
  f16* W1th = H; H += (size_t)DD * DD;     // W1^T [512][512]
  f16* W1tl = H; H += (size_t)DD * DD;
  f16* W2th = H; H += (size_t)DD * DD;
  f16* W2tl = H; H += (size_t)DD * DD;
  f16* fwth = H; H += (size_t)128 * DD;    // fcw^T [128][512] (k-pad zeroed)
  f16* fwtl = H; H += (size_t)128 * DD;
  f16* h2h  = H; H += (size_t)NS * DD;
  f16* h2l  = H; H += (size_t)NS * DD;
  f16* h1pth = H; H += (size_t)DD * 128;   // h1 proxy rows ^T [512][128]
  f16* h1ptl = H; H += (size_t)DD * 128;
  float* h2s = out + (size_t)NS * CC;      // layer-2 sample out in d_out

  dim3 blk(NTHR);
  // K1: weight matvecs + zero ls2/ld2 accumulators
  prep1_k<<<dim3(257), blk, 0, stream>>>(W1, W2, as1, ad1, as2, ad2,
                                         v1s, v1d, v2s, v2d, ls2, ld2);
  // K2: transposes/splits + layer-1 logits
  prep2_k<<<dim3(569), blk, 0, stream>>>(x, prox, W1, W2, fcw, v1s, v1d,
      xth, xtl, pth, ptl, W1th, W1tl, W2th, W2tl, fwth, fwtl, ls1, ld1);
  // K3: layer-1 aggregation (both sides inline softmax) -> M1 splits
  agg1x_k<<<dim3(144), blk, 0, stream>>>(ls1, ld1, pth, ptl, xth, xtl,
                                         x, prox, M1h, M1l);
  // K4: h1 = relu(M1@W1+b1) + proxy^T splits + atomic layer-2 logits
  h1_k<<<dim3(144), blk, 0, stream>>>(M1h, M1l, W1th, W1tl, b1, v2s, v2d,
                                      h1, h1pth, h1ptl, ls2, ld2);
  // K5: layer-2 aggregation (softmax fused) -> M2 splits
  agg2x_k<<<dim3(128), blk, 0, stream>>>(ls2, ld2, h1pth, h1ptl, h1, M2h, M2l);
  // K6: h2 = relu(M2@W2+b2) -> d_out (+ split)
  h2_k<<<dim3(128), blk, 0, stream>>>(M2h, M2l, W2th, W2tl, b2, h2s, h2h, h2l);
  // K7: preds = h2 @ fcw + fcb
  fc_k<<<dim3(32), blk, 0, stream>>>(h2h, h2l, fwth, fwtl, fcb, out);
}

// Round 9
// 151.590 us; speedup vs baseline: 3.8359x; 1.0059x over previous
//
#include <hip/hip_runtime.h>

// Problem constants (complete bipartite proxy<->sample + self-loops)
#define PP 100    // proxies
#define NS 1024   // samples
#define NN 1124   // total nodes
#define DD 512    // feature dim
#define CC 100    // fc out dim
#define NTHR 256

typedef _Float16 f16;
typedef _Float16 f16x8 __attribute__((ext_vector_type(8)));
typedef float    f32x4 __attribute__((ext_vector_type(4)));

__device__ __forceinline__ float lk(float v) { return v > 0.f ? v : 0.2f * v; }
__device__ __forceinline__ f16 hif(float v) { return (f16)v; }
__device__ __forceinline__ f16 lof(float v) { return (f16)(v - (float)((f16)v)); }

// LDS buffer layout (halves): buf k at lds + k*10240;
// sections within buf: Ash=0, Asl=2560, Bsh=5120, Bsl=7680 (rows of 40)

// =================== MFMA split-f16 GEMM core (double-buffered) ===========
// acc[2][2] += A[row0.., K] @ B ; A = (Ah,Al) row-major [*,K], B TRANSPOSED
// as (Bth,Btl) row-major [*,K] (row = output col). 64x64 tile, 4 waves of
// 32x32, BK=32. C = Ah*Bh + Al*Bh + Ah*Bl (fp32 acc; al*bl dropped).
// One __syncthreads per K-step: iteration i reads buf[i&1], writes next
// chunk to buf[(i+1)&1] (safe: that buf was last read before prev barrier).
__device__ __forceinline__ void mgemm_core(
    const f16* __restrict__ Ah, const f16* __restrict__ Al,
    const f16* __restrict__ Bth, const f16* __restrict__ Btl,
    int K, int row0, int col0, f16* __restrict__ lds, f32x4 acc[2][2])
{
  const int t = threadIdx.x;
  const int lane = t & 63, w = t >> 6;
  const int wr = w >> 1, wc = w & 1;
  const int srow = t >> 2, su = t & 3;
  const size_t aoff = (size_t)(row0 + srow) * K + su * 8;
  const size_t boff = (size_t)(col0 + srow) * K + su * 8;
  const int lw = srow * 40 + su * 8;
  const int fra = wr * 32 + (lane & 15);
  const int frb = wc * 32 + (lane & 15);
  const int fu  = (lane >> 4) * 8;
  f32x4 pa0 = *(const f32x4*)(Ah + aoff);
  f32x4 pa1 = *(const f32x4*)(Al + aoff);
  f32x4 pb0 = *(const f32x4*)(Bth + boff);
  f32x4 pb1 = *(const f32x4*)(Btl + boff);
  *(f32x4*)(lds + 0    + lw) = pa0;
  *(f32x4*)(lds + 2560 + lw) = pa1;
  *(f32x4*)(lds + 5120 + lw) = pb0;
  *(f32x4*)(lds + 7680 + lw) = pb1;
  if (K > 32) {                        // prefetch chunk 1
    pa0 = *(const f32x4*)(Ah + aoff + 32);
    pa1 = *(const f32x4*)(Al + aoff + 32);
    pb0 = *(const f32x4*)(Bth + boff + 32);
    pb1 = *(const f32x4*)(Btl + boff + 32);
  }
  __syncthreads();
  int cur = 0;
  for (int kt = 32; kt <= K; kt += 32) {
    f16* rb = lds + cur * 10240;
    f16* wb = lds + (cur ^ 1) * 10240;
    f16x8 ah[2], al[2], bh[2], bl[2];
#pragma unroll
    for (int m = 0; m < 2; ++m) {
      ah[m] = *(const f16x8*)(rb + (fra + m * 16) * 40 + fu);
      al[m] = *(const f16x8*)(rb + 2560 + (fra + m * 16) * 40 + fu);
    }
#pragma unroll
    for (int n = 0; n < 2; ++n) {
      bh[n] = *(const f16x8*)(rb + 5120 + (frb + n * 16) * 40 + fu);
      bl[n] = *(const f16x8*)(rb + 7680 + (frb + n * 16) * 40 + fu);
    }
    if (kt < K) {                      // stage chunk (kt/32) into other buf
      *(f32x4*)(wb + 0    + lw) = pa0;
      *(f32x4*)(wb + 2560 + lw) = pa1;
      *(f32x4*)(wb + 5120 + lw) = pb0;
      *(f32x4*)(wb + 7680 + lw) = pb1;
      if (kt + 32 < K) {               // prefetch chunk (kt/32 + 1)
        pa0 = *(const f32x4*)(Ah + aoff + kt + 32);
        pa1 = *(const f32x4*)(Al + aoff + kt + 32);
        pb0 = *(const f32x4*)(Bth + boff + kt + 32);
        pb1 = *(const f32x4*)(Btl + boff + kt + 32);
      }
    }
#pragma unroll
    for (int m = 0; m < 2; ++m)
#pragma unroll
      for (int n = 0; n < 2; ++n) {
        acc[m][n] = __builtin_amdgcn_mfma_f32_16x16x32_f16(ah[m], bh[n], acc[m][n], 0, 0, 0);
        acc[m][n] = __builtin_amdgcn_mfma_f32_16x16x32_f16(al[m], bh[n], acc[m][n], 0, 0, 0);
        acc[m][n] = __builtin_amdgcn_mfma_f32_16x16x32_f16(ah[m], bl[n], acc[m][n], 0, 0, 0);
      }
    __syncthreads();
    cur ^= 1;
  }
}

// ============ fused softmax+aggregation GEMM (double-buffered) =============
// A[r][k] = exp(lk(lsrc[k] + ld_r) - m_r) computed at staging time from
// REGISTER-PREFETCHED lsrc chunks (k >= kvalid or invalid row -> 0).
// m_r = lk(max(smax, ls_self_r) + ld_r) via leaky_relu monotonicity.
// Per-row denominator z accumulated during staging; epilogue:
// out = (acc + es*self)*iz, split f16 write.
__device__ __forceinline__ void agg_core(
    const float* __restrict__ lsrc, int kvalid,
    const float* __restrict__ ldb, const float* __restrict__ lsb,
    const f16* __restrict__ Bth, const f16* __restrict__ Btl,
    int K, int row0, int col0, int rvalid,
    const float* __restrict__ selfv,
    f16* __restrict__ outh, f16* __restrict__ outl,
    f16* __restrict__ lds, float* __restrict__ fred)
{
  const int t = threadIdx.x, lane = t & 63, w = t >> 6;
  const int wr = w >> 1, wc = w & 1;
  float* zred = fred;          // [256]
  float* res  = fred + 256;    // [64] self exps
  float* riz  = fred + 320;    // [64] 1/denominator
  const int srow = t >> 2, su = t & 3;
  // block-uniform max over lsrc[0..kvalid)
  float sm = -1e30f;
  for (int k = t; k < kvalid; k += NTHR) sm = fmaxf(sm, lsrc[k]);
#pragma unroll
  for (int off = 1; off < 64; off <<= 1) sm = fmaxf(sm, __shfl_xor(sm, off));
  if (lane == 0) zred[w] = sm;
  __syncthreads();
  sm = fmaxf(fmaxf(zred[0], zred[1]), fmaxf(zred[2], zred[3]));
  __syncthreads();
  // per staging-row constants
  const bool rok = (row0 + srow) < rvalid;
  float ldr = 0.f, mr = 0.f;
  if (rok) {
    ldr = ldb[row0 + srow];
    mr  = lk(fmaxf(sm, lsb[row0 + srow]) + ldr);
  }
  const size_t boff = (size_t)(col0 + srow) * K + su * 8;
  const int lw = srow * 40 + su * 8;
  const int fra = wr * 32 + (lane & 15);
  const int frb = wc * 32 + (lane & 15);
  const int fu  = (lane >> 4) * 8;
  f32x4 acc[2][2] = {};
  float zacc = 0.f;
  // chunk 0: load lsrc + B regs, exp at store time
  f32x4 pl0 = *(const f32x4*)(lsrc + su * 8);       // k = su*8 .. +3
  f32x4 pl1 = *(const f32x4*)(lsrc + su * 8 + 4);   // k = su*8+4 .. +7
  f32x4 pb0 = *(const f32x4*)(Bth + boff);
  f32x4 pb1 = *(const f32x4*)(Btl + boff);
  {
    f16x8 ae, al8;
#pragma unroll
    for (int j = 0; j < 8; ++j) {
      const int k = su * 8 + j;
      const float lv = (j < 4) ? pl0[j] : pl1[j - 4];
      float f = 0.f;
      if (rok && k < kvalid) f = __expf(lk(lv + ldr) - mr);
      zacc += f;
      ae[j] = hif(f); al8[j] = lof(f);
    }
    *(f16x8*)(lds + 0    + lw) = ae;
    *(f16x8*)(lds + 2560 + lw) = al8;
    *(f32x4*)(lds + 5120 + lw) = pb0;
    *(f32x4*)(lds + 7680 + lw) = pb1;
  }
  if (K > 32) {                        // prefetch chunk 1
    pl0 = *(const f32x4*)(lsrc + 32 + su * 8);
    pl1 = *(const f32x4*)(lsrc + 32 + su * 8 + 4);
    pb0 = *(const f32x4*)(Bth + boff + 32);
    pb1 = *(const f32x4*)(Btl + boff + 32);
  }
  __syncthreads();
  int cur = 0;
  for (int kt = 32; kt <= K; kt += 32) {
    f16* rb = lds + cur * 10240;
    f16* wb = lds + (cur ^ 1) * 10240;
    f16x8 ah[2], alr[2], bh[2], bl[2];
#pragma unroll
    for (int m = 0; m < 2; ++m) {
      ah[m]  = *(const f16x8*)(rb + (fra + m * 16) * 40 + fu);
      alr[m] = *(const f16x8*)(rb + 2560 + (fra + m * 16) * 40 + fu);
    }
#pragma unroll
    for (int n = 0; n < 2; ++n) {
      bh[n] = *(const f16x8*)(rb + 5120 + (frb + n * 16) * 40 + fu);
      bl[n] = *(const f16x8*)(rb + 7680 + (frb + n * 16) * 40 + fu);
    }
    if (kt < K) {                      // stage chunk (kt/32): exp from regs
      f16x8 ae, al8;
      const int k0 = kt + su * 8;
#pragma unroll
      for (int j = 0; j < 8; ++j) {
        const int k = k0 + j;
        const float lv = (j < 4) ? pl0[j] : pl1[j - 4];
        float f = 0.f;
        if (rok && k < kvalid) f = __expf(lk(lv + ldr) - mr);
        zacc += f;
        ae[j] = hif(f); al8[j] = lof(f);
      }
      *(f16x8*)(wb + 0    + lw) = ae;
      *(f16x8*)(wb + 2560 + lw) = al8;
      *(f32x4*)(wb + 5120 + lw) = pb0;
      *(f32x4*)(wb + 7680 + lw) = pb1;
      if (kt + 32 < K) {               // prefetch next chunk
        pl0 = *(const f32x4*)(lsrc + kt + 32 + su * 8);
        pl1 = *(const f32x4*)(lsrc + kt + 32 + su * 8 + 4);
        pb0 = *(const f32x4*)(Bth + boff + kt + 32);
        pb1 = *(const f32x4*)(Btl + boff + kt + 32);
      }
    }
#pragma unroll
    for (int m = 0; m < 2; ++m)
#pragma unroll
      for (int n = 0; n < 2; ++n) {
        acc[m][n] = __builtin_amdgcn_mfma_f32_16x16x32_f16(ah[m],  bh[n], acc[m][n], 0, 0, 0);
        acc[m][n] = __builtin_amdgcn_mfma_f32_16x16x32_f16(alr[m], bh[n], acc[m][n], 0, 0, 0);
        acc[m][n] = __builtin_amdgcn_mfma_f32_16x16x32_f16(ah[m],  bl[n], acc[m][n], 0, 0, 0);
      }
    __syncthreads();
    cur ^= 1;
  }
  // per-row denominator, self exp, inverse
  zred[t] = zacc;
  __syncthreads();
  if (t < 64) {
    float z = zred[t * 4] + zred[t * 4 + 1] + zred[t * 4 + 2] + zred[t * 4 + 3];
    float es = 0.f, iz = 0.f;
    if (row0 + t < rvalid) {
      const float l2 = ldb[row0 + t], s2 = lsb[row0 + t];
      const float m2 = lk(fmaxf(sm, s2) + l2);
      es = __expf(lk(s2 + l2) - m2);
      iz = 1.f / (z + es);
    }
    res[t] = es; riz[t] = iz;
  }
  __syncthreads();
  // epilogue
#pragma unroll
  for (int m = 0; m < 2; ++m)
#pragma unroll
    for (int q = 0; q < 4; ++q) {
      const int rl = wr * 32 + m * 16 + (lane >> 4) * 4 + q;
      const int gr = row0 + rl;
      if (gr >= rvalid) continue;
      const float es = res[rl], iz = riz[rl];
#pragma unroll
      for (int n = 0; n < 2; ++n) {
        const int c = col0 + wc * 32 + n * 16 + (lane & 15);
        const float v = (acc[m][n][q] + es * selfv[(size_t)gr * DD + c]) * iz;
        outh[(size_t)gr * DD + c] = hif(v);
        outl[(size_t)gr * DD + c] = lof(v);
      }
    }
}

// ======== 64x64 direct transpose+split tile (no LDS, one pass) =============
// Output row gj (= input column); lanes with consecutive gj read consecutive
// addresses -> coalesced. Each thread: 2 output rows x 8 k-elements.
// Per-element guards zero-fill OOB (preserves k-pad rows for prox/fcw).
__device__ __forceinline__ void cvt_tile(
    const float* __restrict__ in, int R, int Cin,
    f16* __restrict__ oh, f16* __restrict__ ol, int ldo,
    int ti, int tj)
{
  const int t = threadIdx.x;
  const int gj0 = tj * 64 + (t & 31) * 2;        // output rows gj0, gj0+1
  const int i8  = (t >> 5) * 8;                  // k-chunk within tile
  const bool c0 = gj0 < Cin, c1 = (gj0 + 1) < Cin;
  f16x8 vh0, vl0, vh1, vl1;
#pragma unroll
  for (int e = 0; e < 8; ++e) {
    const int gi = ti * 64 + i8 + e;
    float a = 0.f, b = 0.f;
    if (gi < R) {
      if (c0 && c1) {
        const float2 v = *(const float2*)(in + (size_t)gi * Cin + gj0);
        a = v.x; b = v.y;
      } else if (c0) {
        a = in[(size_t)gi * Cin + gj0];
      }
    }
    vh0[e] = hif(a); vl0[e] = lof(a);
    vh1[e] = hif(b); vl1[e] = lof(b);
  }
  const size_t o0 = (size_t)gj0 * ldo + ti * 64 + i8;
  *(f16x8*)(oh + o0) = vh0;
  *(f16x8*)(ol + o0) = vl0;
  const size_t o1 = o0 + ldo;
  *(f16x8*)(oh + o1) = vh1;
  *(f16x8*)(ol + o1) = vl1;
}

// ===== K1: weight matvecs (v = W@a, both layers) + zero ls2/ld2 ============
__global__ __launch_bounds__(NTHR) void prep1_k(
    const float* __restrict__ W1, const float* __restrict__ W2,
    const float* __restrict__ as1, const float* __restrict__ ad1,
    const float* __restrict__ as2, const float* __restrict__ ad2,
    float* __restrict__ v1s, float* __restrict__ v1d,
    float* __restrict__ v2s, float* __restrict__ v2d,
    float* __restrict__ ls2, float* __restrict__ ld2)
{
  const int u = blockIdx.x;
  if (u < 256) {
    const int wid  = u * 4 + (threadIdx.x >> 6);   // 0..1023
    const int lane = threadIdx.x & 63;
    const int r = wid & 511;
    const bool l1 = (wid < 512);
    const float* W = l1 ? W1 : W2;
    const float4* a4 = (const float4*)(l1 ? as1 : as2);
    const float4* b4 = (const float4*)(l1 ? ad1 : ad2);
    const float4* w4 = (const float4*)(W + (size_t)r * DD);
    float4 w0 = w4[lane], w1 = w4[lane + 64];
    float4 a0 = a4[lane], a1 = a4[lane + 64];
    float4 b0 = b4[lane], b1 = b4[lane + 64];
    float s1 = w0.x * a0.x + w0.y * a0.y + w0.z * a0.z + w0.w * a0.w
             + w1.x * a1.x + w1.y * a1.y + w1.z * a1.z + w1.w * a1.w;
    float s2 = w0.x * b0.x + w0.y * b0.y + w0.z * b0.z + w0.w * b0.w
             + w1.x * b1.x + w1.y * b1.y + w1.z * b1.z + w1.w * b1.w;
#pragma unroll
    for (int off = 32; off > 0; off >>= 1) {
      s1 += __shfl_down(s1, off);
      s2 += __shfl_down(s2, off);
    }
    if (lane == 0) {
      (l1 ? v1s : v2s)[r] = s1;
      (l1 ? v1d : v2d)[r] = s2;
    }
  } else {
    for (int i = threadIdx.x; i < 1152; i += NTHR) { ls2[i] = 0.f; ld2[i] = 0.f; }
  }
}

// ===== K2: transposes/splits + layer-1 logits (needs v1 from K1) ==========
__global__ __launch_bounds__(NTHR) void prep2_k(
    const float* __restrict__ x, const float* __restrict__ prox,
    const float* __restrict__ W1, const float* __restrict__ W2,
    const float* __restrict__ fcw,
    const float* __restrict__ v1s, const float* __restrict__ v1d,
    f16* xth, f16* xtl, f16* pth, f16* ptl,
    f16* W1th, f16* W1tl, f16* W2th, f16* W2tl, f16* fwth, f16* fwtl,
    float* __restrict__ ls1, float* __restrict__ ld1)
{
  const int b = blockIdx.x;
  if (b < 64) {
    cvt_tile(W1, 512, 512, W1th, W1tl, 512, b >> 3, b & 7);
  } else if (b < 128) {
    cvt_tile(W2, 512, 512, W2th, W2tl, 512, (b - 64) >> 3, (b - 64) & 7);
  } else if (b < 256) {
    cvt_tile(x, NS, 512, xth, xtl, NS, (b - 128) >> 3, (b - 128) & 7);
  } else if (b < 272) {
    cvt_tile(prox, PP, 512, pth, ptl, 128, (b - 256) >> 3, (b - 256) & 7);
  } else if (b < 288) {
    cvt_tile(fcw, 512, CC, fwth, fwtl, 512, (b - 272) >> 1, (b - 272) & 1);
  } else {
    // layer-1 logits: one wave per node row
    const int r    = (b - 288) * 4 + (threadIdx.x >> 6);
    const int lane = threadIdx.x & 63;
    if (r >= NN) return;
    const float* row = (r < PP) ? prox + (size_t)r * DD
                                : x + (size_t)(r - PP) * DD;
    const float4* r4 = (const float4*)row;
    const float4* s4 = (const float4*)v1s;
    const float4* d4 = (const float4*)v1d;
    float4 v0 = r4[lane], v1 = r4[lane + 64];
    float4 a0 = s4[lane], a1 = s4[lane + 64];
    float4 b0 = d4[lane], b1 = d4[lane + 64];
    float s1 = v0.x * a0.x + v0.y * a0.y + v0.z * a0.z + v0.w * a0.w
             + v1.x * a1.x + v1.y * a1.y + v1.z * a1.z + v1.w * a1.w;
    float s2 = v0.x * b0.x + v0.y * b0.y + v0.z * b0.z + v0.w * b0.w
             + v1.x * b1.x + v1.y * b1.y + v1.z * b1.z + v1.w * b1.w;
#pragma unroll
    for (int off = 32; off > 0; off >>= 1) {
      s1 += __shfl_down(s1, off);
      s2 += __shfl_down(s2, off);
    }
    if (lane == 0) { ls1[r] = s1; ld1[r] = s2; }
  }
}

// ===== K3: layer-1 aggregation: [0,128) samples, [128,144) proxies (inline)
__global__ __launch_bounds__(NTHR) void agg1x_k(
    const float* __restrict__ ls1, const float* __restrict__ ld1,
    const f16* __restrict__ pth, const f16* __restrict__ ptl,
    const f16* __restrict__ xth, const f16* __restrict__ xtl,
    const float* __restrict__ x, const float* __restrict__ prox,
    f16* __restrict__ M1h, f16* __restrict__ M1l)
{
  __shared__ __align__(16) f16 lds[20480];
  __shared__ float fred[384];
  const int b = blockIdx.x;
  if (b < 128) {
    // M1_samp = softmax_rows(exp over 100 proxies) @ prox^T, self = x
    const int row0 = (b >> 3) * 64, col0 = (b & 7) * 64;
    agg_core(ls1, PP, ld1 + PP, ls1 + PP, pth, ptl, 128, row0, col0, NS,
             x, M1h + (size_t)PP * DD, M1l + (size_t)PP * DD, lds, fred);
  } else {
    // M1_prox = softmax_rows(exp over 1024 samples) @ x^T, self = prox
    const int b2 = b - 128;
    const int row0 = (b2 >> 3) * 64, col0 = (b2 & 7) * 64;
    agg_core(ls1 + PP, NS, ld1, ls1, xth, xtl, NS, row0, col0, PP,
             prox, M1h, M1l, lds, fred);
  }
}

// ===== K4: h1 = relu(M1@W1 + b1); emit proxy^T splits; atomic layer-2 logits
__global__ __launch_bounds__(NTHR) void h1_k(
    const f16* __restrict__ M1h, const f16* __restrict__ M1l,
    const f16* __restrict__ W1th, const f16* __restrict__ W1tl,
    const float* __restrict__ b1,
    const float* __restrict__ v2s, const float* __restrict__ v2d,
    float* __restrict__ h1, f16* __restrict__ h1pth, f16* __restrict__ h1ptl,
    float* __restrict__ ls2, float* __restrict__ ld2)
{
  __shared__ __align__(16) f16 lds[20480];
  f32x4 acc[2][2] = {};
  const int t = threadIdx.x, lane = t & 63, w = t >> 6, wr = w >> 1, wc = w & 1;
  const int b = blockIdx.x;
  const int row0 = (b >> 3) * 64, col0 = (b & 7) * 64;
  mgemm_core(M1h, M1l, W1th, W1tl, DD, row0, col0, lds, acc);
  const int c0 = col0 + wc * 32 + (lane & 15);
  const int c1 = c0 + 16;
  const float vs0 = v2s[c0], vs1 = v2s[c1];
  const float vd0 = v2d[c0], vd1 = v2d[c1];
  const float bb0 = b1[c0],  bb1 = b1[c1];
#pragma unroll
  for (int m = 0; m < 2; ++m)
#pragma unroll
    for (int q = 0; q < 4; ++q) {
      const int r = row0 + wr * 32 + m * 16 + (lane >> 4) * 4 + q;
      if (r >= NN) continue;           // uniform within each 16-lane group
      float ps = 0.f, pd = 0.f;
#pragma unroll
      for (int n = 0; n < 2; ++n) {
        const int c = (n == 0) ? c0 : c1;
        const float v = fmaxf(acc[m][n][q] + (n == 0 ? bb0 : bb1), 0.f);
        h1[(size_t)r * DD + c] = v;
        ps += v * (n == 0 ? vs0 : vs1);
        pd += v * (n == 0 ? vd0 : vd1);
        if (r < 128) {                 // agg2 B operand: zero-fill k-pad rows
          const size_t o = (size_t)c * 128 + r;
          f16 hh = (f16)0.f, ll = (f16)0.f;
          if (r < PP) { hh = hif(v); ll = lof(v); }
          h1pth[o] = hh; h1ptl[o] = ll;
        }
      }
      // reduce the 16-lane group (same r) and accumulate layer-2 logits
#pragma unroll
      for (int off = 1; off < 16; off <<= 1) {
        ps += __shfl_xor(ps, off);
        pd += __shfl_xor(pd, off);
      }
      if ((lane & 15) == 0) {
        atomicAdd(&ls2[r], ps);
        atomicAdd(&ld2[r], pd);
      }
    }
}

// ===== K5: layer-2 aggregation (softmax fused; sample dsts only) ===========
__global__ __launch_bounds__(NTHR) void agg2x_k(
    const float* __restrict__ ls2, const float* __restrict__ ld2,
    const f16* __restrict__ h1pth, const f16* __restrict__ h1ptl,
    const float* __restrict__ h1,
    f16* __restrict__ M2h, f16* __restrict__ M2l)
{
  __shared__ __align__(16) f16 lds[20480];
  __shared__ float fred[384];
  const int b = blockIdx.x;
  const int row0 = (b >> 3) * 64, col0 = (b & 7) * 64;
  agg_core(ls2, PP, ld2 + PP, ls2 + PP, h1pth, h1ptl, 128, row0, col0, NS,
           h1 + (size_t)PP * DD, M2h, M2l, lds, fred);
}

// ===== K6: h2 = relu(M2@W2 + b2) -> d_out (fp32) + split for fc ============
__global__ __launch_bounds__(NTHR) void h2_k(
    const f16* __restrict__ M2h, const f16* __restrict__ M2l,
    const f16* __restrict__ W2th, const f16* __restrict__ W2tl,
    const float* __restrict__ b2, float* __restrict__ h2s,
    f16* __restrict__ h2h, f16* __restrict__ h2l)
{
  __shared__ __align__(16) f16 lds[20480];
  f32x4 acc[2][2] = {};
  const int t = threadIdx.x, lane = t & 63, w = t >> 6, wr = w >> 1, wc = w & 1;
  const int b = blockIdx.x;
  const int row0 = (b >> 3) * 64, col0 = (b & 7) * 64;
  mgemm_core(M2h, M2l, W2th, W2tl, DD, row0, col0, lds, acc);
#pragma unroll
  for (int m = 0; m < 2; ++m)
#pragma unroll
    for (int q = 0; q < 4; ++q) {
      const int r = row0 + wr * 32 + m * 16 + (lane >> 4) * 4 + q;
#pragma unroll
      for (int n = 0; n < 2; ++n) {
        const int c = col0 + wc * 32 + n * 16 + (lane & 15);
        const float v = fmaxf(acc[m][n][q] + b2[c], 0.f);
        const size_t o = (size_t)r * DD + c;
        h2s[o] = v;
        h2h[o] = hif(v); h2l[o] = lof(v);
      }
    }
}

// ===== K7: preds = h2 @ fcw + fcb ==========================================
__global__ __launch_bounds__(NTHR) void fc_k(
    const f16* __restrict__ h2h, const f16* __restrict__ h2l,
    const f16* __restrict__ fwth, const f16* __restrict__ fwtl,
    const float* __restrict__ fcb, float* __restrict__ out)
{
  __shared__ __align__(16) f16 lds[20480];
  f32x4 acc[2][2] = {};
  const int t = threadIdx.x, lane = t & 63, w = t >> 6, wr = w >> 1, wc = w & 1;
  const int b = blockIdx.x;
  const int row0 = (b >> 1) * 64, col0 = (b & 1) * 64;
  mgemm_core(h2h, h2l, fwth, fwtl, DD, row0, col0, lds, acc);
#pragma unroll
  for (int m = 0; m < 2; ++m)
#pragma unroll
    for (int q = 0; q < 4; ++q) {
      const int r = row0 + wr * 32 + m * 16 + (lane >> 4) * 4 + q;
#pragma unroll
      for (int n = 0; n < 2; ++n) {
        const int c = col0 + wc * 32 + n * 16 + (lane & 15);
        if (c < CC) out[(size_t)r * CC + c] = acc[m][n][q] + fcb[c];
      }
    }
}

extern "C" void kernel_launch(void* const* d_in, const int* in_sizes, int n_in,
                              void* d_out, int out_size, void* d_ws, size_t ws_size,
                              hipStream_t stream)
{
  const float* x    = (const float*)d_in[0];
  const float* prox = (const float*)d_in[1];
  const float* W1   = (const float*)d_in[2];
  const float* as1  = (const float*)d_in[3];
  const float* ad1  = (const float*)d_in[4];
  const float* b1   = (const float*)d_in[5];
  const float* W2   = (const float*)d_in[6];
  const float* as2  = (const float*)d_in[7];
  const float* ad2  = (const float*)d_in[8];
  const float* b2   = (const float*)d_in[9];
  const float* fcw  = (const float*)d_in[10];
  const float* fcb  = (const float*)d_in[11];
  float* out = (float*)d_out;

  // fp32 workspace
  float* F = (float*)d_ws;
  float* h1   = F; F += (size_t)NN * DD;
  float* ls1  = F; F += 1152;
  float* ld1  = F; F += 1152;
  float* ls2  = F; F += 1152;
  float* ld2  = F; F += 1152;
  float* v1s  = F; F += DD;
  float* v1d  = F; F += DD;
  float* v2s  = F; F += DD;
  float* v2d  = F; F += DD;
  // f16 split workspace (all bases 16B aligned; sizes multiples of 8 halves)
  f16* H = (f16*)F;
  f16* M1h  = H; H += (size_t)1152 * DD;   // rows: 100 prox + 1024 samp + pad
  f16* M1l  = H; H += (size_t)1152 * DD;
  f16* M2h  = H; H += (size_t)NS * DD;
  f16* M2l  = H; H += (size_t)NS * DD;
  f16* xth  = H; H += (size_t)DD * NS;     // x^T  [512][1024]
  f16* xtl  = H; H += (size_t)DD * NS;
  f16* pth  = H; H += (size_t)DD * 128;    // prox^T [512][128] (k-pad zeroed)
  f16* ptl  = H; H += (size_t)DD * 128;
  f16* W1th = H; H += (size_t)DD * DD;     // W1^T [512][512]
  f16* W1tl = H; H += (size_t)DD * DD;
  f16* W2th = H; H += (size_t)DD * DD;
  f16* W2tl = H; H += (size_t)DD * DD;
  f16* fwth = H; H += (size_t)128 * DD;    // fcw^T [128][512] (k-pad zeroed)
  f16* fwtl = H; H += (size_t)128 * DD;
  f16* h2h  = H; H += (size_t)NS * DD;
  f16* h2l  = H; H += (size_t)NS * DD;
  f16* h1pth = H; H += (size_t)DD * 128;   // h1 proxy rows ^T [512][128]
  f16* h1ptl = H; H += (size_t)DD * 128;
  float* h2s = out + (size_t)NS * CC;      // layer-2 sample out in d_out

  dim3 blk(NTHR);
  // K1: weight matvecs + zero ls2/ld2 accumulators
  prep1_k<<<dim3(257), blk, 0, stream>>>(W1, W2, as1, ad1, as2, ad2,
                                         v1s, v1d, v2s, v2d, ls2, ld2);
  // K2: transposes/splits + layer-1 logits
  prep2_k<<<dim3(569), blk, 0, stream>>>(x, prox, W1, W2, fcw, v1s, v1d,
      xth, xtl, pth, ptl, W1th, W1tl, W2th, W2tl, fwth, fwtl, ls1, ld1);
  // K3: layer-1 aggregation (both sides inline softmax) -> M1 splits
  agg1x_k<<<dim3(144), blk, 0, stream>>>(ls1, ld1, pth, ptl, xth, xtl,
                                         x, prox, M1h, M1l);
  // K4: h1 = relu(M1@W1+b1) + proxy^T splits + atomic layer-2 logits
  h1_k<<<dim3(144), blk, 0, stream>>>(M1h, M1l, W1th, W1tl, b1, v2s, v2d,
                                      h1, h1pth, h1ptl, ls2, ld2);
  // K5: layer-2 aggregation (softmax fused) -> M2 splits
  agg2x_k<<<dim3(128), blk, 0, stream>>>(ls2, ld2, h1pth, h1ptl, h1, M2h, M2l);
  // K6: h2 = relu(M2@W2+b2) -> d_out (+ split)
  h2_k<<<dim3(128), blk, 0, stream>>>(M2h, M2l, W2th, W2tl, b2, h2s, h2h, h2l);
  // K7: preds = h2 @ fcw + fcb
  fc_k<<<dim3(32), blk, 0, stream>>>(h2h, h2l, fwth, fwtl, fcb, out);
}

// Round 11
// 141.868 us; speedup vs baseline: 4.0987x; 1.0685x over previous
//
#include <hip/hip_runtime.h>

// Problem constants (complete bipartite proxy<->sample + self-loops)
#define PP 100    // proxies
#define NS 1024   // samples
#define NN 1124   // total nodes
#define DD 512    // feature dim
#define CC 100    // fc out dim
#define NTHR 256

typedef _Float16 f16;
typedef _Float16 f16x8 __attribute__((ext_vector_type(8)));
typedef float    f32x4 __attribute__((ext_vector_type(4)));

__device__ __forceinline__ float lk(float v) { return v > 0.f ? v : 0.2f * v; }
__device__ __forceinline__ f16 hif(float v) { return (f16)v; }
__device__ __forceinline__ f16 lof(float v) { return (f16)(v - (float)((f16)v)); }

// LDS buffer layout (halves): buf k at lds + k*10240;
// sections within buf: Ash=0, Asl=2560, Bsh=5120, Bsl=7680 (rows of 40)

// =================== MFMA split-f16 GEMM core (double-buffered) ===========
// acc[2][2] += A[row0.., K] @ B ; A = (Ah,Al) row-major [*,K], B TRANSPOSED
// as (Bth,Btl) row-major [*,K] (row = output col). 64x64 tile, 4 waves of
// 32x32, BK=32. C = Ah*Bh + Al*Bh + Ah*Bl (fp32 acc; al*bl dropped).
__device__ __forceinline__ void mgemm_core(
    const f16* __restrict__ Ah, const f16* __restrict__ Al,
    const f16* __restrict__ Bth, const f16* __restrict__ Btl,
    int K, int row0, int col0, f16* __restrict__ lds, f32x4 acc[2][2])
{
  const int t = threadIdx.x;
  const int lane = t & 63, w = t >> 6;
  const int wr = w >> 1, wc = w & 1;
  const int srow = t >> 2, su = t & 3;
  const size_t aoff = (size_t)(row0 + srow) * K + su * 8;
  const size_t boff = (size_t)(col0 + srow) * K + su * 8;
  const int lw = srow * 40 + su * 8;
  const int fra = wr * 32 + (lane & 15);
  const int frb = wc * 32 + (lane & 15);
  const int fu  = (lane >> 4) * 8;
  f32x4 pa0 = *(const f32x4*)(Ah + aoff);
  f32x4 pa1 = *(const f32x4*)(Al + aoff);
  f32x4 pb0 = *(const f32x4*)(Bth + boff);
  f32x4 pb1 = *(const f32x4*)(Btl + boff);
  *(f32x4*)(lds + 0    + lw) = pa0;
  *(f32x4*)(lds + 2560 + lw) = pa1;
  *(f32x4*)(lds + 5120 + lw) = pb0;
  *(f32x4*)(lds + 7680 + lw) = pb1;
  if (K > 32) {
    pa0 = *(const f32x4*)(Ah + aoff + 32);
    pa1 = *(const f32x4*)(Al + aoff + 32);
    pb0 = *(const f32x4*)(Bth + boff + 32);
    pb1 = *(const f32x4*)(Btl + boff + 32);
  }
  __syncthreads();
  int cur = 0;
  for (int kt = 32; kt <= K; kt += 32) {
    f16* rb = lds + cur * 10240;
    f16* wb = lds + (cur ^ 1) * 10240;
    f16x8 ah[2], al[2], bh[2], bl[2];
#pragma unroll
    for (int m = 0; m < 2; ++m) {
      ah[m] = *(const f16x8*)(rb + (fra + m * 16) * 40 + fu);
      al[m] = *(const f16x8*)(rb + 2560 + (fra + m * 16) * 40 + fu);
    }
#pragma unroll
    for (int n = 0; n < 2; ++n) {
      bh[n] = *(const f16x8*)(rb + 5120 + (frb + n * 16) * 40 + fu);
      bl[n] = *(const f16x8*)(rb + 7680 + (frb + n * 16) * 40 + fu);
    }
    if (kt < K) {
      *(f32x4*)(wb + 0    + lw) = pa0;
      *(f32x4*)(wb + 2560 + lw) = pa1;
      *(f32x4*)(wb + 5120 + lw) = pb0;
      *(f32x4*)(wb + 7680 + lw) = pb1;
      if (kt + 32 < K) {
        pa0 = *(const f32x4*)(Ah + aoff + kt + 32);
        pa1 = *(const f32x4*)(Al + aoff + kt + 32);
        pb0 = *(const f32x4*)(Bth + boff + kt + 32);
        pb1 = *(const f32x4*)(Btl + boff + kt + 32);
      }
    }
#pragma unroll
    for (int m = 0; m < 2; ++m)
#pragma unroll
      for (int n = 0; n < 2; ++n) {
        acc[m][n] = __builtin_amdgcn_mfma_f32_16x16x32_f16(ah[m], bh[n], acc[m][n], 0, 0, 0);
        acc[m][n] = __builtin_amdgcn_mfma_f32_16x16x32_f16(al[m], bh[n], acc[m][n], 0, 0, 0);
        acc[m][n] = __builtin_amdgcn_mfma_f32_16x16x32_f16(ah[m], bl[n], acc[m][n], 0, 0, 0);
      }
    __syncthreads();
    cur ^= 1;
  }
}

// ============ fused softmax+aggregation GEMM (short-K, double-buffered) ====
__device__ __forceinline__ void agg_core(
    const float* __restrict__ lsrc, int kvalid,
    const float* __restrict__ ldb, const float* __restrict__ lsb,
    const f16* __restrict__ Bth, const f16* __restrict__ Btl,
    int K, int row0, int col0, int rvalid,
    const float* __restrict__ selfv,
    f16* __restrict__ outh, f16* __restrict__ outl,
    f16* __restrict__ lds, float* __restrict__ fred)
{
  const int t = threadIdx.x, lane = t & 63, w = t >> 6;
  const int wr = w >> 1, wc = w & 1;
  float* zred = fred;          // [256]
  float* res  = fred + 256;    // [64] self exps
  float* riz  = fred + 320;    // [64] 1/denominator
  const int srow = t >> 2, su = t & 3;
  float sm = -1e30f;
  for (int k = t; k < kvalid; k += NTHR) sm = fmaxf(sm, lsrc[k]);
#pragma unroll
  for (int off = 1; off < 64; off <<= 1) sm = fmaxf(sm, __shfl_xor(sm, off));
  if (lane == 0) zred[w] = sm;
  __syncthreads();
  sm = fmaxf(fmaxf(zred[0], zred[1]), fmaxf(zred[2], zred[3]));
  __syncthreads();
  const bool rok = (row0 + srow) < rvalid;
  float ldr = 0.f, mr = 0.f;
  if (rok) {
    ldr = ldb[row0 + srow];
    mr  = lk(fmaxf(sm, lsb[row0 + srow]) + ldr);
  }
  const size_t boff = (size_t)(col0 + srow) * K + su * 8;
  const int lw = srow * 40 + su * 8;
  const int fra = wr * 32 + (lane & 15);
  const int frb = wc * 32 + (lane & 15);
  const int fu  = (lane >> 4) * 8;
  f32x4 acc[2][2] = {};
  float zacc = 0.f;
  f32x4 pl0 = *(const f32x4*)(lsrc + su * 8);
  f32x4 pl1 = *(const f32x4*)(lsrc + su * 8 + 4);
  f32x4 pb0 = *(const f32x4*)(Bth + boff);
  f32x4 pb1 = *(const f32x4*)(Btl + boff);
  {
    f16x8 ae, al8;
#pragma unroll
    for (int j = 0; j < 8; ++j) {
      const int k = su * 8 + j;
      const float lv = (j < 4) ? pl0[j] : pl1[j - 4];
      float f = 0.f;
      if (rok && k < kvalid) f = __expf(lk(lv + ldr) - mr);
      zacc += f;
      ae[j] = hif(f); al8[j] = lof(f);
    }
    *(f16x8*)(lds + 0    + lw) = ae;
    *(f16x8*)(lds + 2560 + lw) = al8;
    *(f32x4*)(lds + 5120 + lw) = pb0;
    *(f32x4*)(lds + 7680 + lw) = pb1;
  }
  if (K > 32) {
    pl0 = *(const f32x4*)(lsrc + 32 + su * 8);
    pl1 = *(const f32x4*)(lsrc + 32 + su * 8 + 4);
    pb0 = *(const f32x4*)(Bth + boff + 32);
    pb1 = *(const f32x4*)(Btl + boff + 32);
  }
  __syncthreads();
  int cur = 0;
  for (int kt = 32; kt <= K; kt += 32) {
    f16* rb = lds + cur * 10240;
    f16* wb = lds + (cur ^ 1) * 10240;
    f16x8 ah[2], alr[2], bh[2], bl[2];
#pragma unroll
    for (int m = 0; m < 2; ++m) {
      ah[m]  = *(const f16x8*)(rb + (fra + m * 16) * 40 + fu);
      alr[m] = *(const f16x8*)(rb + 2560 + (fra + m * 16) * 40 + fu);
    }
#pragma unroll
    for (int n = 0; n < 2; ++n) {
      bh[n] = *(const f16x8*)(rb + 5120 + (frb + n * 16) * 40 + fu);
      bl[n] = *(const f16x8*)(rb + 7680 + (frb + n * 16) * 40 + fu);
    }
    if (kt < K) {
      f16x8 ae, al8;
      const int k0 = kt + su * 8;
#pragma unroll
      for (int j = 0; j < 8; ++j) {
        const int k = k0 + j;
        const float lv = (j < 4) ? pl0[j] : pl1[j - 4];
        float f = 0.f;
        if (rok && k < kvalid) f = __expf(lk(lv + ldr) - mr);
        zacc += f;
        ae[j] = hif(f); al8[j] = lof(f);
      }
      *(f16x8*)(wb + 0    + lw) = ae;
      *(f16x8*)(wb + 2560 + lw) = al8;
      *(f32x4*)(wb + 5120 + lw) = pb0;
      *(f32x4*)(wb + 7680 + lw) = pb1;
      if (kt + 32 < K) {
        pl0 = *(const f32x4*)(lsrc + kt + 32 + su * 8);
        pl1 = *(const f32x4*)(lsrc + kt + 32 + su * 8 + 4);
        pb0 = *(const f32x4*)(Bth + boff + kt + 32);
        pb1 = *(const f32x4*)(Btl + boff + kt + 32);
      }
    }
#pragma unroll
    for (int m = 0; m < 2; ++m)
#pragma unroll
      for (int n = 0; n < 2; ++n) {
        acc[m][n] = __builtin_amdgcn_mfma_f32_16x16x32_f16(ah[m],  bh[n], acc[m][n], 0, 0, 0);
        acc[m][n] = __builtin_amdgcn_mfma_f32_16x16x32_f16(alr[m], bh[n], acc[m][n], 0, 0, 0);
        acc[m][n] = __builtin_amdgcn_mfma_f32_16x16x32_f16(ah[m],  bl[n], acc[m][n], 0, 0, 0);
      }
    __syncthreads();
    cur ^= 1;
  }
  zred[t] = zacc;
  __syncthreads();
  if (t < 64) {
    float z = zred[t * 4] + zred[t * 4 + 1] + zred[t * 4 + 2] + zred[t * 4 + 3];
    float es = 0.f, iz = 0.f;
    if (row0 + t < rvalid) {
      const float l2 = ldb[row0 + t], s2 = lsb[row0 + t];
      const float m2 = lk(fmaxf(sm, s2) + l2);
      es = __expf(lk(s2 + l2) - m2);
      iz = 1.f / (z + es);
    }
    res[t] = es; riz[t] = iz;
  }
  __syncthreads();
#pragma unroll
  for (int m = 0; m < 2; ++m)
#pragma unroll
    for (int q = 0; q < 4; ++q) {
      const int rl = wr * 32 + m * 16 + (lane >> 4) * 4 + q;
      const int gr = row0 + rl;
      if (gr >= rvalid) continue;
      const float es = res[rl], iz = riz[rl];
#pragma unroll
      for (int n = 0; n < 2; ++n) {
        const int c = col0 + wc * 32 + n * 16 + (lane & 15);
        const float v = (acc[m][n][q] + es * selfv[(size_t)gr * DD + c]) * iz;
        outh[(size_t)gr * DD + c] = hif(v);
        outl[(size_t)gr * DD + c] = lof(v);
      }
    }
}

// ======== 64x64 direct transpose+split tile (no LDS, one pass) =============
__device__ __forceinline__ void cvt_tile(
    const float* __restrict__ in, int R, int Cin,
    f16* __restrict__ oh, f16* __restrict__ ol, int ldo,
    int ti, int tj)
{
  const int t = threadIdx.x;
  const int gj0 = tj * 64 + (t & 31) * 2;
  const int i8  = (t >> 5) * 8;
  const bool c0 = gj0 < Cin, c1 = (gj0 + 1) < Cin;
  f16x8 vh0, vl0, vh1, vl1;
#pragma unroll
  for (int e = 0; e < 8; ++e) {
    const int gi = ti * 64 + i8 + e;
    float a = 0.f, b = 0.f;
    if (gi < R) {
      if (c0 && c1) {
        const float2 v = *(const float2*)(in + (size_t)gi * Cin + gj0);
        a = v.x; b = v.y;
      } else if (c0) {
        a = in[(size_t)gi * Cin + gj0];
      }
    }
    vh0[e] = hif(a); vl0[e] = lof(a);
    vh1[e] = hif(b); vl1[e] = lof(b);
  }
  const size_t o0 = (size_t)gj0 * ldo + ti * 64 + i8;
  *(f16x8*)(oh + o0) = vh0;
  *(f16x8*)(ol + o0) = vl0;
  const size_t o1 = o0 + ldo;
  *(f16x8*)(oh + o1) = vh1;
  *(f16x8*)(ol + o1) = vl1;
}

// ===== K1: weight matvecs + zero ls2/ld2 + zero M1pf/zP ====================
__global__ __launch_bounds__(NTHR) void prep1_k(
    const float* __restrict__ W1, const float* __restrict__ W2,
    const float* __restrict__ as1, const float* __restrict__ ad1,
    const float* __restrict__ as2, const float* __restrict__ ad2,
    float* __restrict__ v1s, float* __restrict__ v1d,
    float* __restrict__ v2s, float* __restrict__ v2d,
    float* __restrict__ ls2, float* __restrict__ ld2,
    float* __restrict__ M1pf, float* __restrict__ zP)
{
  const int u = blockIdx.x;
  if (u < 256) {
    const int wid  = u * 4 + (threadIdx.x >> 6);
    const int lane = threadIdx.x & 63;
    const int r = wid & 511;
    const bool l1 = (wid < 512);
    const float* W = l1 ? W1 : W2;
    const float4* a4 = (const float4*)(l1 ? as1 : as2);
    const float4* b4 = (const float4*)(l1 ? ad1 : ad2);
    const float4* w4 = (const float4*)(W + (size_t)r * DD);
    float4 w0 = w4[lane], w1 = w4[lane + 64];
    float4 a0 = a4[lane], a1 = a4[lane + 64];
    float4 b0 = b4[lane], b1 = b4[lane + 64];
    float s1 = w0.x * a0.x + w0.y * a0.y + w0.z * a0.z + w0.w * a0.w
             + w1.x * a1.x + w1.y * a1.y + w1.z * a1.z + w1.w * a1.w;
    float s2 = w0.x * b0.x + w0.y * b0.y + w0.z * b0.z + w0.w * b0.w
             + w1.x * b1.x + w1.y * b1.y + w1.z * b1.z + w1.w * b1.w;
#pragma unroll
    for (int off = 32; off > 0; off >>= 1) {
      s1 += __shfl_down(s1, off);
      s2 += __shfl_down(s2, off);
    }
    if (lane == 0) {
      (l1 ? v1s : v2s)[r] = s1;
      (l1 ? v1d : v2d)[r] = s2;
    }
  } else if (u == 256) {
    for (int i = threadIdx.x; i < 1152; i += NTHR) { ls2[i] = 0.f; ld2[i] = 0.f; }
    if (threadIdx.x < 128) zP[threadIdx.x] = 0.f;
  } else {
    // zero M1pf[100*512] floats: 16 blocks x 800 float4
    float4* p4 = (float4*)M1pf + (size_t)(u - 257) * 800;
#pragma unroll
    for (int p = 0; p < 4; ++p) {
      const int i = threadIdx.x + p * 256;
      if (i < 800) p4[i] = make_float4(0.f, 0.f, 0.f, 0.f);
    }
  }
}

// ===== K2: transposes/splits + layer-1 logits ==============================
__global__ __launch_bounds__(NTHR) void prep2_k(
    const float* __restrict__ x, const float* __restrict__ prox,
    const float* __restrict__ W1, const float* __restrict__ W2,
    const float* __restrict__ fcw,
    const float* __restrict__ v1s, const float* __restrict__ v1d,
    f16* xth, f16* xtl, f16* pth, f16* ptl,
    f16* W1th, f16* W1tl, f16* W2th, f16* W2tl, f16* fwth, f16* fwtl,
    float* __restrict__ ls1, float* __restrict__ ld1)
{
  const int b = blockIdx.x;
  if (b < 64) {
    cvt_tile(W1, 512, 512, W1th, W1tl, 512, b >> 3, b & 7);
  } else if (b < 128) {
    cvt_tile(W2, 512, 512, W2th, W2tl, 512, (b - 64) >> 3, (b - 64) & 7);
  } else if (b < 256) {
    cvt_tile(x, NS, 512, xth, xtl, NS, (b - 128) >> 3, (b - 128) & 7);
  } else if (b < 272) {
    cvt_tile(prox, PP, 512, pth, ptl, 128, (b - 256) >> 3, (b - 256) & 7);
  } else if (b < 288) {
    cvt_tile(fcw, 512, CC, fwth, fwtl, 512, (b - 272) >> 1, (b - 272) & 1);
  } else {
    const int r    = (b - 288) * 4 + (threadIdx.x >> 6);
    const int lane = threadIdx.x & 63;
    if (r >= NN) return;
    const float* row = (r < PP) ? prox + (size_t)r * DD
                                : x + (size_t)(r - PP) * DD;
    const float4* r4 = (const float4*)row;
    const float4* s4 = (const float4*)v1s;
    const float4* d4 = (const float4*)v1d;
    float4 v0 = r4[lane], v1 = r4[lane + 64];
    float4 a0 = s4[lane], a1 = s4[lane + 64];
    float4 b0 = d4[lane], b1 = d4[lane + 64];
    float s1 = v0.x * a0.x + v0.y * a0.y + v0.z * a0.z + v0.w * a0.w
             + v1.x * a1.x + v1.y * a1.y + v1.z * a1.z + v1.w * a1.w;
    float s2 = v0.x * b0.x + v0.y * b0.y + v0.z * b0.z + v0.w * b0.w
             + v1.x * b1.x + v1.y * b1.y + v1.z * b1.z + v1.w * b1.w;
#pragma unroll
    for (int off = 32; off > 0; off >>= 1) {
      s1 += __shfl_down(s1, off);
      s2 += __shfl_down(s2, off);
    }
    if (lane == 0) { ls1[r] = s1; ld1[r] = s2; }
  }
}

// ===== K3: layer-1 aggregation =============================================
// blocks [0,128): sample dsts (fused softmax, K=128)
// blocks [128,192): proxy split-K partials: 16 tiles x 4 K-chunks of 256;
//   exp-A from ls1 (global max over all 1024), partial acc atomicAdd into
//   M1pf; z partial added ONCE per (row,chunk) (col0==0 blocks only).
__global__ __launch_bounds__(NTHR) void agg1x_k(
    const float* __restrict__ ls1, const float* __restrict__ ld1,
    const f16* __restrict__ pth, const f16* __restrict__ ptl,
    const f16* __restrict__ xth, const f16* __restrict__ xtl,
    const float* __restrict__ x,
    float* __restrict__ M1pf, float* __restrict__ zP,
    f16* __restrict__ M1h, f16* __restrict__ M1l)
{
  __shared__ __align__(16) f16 lds[20480];
  __shared__ float fred[384];
  const int b = blockIdx.x;
  if (b < 128) {
    const int row0 = (b >> 3) * 64, col0 = (b & 7) * 64;
    agg_core(ls1, PP, ld1 + PP, ls1 + PP, pth, ptl, 128, row0, col0, NS,
             x, M1h + (size_t)PP * DD, M1l + (size_t)PP * DD, lds, fred);
    return;
  }
  // ---- proxy split-K partial ----
  const int t = threadIdx.x, lane = t & 63, w = t >> 6;
  const int wr = w >> 1, wc = w & 1;
  const int b2 = b - 128;
  const int tile = b2 >> 2, chunk = b2 & 3;
  const int row0 = (tile >> 3) * 64, col0 = (tile & 7) * 64;
  const int k0 = chunk * 256;
  const float* lsrc = ls1 + PP;
  float sm = -1e30f;
  for (int k = t; k < NS; k += NTHR) sm = fmaxf(sm, lsrc[k]);
#pragma unroll
  for (int off = 1; off < 64; off <<= 1) sm = fmaxf(sm, __shfl_xor(sm, off));
  if (lane == 0) fred[w] = sm;
  __syncthreads();
  sm = fmaxf(fmaxf(fred[0], fred[1]), fmaxf(fred[2], fred[3]));
  __syncthreads();
  const int srow = t >> 2, su = t & 3;
  const bool rok = (row0 + srow) < PP;
  float ldr = 0.f, mr = 0.f;
  if (rok) {
    ldr = ld1[row0 + srow];
    mr  = lk(fmaxf(sm, ls1[row0 + srow]) + ldr);
  }
  const size_t boff = (size_t)(col0 + srow) * NS + k0 + su * 8;
  const int lw = srow * 40 + su * 8;
  const int fra = wr * 32 + (lane & 15);
  const int frb = wc * 32 + (lane & 15);
  const int fu  = (lane >> 4) * 8;
  f32x4 acc[2][2] = {};
  float zacc = 0.f;
  f32x4 pl0 = *(const f32x4*)(lsrc + k0 + su * 8);
  f32x4 pl1 = *(const f32x4*)(lsrc + k0 + su * 8 + 4);
  f32x4 pb0 = *(const f32x4*)(xth + boff);
  f32x4 pb1 = *(const f32x4*)(xtl + boff);
  {
    f16x8 ae, al8;
#pragma unroll
    for (int j = 0; j < 8; ++j) {
      const float lv = (j < 4) ? pl0[j] : pl1[j - 4];
      float f = 0.f;
      if (rok) f = __expf(lk(lv + ldr) - mr);
      zacc += f;
      ae[j] = hif(f); al8[j] = lof(f);
    }
    *(f16x8*)(lds + 0    + lw) = ae;
    *(f16x8*)(lds + 2560 + lw) = al8;
    *(f32x4*)(lds + 5120 + lw) = pb0;
    *(f32x4*)(lds + 7680 + lw) = pb1;
  }
  pl0 = *(const f32x4*)(lsrc + k0 + 32 + su * 8);
  pl1 = *(const f32x4*)(lsrc + k0 + 32 + su * 8 + 4);
  pb0 = *(const f32x4*)(xth + boff + 32);
  pb1 = *(const f32x4*)(xtl + boff + 32);
  __syncthreads();
  int cur = 0;
  for (int kt = 32; kt <= 256; kt += 32) {
    f16* rb = lds + cur * 10240;
    f16* wb = lds + (cur ^ 1) * 10240;
    f16x8 ah[2], alr[2], bh[2], bl[2];
#pragma unroll
    for (int m = 0; m < 2; ++m) {
      ah[m]  = *(const f16x8*)(rb + (fra + m * 16) * 40 + fu);
      alr[m] = *(const f16x8*)(rb + 2560 + (fra + m * 16) * 40 + fu);
    }
#pragma unroll
    for (int n = 0; n < 2; ++n) {
      bh[n] = *(const f16x8*)(rb + 5120 + (frb + n * 16) * 40 + fu);
      bl[n] = *(const f16x8*)(rb + 7680 + (frb + n * 16) * 40 + fu);
    }
    if (kt < 256) {
      f16x8 ae, al8;
#pragma unroll
      for (int j = 0; j < 8; ++j) {
        const float lv = (j < 4) ? pl0[j] : pl1[j - 4];
        float f = 0.f;
        if (rok) f = __expf(lk(lv + ldr) - mr);
        zacc += f;
        ae[j] = hif(f); al8[j] = lof(f);
      }
      *(f16x8*)(wb + 0    + lw) = ae;
      *(f16x8*)(wb + 2560 + lw) = al8;
      *(f32x4*)(wb + 5120 + lw) = pb0;
      *(f32x4*)(wb + 7680 + lw) = pb1;
      if (kt + 32 < 256) {
        pl0 = *(const f32x4*)(lsrc + k0 + kt + 32 + su * 8);
        pl1 = *(const f32x4*)(lsrc + k0 + kt + 32 + su * 8 + 4);
        pb0 = *(const f32x4*)(xth + boff + kt + 32);
        pb1 = *(const f32x4*)(xtl + boff + kt + 32);
      }
    }
#pragma unroll
    for (int m = 0; m < 2; ++m)
#pragma unroll
      for (int n = 0; n < 2; ++n) {
        acc[m][n] = __builtin_amdgcn_mfma_f32_16x16x32_f16(ah[m],  bh[n], acc[m][n], 0, 0, 0);
        acc[m][n] = __builtin_amdgcn_mfma_f32_16x16x32_f16(alr[m], bh[n], acc[m][n], 0, 0, 0);
        acc[m][n] = __builtin_amdgcn_mfma_f32_16x16x32_f16(ah[m],  bl[n], acc[m][n], 0, 0, 0);
      }
    __syncthreads();
    cur ^= 1;
  }
  // z depends only on (row, chunk) — add exactly once per chunk: col0==0 only
  if (col0 == 0) {
    fred[t] = zacc;
    __syncthreads();
    if (t < 64) {
      const int r = row0 + t;
      if (r < PP) {
        float z = fred[t * 4] + fred[t * 4 + 1] + fred[t * 4 + 2] + fred[t * 4 + 3];
        atomicAdd(&zP[r], z);
      }
    }
  }
#pragma unroll
  for (int m = 0; m < 2; ++m)
#pragma unroll
    for (int q = 0; q < 4; ++q) {
      const int gr = row0 + wr * 32 + m * 16 + (lane >> 4) * 4 + q;
      if (gr >= PP) continue;
#pragma unroll
      for (int n = 0; n < 2; ++n) {
        const int c = col0 + wc * 32 + n * 16 + (lane & 15);
        atomicAdd(&M1pf[(size_t)gr * DD + c], acc[m][n][q]);
      }
    }
}

// ===== K4: h1 = relu(M1@W1 + b1); proxy rows finalized inline in A-staging;
//           emit proxy^T splits; atomic layer-2 logits =====================
__global__ __launch_bounds__(NTHR) void h1_k(
    const f16* __restrict__ M1h, const f16* __restrict__ M1l,
    const float* __restrict__ M1pf, const float* __restrict__ zP,
    const float* __restrict__ ls1, const float* __restrict__ ld1,
    const float* __restrict__ prox,
    const f16* __restrict__ W1th, const f16* __restrict__ W1tl,
    const float* __restrict__ b1,
    const float* __restrict__ v2s, const float* __restrict__ v2d,
    float* __restrict__ h1, f16* __restrict__ h1pth, f16* __restrict__ h1ptl,
    float* __restrict__ ls2, float* __restrict__ ld2)
{
  __shared__ __align__(16) f16 lds[20480];
  __shared__ float fred[384];
  float* esA = fred + 256;   // [64]
  float* izA = fred + 320;   // [64]
  const int t = threadIdx.x, lane = t & 63, w = t >> 6, wr = w >> 1, wc = w & 1;
  const int b = blockIdx.x;
  const int row0 = (b >> 3) * 64, col0 = (b & 7) * 64;
  const bool hasP = (row0 < 128);
  if (hasP) {
    // es/iz for proxy rows in this tile (same formulas as split-K partials)
    float sm = -1e30f;
    for (int k = t; k < NS; k += NTHR) sm = fmaxf(sm, ls1[PP + k]);
#pragma unroll
    for (int off = 1; off < 64; off <<= 1) sm = fmaxf(sm, __shfl_xor(sm, off));
    if (lane == 0) fred[w] = sm;
    __syncthreads();
    sm = fmaxf(fmaxf(fred[0], fred[1]), fmaxf(fred[2], fred[3]));
    if (t < 64) {
      const int r = row0 + t;
      float es = 0.f, iz = 0.f;
      if (r < PP) {
        const float ldr = ld1[r];
        const float m = lk(fmaxf(sm, ls1[r]) + ldr);
        es = __expf(lk(ls1[r] + ldr) - m);
        iz = 1.f / (zP[r] + es);
      }
      esA[t] = es; izA[t] = iz;
    }
    __syncthreads();
  }
  // ---- GEMM with mixed-source A staging ----
  const int srow = t >> 2, su = t & 3;
  const int ar = row0 + srow;
  const bool isP = ar < PP;
  const size_t aoff = (size_t)ar * DD + su * 8;
  const size_t boff = (size_t)(col0 + srow) * DD + su * 8;
  const int lw = srow * 40 + su * 8;
  const int fra = wr * 32 + (lane & 15);
  const int frb = wc * 32 + (lane & 15);
  const int fu  = (lane >> 4) * 8;
  const float esr = isP ? esA[srow] : 0.f;
  const float izr = isP ? izA[srow] : 0.f;
  f32x4 qa0, qa1, qb0, qb1, pb0, pb1;
  auto loadA = [&](int k) {
    if (isP) {
      qa0 = *(const f32x4*)(M1pf + aoff + k);
      qa1 = *(const f32x4*)(M1pf + aoff + k + 4);
      qb0 = *(const f32x4*)(prox + aoff + k);
      qb1 = *(const f32x4*)(prox + aoff + k + 4);
    } else {
      qa0 = *(const f32x4*)(M1h + aoff + k);
      qa1 = *(const f32x4*)(M1l + aoff + k);
    }
  };
  auto storeA = [&](f16* wb) {
    if (isP) {
      f16x8 hh, ll;
#pragma unroll
      for (int j = 0; j < 8; ++j) {
        const float pv = (j < 4) ? qa0[j] : qa1[j - 4];
        const float xv = (j < 4) ? qb0[j] : qb1[j - 4];
        const float v = (pv + esr * xv) * izr;
        hh[j] = hif(v); ll[j] = lof(v);
      }
      *(f16x8*)(wb + lw) = hh;
      *(f16x8*)(wb + 2560 + lw) = ll;
    } else {
      *(f32x4*)(wb + lw) = qa0;
      *(f32x4*)(wb + 2560 + lw) = qa1;
    }
  };
  f32x4 acc[2][2] = {};
  loadA(0);
  pb0 = *(const f32x4*)(W1th + boff);
  pb1 = *(const f32x4*)(W1tl + boff);
  storeA(lds);
  *(f32x4*)(lds + 5120 + lw) = pb0;
  *(f32x4*)(lds + 7680 + lw) = pb1;
  loadA(32);
  pb0 = *(const f32x4*)(W1th + boff + 32);
  pb1 = *(const f32x4*)(W1tl + boff + 32);
  __syncthreads();
  int cur = 0;
  for (int kt = 32; kt <= DD; kt += 32) {
    f16* rb = lds + cur * 10240;
    f16* wb = lds + (cur ^ 1) * 10240;
    f16x8 ah[2], al[2], bh[2], bl[2];
#pragma unroll
    for (int m = 0; m < 2; ++m) {
      ah[m] = *(const f16x8*)(rb + (fra + m * 16) * 40 + fu);
      al[m] = *(const f16x8*)(rb + 2560 + (fra + m * 16) * 40 + fu);
    }
#pragma unroll
    for (int n = 0; n < 2; ++n) {
      bh[n] = *(const f16x8*)(rb + 5120 + (frb + n * 16) * 40 + fu);
      bl[n] = *(const f16x8*)(rb + 7680 + (frb + n * 16) * 40 + fu);
    }
    if (kt < DD) {
      storeA(wb);
      *(f32x4*)(wb + 5120 + lw) = pb0;
      *(f32x4*)(wb + 7680 + lw) = pb1;
      if (kt + 32 < DD) {
        loadA(kt + 32);
        pb0 = *(const f32x4*)(W1th + boff + kt + 32);
        pb1 = *(const f32x4*)(W1tl + boff + kt + 32);
      }
    }
#pragma unroll
    for (int m = 0; m < 2; ++m)
#pragma unroll
      for (int n = 0; n < 2; ++n) {
        acc[m][n] = __builtin_amdgcn_mfma_f32_16x16x32_f16(ah[m], bh[n], acc[m][n], 0, 0, 0);
        acc[m][n] = __builtin_amdgcn_mfma_f32_16x16x32_f16(al[m], bh[n], acc[m][n], 0, 0, 0);
        acc[m][n] = __builtin_amdgcn_mfma_f32_16x16x32_f16(ah[m], bl[n], acc[m][n], 0, 0, 0);
      }
    __syncthreads();
    cur ^= 1;
  }
  // ---- epilogue ----
  const int c0 = col0 + wc * 32 + (lane & 15);
  const int c1 = c0 + 16;
  const float vs0 = v2s[c0], vs1 = v2s[c1];
  const float vd0 = v2d[c0], vd1 = v2d[c1];
  const float bb0 = b1[c0],  bb1 = b1[c1];
#pragma unroll
  for (int m = 0; m < 2; ++m)
#pragma unroll
    for (int q = 0; q < 4; ++q) {
      const int r = row0 + wr * 32 + m * 16 + (lane >> 4) * 4 + q;
      if (r >= NN) continue;
      float ps = 0.f, pd = 0.f;
#pragma unroll
      for (int n = 0; n < 2; ++n) {
        const int c = (n == 0) ? c0 : c1;
        const float v = fmaxf(acc[m][n][q] + (n == 0 ? bb0 : bb1), 0.f);
        h1[(size_t)r * DD + c] = v;
        ps += v * (n == 0 ? vs0 : vs1);
        pd += v * (n == 0 ? vd0 : vd1);
        if (r < 128) {
          const size_t o = (size_t)c * 128 + r;
          f16 hh = (f16)0.f, ll = (f16)0.f;
          if (r < PP) { hh = hif(v); ll = lof(v); }
          h1pth[o] = hh; h1ptl[o] = ll;
        }
      }
#pragma unroll
      for (int off = 1; off < 16; off <<= 1) {
        ps += __shfl_xor(ps, off);
        pd += __shfl_xor(pd, off);
      }
      if ((lane & 15) == 0) {
        atomicAdd(&ls2[r], ps);
        atomicAdd(&ld2[r], pd);
      }
    }
}

// ===== K5: layer-2 aggregation (softmax fused; sample dsts only) ===========
__global__ __launch_bounds__(NTHR) void agg2x_k(
    const float* __restrict__ ls2, const float* __restrict__ ld2,
    const f16* __restrict__ h1pth, const f16* __restrict__ h1ptl,
    const float* __restrict__ h1,
    f16* __restrict__ M2h, f16* __restrict__ M2l)
{
  __shared__ __align__(16) f16 lds[20480];
  __shared__ float fred[384];
  const int b = blockIdx.x;
  const int row0 = (b >> 3) * 64, col0 = (b & 7) * 64;
  agg_core(ls2, PP, ld2 + PP, ls2 + PP, h1pth, h1ptl, 128, row0, col0, NS,
           h1 + (size_t)PP * DD, M2h, M2l, lds, fred);
}

// ===== K6: h2 = relu(M2@W2 + b2) -> d_out (fp32) + split for fc ============
__global__ __launch_bounds__(NTHR) void h2_k(
    const f16* __restrict__ M2h, const f16* __restrict__ M2l,
    const f16* __restrict__ W2th, const f16* __restrict__ W2tl,
    const float* __restrict__ b2, float* __restrict__ h2s,
    f16* __restrict__ h2h, f16* __restrict__ h2l)
{
  __shared__ __align__(16) f16 lds[20480];
  f32x4 acc[2][2] = {};
  const int t = threadIdx.x, lane = t & 63, w = t >> 6, wr = w >> 1, wc = w & 1;
  const int b = blockIdx.x;
  const int row0 = (b >> 3) * 64, col0 = (b & 7) * 64;
  mgemm_core(M2h, M2l, W2th, W2tl, DD, row0, col0, lds, acc);
#pragma unroll
  for (int m = 0; m < 2; ++m)
#pragma unroll
    for (int q = 0; q < 4; ++q) {
      const int r = row0 + wr * 32 + m * 16 + (lane >> 4) * 4 + q;
#pragma unroll
      for (int n = 0; n < 2; ++n) {
        const int c = col0 + wc * 32 + n * 16 + (lane & 15);
        const float v = fmaxf(acc[m][n][q] + b2[c], 0.f);
        const size_t o = (size_t)r * DD + c;
        h2s[o] = v;
        h2h[o] = hif(v); h2l[o] = lof(v);
      }
    }
}

// ===== K7: preds = h2 @ fcw + fcb ==========================================
__global__ __launch_bounds__(NTHR) void fc_k(
    const f16* __restrict__ h2h, const f16* __restrict__ h2l,
    const f16* __restrict__ fwth, const f16* __restrict__ fwtl,
    const float* __restrict__ fcb, float* __restrict__ out)
{
  __shared__ __align__(16) f16 lds[20480];
  f32x4 acc[2][2] = {};
  const int t = threadIdx.x, lane = t & 63, w = t >> 6, wr = w >> 1, wc = w & 1;
  const int b = blockIdx.x;
  const int row0 = (b >> 1) * 64, col0 = (b & 1) * 64;
  mgemm_core(h2h, h2l, fwth, fwtl, DD, row0, col0, lds, acc);
#pragma unroll
  for (int m = 0; m < 2; ++m)
#pragma unroll
    for (int q = 0; q < 4; ++q) {
      const int r = row0 + wr * 32 + m * 16 + (lane >> 4) * 4 + q;
#pragma unroll
      for (int n = 0; n < 2; ++n) {
        const int c = col0 + wc * 32 + n * 16 + (lane & 15);
        if (c < CC) out[(size_t)r * CC + c] = acc[m][n][q] + fcb[c];
      }
    }
}

extern "C" void kernel_launch(void* const* d_in, const int* in_sizes, int n_in,
                              void* d_out, int out_size, void* d_ws, size_t ws_size,
                              hipStream_t stream)
{
  const float* x    = (const float*)d_in[0];
  const float* prox = (const float*)d_in[1];
  const float* W1   = (const float*)d_in[2];
  const float* as1  = (const float*)d_in[3];
  const float* ad1  = (const float*)d_in[4];
  const float* b1   = (const float*)d_in[5];
  const float* W2   = (const float*)d_in[6];
  const float* as2  = (const float*)d_in[7];
  const float* ad2  = (const float*)d_in[8];
  const float* b2   = (const float*)d_in[9];
  const float* fcw  = (const float*)d_in[10];
  const float* fcb  = (const float*)d_in[11];
  float* out = (float*)d_out;

  // fp32 workspace
  float* F = (float*)d_ws;
  float* h1   = F; F += (size_t)NN * DD;
  float* ls1  = F; F += 1152;
  float* ld1  = F; F += 1152;
  float* ls2  = F; F += 1152;
  float* ld2  = F; F += 1152;
  float* v1s  = F; F += DD;
  float* v1d  = F; F += DD;
  float* v2s  = F; F += DD;
  float* v2d  = F; F += DD;
  float* M1pf = F; F += (size_t)128 * DD;  // proxy split-K partials (fp32)
  float* zP   = F; F += 128;               // proxy denominator partials
  // f16 split workspace (all bases 16B aligned; sizes multiples of 8 halves)
  f16* H = (f16*)F;
  f16* M1h  = H; H += (size_t)1152 * DD;   // rows: 100 prox(unused) + 1024 samp
  f16* M1l  = H; H += (size_t)1152 * DD;
  f16* M2h  = H; H += (size_t)NS * DD;
  f16* M2l  = H; H += (size_t)NS * DD;
  f16* xth  = H; H += (size_t)DD * NS;     // x^T  [512][1024]
  f16* xtl  = H; H += (size_t)DD * NS;
  f16* pth  = H; H += (size_t)DD * 128;    // prox^T [512][128] (k-pad zeroed)
  f16* ptl  = H; H += (size_t)DD * 128;
  f16* W1th = H; H += (size_t)DD * DD;     // W1^T [512][512]
  f16* W1tl = H; H += (size_t)DD * DD;
  f16* W2th = H; H += (size_t)DD * DD;
  f16* W2tl = H; H += (size_t)DD * DD;
  f16* fwth = H; H += (size_t)128 * DD;    // fcw^T [128][512] (k-pad zeroed)
  f16* fwtl = H; H += (size_t)128 * DD;
  f16* h2h  = H; H += (size_t)NS * DD;
  f16* h2l  = H; H += (size_t)NS * DD;
  f16* h1pth = H; H += (size_t)DD * 128;   // h1 proxy rows ^T [512][128]
  f16* h1ptl = H; H += (size_t)DD * 128;
  float* h2s = out + (size_t)NS * CC;      // layer-2 sample out in d_out

  dim3 blk(NTHR);
  // K1: weight matvecs + zero ls2/ld2 + zero M1pf/zP
  prep1_k<<<dim3(273), blk, 0, stream>>>(W1, W2, as1, ad1, as2, ad2,
                                         v1s, v1d, v2s, v2d, ls2, ld2,
                                         M1pf, zP);
  // K2: transposes/splits + layer-1 logits
  prep2_k<<<dim3(569), blk, 0, stream>>>(x, prox, W1, W2, fcw, v1s, v1d,
      xth, xtl, pth, ptl, W1th, W1tl, W2th, W2tl, fwth, fwtl, ls1, ld1);
  // K3: layer-1 aggregation (samples fused-SM + proxy split-K partials)
  agg1x_k<<<dim3(192), blk, 0, stream>>>(ls1, ld1, pth, ptl, xth, xtl,
                                         x, M1pf, zP, M1h, M1l);
  // K4: h1 (proxy finalize inline) + proxy^T splits + atomic layer-2 logits
  h1_k<<<dim3(144), blk, 0, stream>>>(M1h, M1l, M1pf, zP, ls1, ld1, prox,
                                      W1th, W1tl, b1, v2s, v2d,
                                      h1, h1pth, h1ptl, ls2, ld2);
  // K5: layer-2 aggregation (softmax fused) -> M2 splits
  agg2x_k<<<dim3(128), blk, 0, stream>>>(ls2, ld2, h1pth, h1ptl, h1, M2h, M2l);
  // K6: h2 = relu(M2@W2+b2) -> d_out (+ split)
  h2_k<<<dim3(128), blk, 0, stream>>>(M2h, M2l, W2th, W2tl, b2, h2s, h2h, h2l);
  // K7: preds = h2 @ fcw + fcb
  fc_k<<<dim3(32), blk, 0, stream>>>(h2h, h2l, fwth, fwtl, fcb, out);
}

// Round 12
// 140.285 us; speedup vs baseline: 4.1450x; 1.0113x over previous
//
#include <hip/hip_runtime.h>

// Problem constants (complete bipartite proxy<->sample + self-loops)
#define PP 100    // proxies
#define NS 1024   // samples
#define NN 1124   // total nodes
#define DD 512    // feature dim
#define CC 100    // fc out dim
#define NTHR 256  // prep kernels
#define GT  512   // GEMM kernels (8 waves: 4 row x 2 col of 16x32)

typedef _Float16 f16;
typedef _Float16 f16x8 __attribute__((ext_vector_type(8)));
typedef float    f32x4 __attribute__((ext_vector_type(4)));

__device__ __forceinline__ float lk(float v) { return v > 0.f ? v : 0.2f * v; }
__device__ __forceinline__ f16 hif(float v) { return (f16)v; }
__device__ __forceinline__ f16 lof(float v) { return (f16)(v - (float)((f16)v)); }

#define MFMA16(a, b, c) __builtin_amdgcn_mfma_f32_16x16x32_f16(a, b, c, 0, 0, 0)

// LDS: buf k at lds + k*10240; sections Ash=0, Asl=2560, Bsh=5120, Bsl=7680
// (64 rows of 40 halves each). Double-buffered, one barrier per K-step.
// 512-thread role split: t<256 stages A (srow=(t&255)>>2, su=t&3), t>=256
// stages B. Waves: w=t>>6 in 0..7; wr=w>>1 rows [wr*16..), wc=w&1 cols
// [wc*32..); per wave acc[2] (two 16x16 frags), 6 MFMA per K-step.

// =================== MFMA split-f16 GEMM core (512 thr) ====================
__device__ __forceinline__ void mgemm_core(
    const f16* __restrict__ Ah, const f16* __restrict__ Al,
    const f16* __restrict__ Bth, const f16* __restrict__ Btl,
    int K, int row0, int col0, f16* __restrict__ lds, f32x4 acc[2])
{
  const int t = threadIdx.x;
  const int lane = t & 63, w = t >> 6;
  const int wr = w >> 1, wc = w & 1;
  const bool isA = t < 256;
  const int tt = t & 255;
  const int srow = tt >> 2, su = tt & 3;
  const int lw = srow * 40 + su * 8;
  const int sec0 = isA ? 0 : 5120, sec1 = isA ? 2560 : 7680;
  const f16* g0 = isA ? Ah : Bth;
  const f16* g1 = isA ? Al : Btl;
  const size_t goff = (size_t)((isA ? row0 : col0) + srow) * K + su * 8;
  const int fra = wr * 16 + (lane & 15);
  const int frb = wc * 32 + (lane & 15);
  const int fu  = (lane >> 4) * 8;
  f32x4 p0 = *(const f32x4*)(g0 + goff);
  f32x4 p1 = *(const f32x4*)(g1 + goff);
  *(f32x4*)(lds + sec0 + lw) = p0;
  *(f32x4*)(lds + sec1 + lw) = p1;
  if (K > 32) {
    p0 = *(const f32x4*)(g0 + goff + 32);
    p1 = *(const f32x4*)(g1 + goff + 32);
  }
  __syncthreads();
  int cur = 0;
  for (int kt = 32; kt <= K; kt += 32) {
    f16* rb = lds + cur * 10240;
    f16* wb = lds + (cur ^ 1) * 10240;
    f16x8 ah  = *(const f16x8*)(rb + fra * 40 + fu);
    f16x8 al  = *(const f16x8*)(rb + 2560 + fra * 40 + fu);
    f16x8 bh0 = *(const f16x8*)(rb + 5120 + frb * 40 + fu);
    f16x8 bl0 = *(const f16x8*)(rb + 7680 + frb * 40 + fu);
    f16x8 bh1 = *(const f16x8*)(rb + 5120 + (frb + 16) * 40 + fu);
    f16x8 bl1 = *(const f16x8*)(rb + 7680 + (frb + 16) * 40 + fu);
    if (kt < K) {
      *(f32x4*)(wb + sec0 + lw) = p0;
      *(f32x4*)(wb + sec1 + lw) = p1;
      if (kt + 32 < K) {
        p0 = *(const f32x4*)(g0 + goff + kt + 32);
        p1 = *(const f32x4*)(g1 + goff + kt + 32);
      }
    }
    acc[0] = MFMA16(ah, bh0, acc[0]);
    acc[0] = MFMA16(al, bh0, acc[0]);
    acc[0] = MFMA16(ah, bl0, acc[0]);
    acc[1] = MFMA16(ah, bh1, acc[1]);
    acc[1] = MFMA16(al, bh1, acc[1]);
    acc[1] = MFMA16(ah, bl1, acc[1]);
    __syncthreads();
    cur ^= 1;
  }
}

// ============ fused softmax+aggregation GEMM (short-K, 512 thr) ============
__device__ __forceinline__ void agg_core(
    const float* __restrict__ lsrc, int kvalid,
    const float* __restrict__ ldb, const float* __restrict__ lsb,
    const f16* __restrict__ Bth, const f16* __restrict__ Btl,
    int K, int row0, int col0, int rvalid,
    const float* __restrict__ selfv,
    f16* __restrict__ outh, f16* __restrict__ outl,
    f16* __restrict__ lds, float* __restrict__ fred)
{
  const int t = threadIdx.x, lane = t & 63, w = t >> 6;
  const int wr = w >> 1, wc = w & 1;
  float* zred = fred;          // [256]
  float* res  = fred + 256;    // [64] self exps
  float* riz  = fred + 320;    // [64] 1/denominator
  float sm = -1e30f;
  for (int k = t; k < kvalid; k += GT) sm = fmaxf(sm, lsrc[k]);
#pragma unroll
  for (int off = 1; off < 64; off <<= 1) sm = fmaxf(sm, __shfl_xor(sm, off));
  if (lane == 0) zred[w] = sm;
  __syncthreads();
  sm = fmaxf(fmaxf(fmaxf(zred[0], zred[1]), fmaxf(zred[2], zred[3])),
             fmaxf(fmaxf(zred[4], zred[5]), fmaxf(zred[6], zred[7])));
  __syncthreads();
  const bool isA = t < 256;
  const int tt = t & 255;
  const int srow = tt >> 2, su = tt & 3;
  const int lw = srow * 40 + su * 8;
  bool rok = false; float ldr = 0.f, mr = 0.f;
  if (isA && (row0 + srow) < rvalid) {
    rok = true;
    ldr = ldb[row0 + srow];
    mr  = lk(fmaxf(sm, lsb[row0 + srow]) + ldr);
  }
  const size_t boff = (size_t)(col0 + srow) * K + su * 8;
  const int fra = wr * 16 + (lane & 15);
  const int frb = wc * 32 + (lane & 15);
  const int fu  = (lane >> 4) * 8;
  f32x4 acc[2] = {};
  float zacc = 0.f;
  f32x4 p0, p1;
  if (isA) {
    p0 = *(const f32x4*)(lsrc + su * 8);
    p1 = *(const f32x4*)(lsrc + su * 8 + 4);
  } else {
    p0 = *(const f32x4*)(Bth + boff);
    p1 = *(const f32x4*)(Btl + boff);
  }
  auto stage = [&](f16* buf, int kbase) {
    if (isA) {
      f16x8 ae, al8;
#pragma unroll
      for (int j = 0; j < 8; ++j) {
        const int k = kbase + su * 8 + j;
        const float lv = (j < 4) ? p0[j] : p1[j - 4];
        float f = 0.f;
        if (rok && k < kvalid) f = __expf(lk(lv + ldr) - mr);
        zacc += f;
        ae[j] = hif(f); al8[j] = lof(f);
      }
      *(f16x8*)(buf + lw) = ae;
      *(f16x8*)(buf + 2560 + lw) = al8;
    } else {
      *(f32x4*)(buf + 5120 + lw) = p0;
      *(f32x4*)(buf + 7680 + lw) = p1;
    }
  };
  auto prefetch = [&](int k) {
    if (isA) {
      p0 = *(const f32x4*)(lsrc + k + su * 8);
      p1 = *(const f32x4*)(lsrc + k + su * 8 + 4);
    } else {
      p0 = *(const f32x4*)(Bth + boff + k);
      p1 = *(const f32x4*)(Btl + boff + k);
    }
  };
  stage(lds, 0);
  if (K > 32) prefetch(32);
  __syncthreads();
  int cur = 0;
  for (int kt = 32; kt <= K; kt += 32) {
    f16* rb = lds + cur * 10240;
    f16* wb = lds + (cur ^ 1) * 10240;
    f16x8 ah  = *(const f16x8*)(rb + fra * 40 + fu);
    f16x8 al  = *(const f16x8*)(rb + 2560 + fra * 40 + fu);
    f16x8 bh0 = *(const f16x8*)(rb + 5120 + frb * 40 + fu);
    f16x8 bl0 = *(const f16x8*)(rb + 7680 + frb * 40 + fu);
    f16x8 bh1 = *(const f16x8*)(rb + 5120 + (frb + 16) * 40 + fu);
    f16x8 bl1 = *(const f16x8*)(rb + 7680 + (frb + 16) * 40 + fu);
    if (kt < K) {
      stage(wb, kt);
      if (kt + 32 < K) prefetch(kt + 32);
    }
    acc[0] = MFMA16(ah, bh0, acc[0]);
    acc[0] = MFMA16(al, bh0, acc[0]);
    acc[0] = MFMA16(ah, bl0, acc[0]);
    acc[1] = MFMA16(ah, bh1, acc[1]);
    acc[1] = MFMA16(al, bh1, acc[1]);
    acc[1] = MFMA16(ah, bl1, acc[1]);
    __syncthreads();
    cur ^= 1;
  }
  if (t < 256) zred[t] = zacc;
  __syncthreads();
  if (t < 64) {
    float z = zred[t * 4] + zred[t * 4 + 1] + zred[t * 4 + 2] + zred[t * 4 + 3];
    float es = 0.f, iz = 0.f;
    if (row0 + t < rvalid) {
      const float l2 = ldb[row0 + t], s2 = lsb[row0 + t];
      const float m2 = lk(fmaxf(sm, s2) + l2);
      es = __expf(lk(s2 + l2) - m2);
      iz = 1.f / (z + es);
    }
    res[t] = es; riz[t] = iz;
  }
  __syncthreads();
#pragma unroll
  for (int q = 0; q < 4; ++q) {
    const int rl = wr * 16 + (lane >> 4) * 4 + q;
    const int gr = row0 + rl;
    if (gr >= rvalid) continue;
    const float es = res[rl], iz = riz[rl];
#pragma unroll
    for (int n = 0; n < 2; ++n) {
      const int c = col0 + wc * 32 + n * 16 + (lane & 15);
      const float v = (acc[n][q] + es * selfv[(size_t)gr * DD + c]) * iz;
      outh[(size_t)gr * DD + c] = hif(v);
      outl[(size_t)gr * DD + c] = lof(v);
    }
  }
}

// ======== 64x64 direct transpose+split tile (no LDS, one pass) =============
__device__ __forceinline__ void cvt_tile(
    const float* __restrict__ in, int R, int Cin,
    f16* __restrict__ oh, f16* __restrict__ ol, int ldo,
    int ti, int tj)
{
  const int t = threadIdx.x;
  const int gj0 = tj * 64 + (t & 31) * 2;
  const int i8  = (t >> 5) * 8;
  const bool c0 = gj0 < Cin, c1 = (gj0 + 1) < Cin;
  f16x8 vh0, vl0, vh1, vl1;
#pragma unroll
  for (int e = 0; e < 8; ++e) {
    const int gi = ti * 64 + i8 + e;
    float a = 0.f, b = 0.f;
    if (gi < R) {
      if (c0 && c1) {
        const float2 v = *(const float2*)(in + (size_t)gi * Cin + gj0);
        a = v.x; b = v.y;
      } else if (c0) {
        a = in[(size_t)gi * Cin + gj0];
      }
    }
    vh0[e] = hif(a); vl0[e] = lof(a);
    vh1[e] = hif(b); vl1[e] = lof(b);
  }
  const size_t o0 = (size_t)gj0 * ldo + ti * 64 + i8;
  *(f16x8*)(oh + o0) = vh0;
  *(f16x8*)(ol + o0) = vl0;
  const size_t o1 = o0 + ldo;
  *(f16x8*)(oh + o1) = vh1;
  *(f16x8*)(ol + o1) = vl1;
}

// ===== K1: weight matvecs + zero ls2/ld2 + zero M1pf/zP ====================
__global__ __launch_bounds__(NTHR) void prep1_k(
    const float* __restrict__ W1, const float* __restrict__ W2,
    const float* __restrict__ as1, const float* __restrict__ ad1,
    const float* __restrict__ as2, const float* __restrict__ ad2,
    float* __restrict__ v1s, float* __restrict__ v1d,
    float* __restrict__ v2s, float* __restrict__ v2d,
    float* __restrict__ ls2, float* __restrict__ ld2,
    float* __restrict__ M1pf, float* __restrict__ zP)
{
  const int u = blockIdx.x;
  if (u < 256) {
    const int wid  = u * 4 + (threadIdx.x >> 6);
    const int lane = threadIdx.x & 63;
    const int r = wid & 511;
    const bool l1 = (wid < 512);
    const float* W = l1 ? W1 : W2;
    const float4* a4 = (const float4*)(l1 ? as1 : as2);
    const float4* b4 = (const float4*)(l1 ? ad1 : ad2);
    const float4* w4 = (const float4*)(W + (size_t)r * DD);
    float4 w0 = w4[lane], w1 = w4[lane + 64];
    float4 a0 = a4[lane], a1 = a4[lane + 64];
    float4 b0 = b4[lane], b1 = b4[lane + 64];
    float s1 = w0.x * a0.x + w0.y * a0.y + w0.z * a0.z + w0.w * a0.w
             + w1.x * a1.x + w1.y * a1.y + w1.z * a1.z + w1.w * a1.w;
    float s2 = w0.x * b0.x + w0.y * b0.y + w0.z * b0.z + w0.w * b0.w
             + w1.x * b1.x + w1.y * b1.y + w1.z * b1.z + w1.w * b1.w;
#pragma unroll
    for (int off = 32; off > 0; off >>= 1) {
      s1 += __shfl_down(s1, off);
      s2 += __shfl_down(s2, off);
    }
    if (lane == 0) {
      (l1 ? v1s : v2s)[r] = s1;
      (l1 ? v1d : v2d)[r] = s2;
    }
  } else if (u == 256) {
    for (int i = threadIdx.x; i < 1152; i += NTHR) { ls2[i] = 0.f; ld2[i] = 0.f; }
    if (threadIdx.x < 128) zP[threadIdx.x] = 0.f;
  } else {
    float4* p4 = (float4*)M1pf + (size_t)(u - 257) * 800;
#pragma unroll
    for (int p = 0; p < 4; ++p) {
      const int i = threadIdx.x + p * 256;
      if (i < 800) p4[i] = make_float4(0.f, 0.f, 0.f, 0.f);
    }
  }
}

// ===== K2: transposes/splits + layer-1 logits ==============================
__global__ __launch_bounds__(NTHR) void prep2_k(
    const float* __restrict__ x, const float* __restrict__ prox,
    const float* __restrict__ W1, const float* __restrict__ W2,
    const float* __restrict__ fcw,
    const float* __restrict__ v1s, const float* __restrict__ v1d,
    f16* xth, f16* xtl, f16* pth, f16* ptl,
    f16* W1th, f16* W1tl, f16* W2th, f16* W2tl, f16* fwth, f16* fwtl,
    float* __restrict__ ls1, float* __restrict__ ld1)
{
  const int b = blockIdx.x;
  if (b < 64) {
    cvt_tile(W1, 512, 512, W1th, W1tl, 512, b >> 3, b & 7);
  } else if (b < 128) {
    cvt_tile(W2, 512, 512, W2th, W2tl, 512, (b - 64) >> 3, (b - 64) & 7);
  } else if (b < 256) {
    cvt_tile(x, NS, 512, xth, xtl, NS, (b - 128) >> 3, (b - 128) & 7);
  } else if (b < 272) {
    cvt_tile(prox, PP, 512, pth, ptl, 128, (b - 256) >> 3, (b - 256) & 7);
  } else if (b < 288) {
    cvt_tile(fcw, 512, CC, fwth, fwtl, 512, (b - 272) >> 1, (b - 272) & 1);
  } else {
    const int r    = (b - 288) * 4 + (threadIdx.x >> 6);
    const int lane = threadIdx.x & 63;
    if (r >= NN) return;
    const float* row = (r < PP) ? prox + (size_t)r * DD
                                : x + (size_t)(r - PP) * DD;
    const float4* r4 = (const float4*)row;
    const float4* s4 = (const float4*)v1s;
    const float4* d4 = (const float4*)v1d;
    float4 v0 = r4[lane], v1 = r4[lane + 64];
    float4 a0 = s4[lane], a1 = s4[lane + 64];
    float4 b0 = d4[lane], b1 = d4[lane + 64];
    float s1 = v0.x * a0.x + v0.y * a0.y + v0.z * a0.z + v0.w * a0.w
             + v1.x * a1.x + v1.y * a1.y + v1.z * a1.z + v1.w * a1.w;
    float s2 = v0.x * b0.x + v0.y * b0.y + v0.z * b0.z + v0.w * b0.w
             + v1.x * b1.x + v1.y * b1.y + v1.z * b1.z + v1.w * b1.w;
#pragma unroll
    for (int off = 32; off > 0; off >>= 1) {
      s1 += __shfl_down(s1, off);
      s2 += __shfl_down(s2, off);
    }
    if (lane == 0) { ls1[r] = s1; ld1[r] = s2; }
  }
}

// ===== K3: layer-1 aggregation (512 thr) ===================================
// blocks [0,128): sample dsts (fused softmax, K=128)
// blocks [128,192): proxy split-K partials (16 tiles x 4 chunks of 256)
__global__ __launch_bounds__(GT) void agg1x_k(
    const float* __restrict__ ls1, const float* __restrict__ ld1,
    const f16* __restrict__ pth, const f16* __restrict__ ptl,
    const f16* __restrict__ xth, const f16* __restrict__ xtl,
    const float* __restrict__ x,
    float* __restrict__ M1pf, float* __restrict__ zP,
    f16* __restrict__ M1h, f16* __restrict__ M1l)
{
  __shared__ __align__(16) f16 lds[20480];
  __shared__ float fred[384];
  const int b = blockIdx.x;
  if (b < 128) {
    const int row0 = (b >> 3) * 64, col0 = (b & 7) * 64;
    agg_core(ls1, PP, ld1 + PP, ls1 + PP, pth, ptl, 128, row0, col0, NS,
             x, M1h + (size_t)PP * DD, M1l + (size_t)PP * DD, lds, fred);
    return;
  }
  // ---- proxy split-K partial ----
  const int t = threadIdx.x, lane = t & 63, w = t >> 6;
  const int wr = w >> 1, wc = w & 1;
  const int b2 = b - 128;
  const int tile = b2 >> 2, chunk = b2 & 3;
  const int row0 = (tile >> 3) * 64, col0 = (tile & 7) * 64;
  const int k0 = chunk * 256;
  const float* lsrc = ls1 + PP;
  float sm = -1e30f;
  for (int k = t; k < NS; k += GT) sm = fmaxf(sm, lsrc[k]);
#pragma unroll
  for (int off = 1; off < 64; off <<= 1) sm = fmaxf(sm, __shfl_xor(sm, off));
  if (lane == 0) fred[w] = sm;
  __syncthreads();
  sm = fmaxf(fmaxf(fmaxf(fred[0], fred[1]), fmaxf(fred[2], fred[3])),
             fmaxf(fmaxf(fred[4], fred[5]), fmaxf(fred[6], fred[7])));
  __syncthreads();
  const bool isA = t < 256;
  const int tt = t & 255;
  const int srow = tt >> 2, su = tt & 3;
  const int lw = srow * 40 + su * 8;
  bool rok = false; float ldr = 0.f, mr = 0.f;
  if (isA && (row0 + srow) < PP) {
    rok = true;
    ldr = ld1[row0 + srow];
    mr  = lk(fmaxf(sm, ls1[row0 + srow]) + ldr);
  }
  const size_t boff = (size_t)(col0 + srow) * NS + k0 + su * 8;
  const int fra = wr * 16 + (lane & 15);
  const int frb = wc * 32 + (lane & 15);
  const int fu  = (lane >> 4) * 8;
  f32x4 acc[2] = {};
  float zacc = 0.f;
  f32x4 p0, p1;
  auto prefetch = [&](int k) {
    if (isA) {
      p0 = *(const f32x4*)(lsrc + k0 + k + su * 8);
      p1 = *(const f32x4*)(lsrc + k0 + k + su * 8 + 4);
    } else {
      p0 = *(const f32x4*)(xth + boff + k);
      p1 = *(const f32x4*)(xtl + boff + k);
    }
  };
  auto stage = [&](f16* buf) {
    if (isA) {
      f16x8 ae, al8;
#pragma unroll
      for (int j = 0; j < 8; ++j) {
        const float lv = (j < 4) ? p0[j] : p1[j - 4];
        float f = 0.f;
        if (rok) f = __expf(lk(lv + ldr) - mr);
        zacc += f;
        ae[j] = hif(f); al8[j] = lof(f);
      }
      *(f16x8*)(buf + lw) = ae;
      *(f16x8*)(buf + 2560 + lw) = al8;
    } else {
      *(f32x4*)(buf + 5120 + lw) = p0;
      *(f32x4*)(buf + 7680 + lw) = p1;
    }
  };
  prefetch(0);
  stage(lds);
  prefetch(32);
  __syncthreads();
  int cur = 0;
  for (int kt = 32; kt <= 256; kt += 32) {
    f16* rb = lds + cur * 10240;
    f16* wb = lds + (cur ^ 1) * 10240;
    f16x8 ah  = *(const f16x8*)(rb + fra * 40 + fu);
    f16x8 al  = *(const f16x8*)(rb + 2560 + fra * 40 + fu);
    f16x8 bh0 = *(const f16x8*)(rb + 5120 + frb * 40 + fu);
    f16x8 bl0 = *(const f16x8*)(rb + 7680 + frb * 40 + fu);
    f16x8 bh1 = *(const f16x8*)(rb + 5120 + (frb + 16) * 40 + fu);
    f16x8 bl1 = *(const f16x8*)(rb + 7680 + (frb + 16) * 40 + fu);
    if (kt < 256) {
      stage(wb);
      if (kt + 32 < 256) prefetch(kt + 32);
    }
    acc[0] = MFMA16(ah, bh0, acc[0]);
    acc[0] = MFMA16(al, bh0, acc[0]);
    acc[0] = MFMA16(ah, bl0, acc[0]);
    acc[1] = MFMA16(ah, bh1, acc[1]);
    acc[1] = MFMA16(al, bh1, acc[1]);
    acc[1] = MFMA16(ah, bl1, acc[1]);
    __syncthreads();
    cur ^= 1;
  }
  // z depends only on (row, chunk) — add exactly once per chunk: col0==0 only
  if (col0 == 0) {
    if (t < 256) fred[t] = zacc;
    __syncthreads();
    if (t < 64) {
      const int r = row0 + t;
      if (r < PP) {
        float z = fred[t * 4] + fred[t * 4 + 1] + fred[t * 4 + 2] + fred[t * 4 + 3];
        atomicAdd(&zP[r], z);
      }
    }
  }
#pragma unroll
  for (int q = 0; q < 4; ++q) {
    const int gr = row0 + wr * 16 + (lane >> 4) * 4 + q;
    if (gr >= PP) continue;
#pragma unroll
    for (int n = 0; n < 2; ++n) {
      const int c = col0 + wc * 32 + n * 16 + (lane & 15);
      atomicAdd(&M1pf[(size_t)gr * DD + c], acc[n][q]);
    }
  }
}

// ===== K4: h1 = relu(M1@W1 + b1) (512 thr); proxy finalize inline;
//           emit proxy^T splits; atomic layer-2 logits =====================
__global__ __launch_bounds__(GT) void h1_k(
    const f16* __restrict__ M1h, const f16* __restrict__ M1l,
    const float* __restrict__ M1pf, const float* __restrict__ zP,
    const float* __restrict__ ls1, const float* __restrict__ ld1,
    const float* __restrict__ prox,
    const f16* __restrict__ W1th, const f16* __restrict__ W1tl,
    const float* __restrict__ b1,
    const float* __restrict__ v2s, const float* __restrict__ v2d,
    float* __restrict__ h1, f16* __restrict__ h1pth, f16* __restrict__ h1ptl,
    float* __restrict__ ls2, float* __restrict__ ld2)
{
  __shared__ __align__(16) f16 lds[20480];
  __shared__ float fred[384];
  float* esA = fred + 256;   // [64]
  float* izA = fred + 320;   // [64]
  const int t = threadIdx.x, lane = t & 63, w = t >> 6;
  const int wr = w >> 1, wc = w & 1;
  const int b = blockIdx.x;
  const int row0 = (b >> 3) * 64, col0 = (b & 7) * 64;
  const bool hasP = (row0 < 128);
  if (hasP) {
    float sm = -1e30f;
    for (int k = t; k < NS; k += GT) sm = fmaxf(sm, ls1[PP + k]);
#pragma unroll
    for (int off = 1; off < 64; off <<= 1) sm = fmaxf(sm, __shfl_xor(sm, off));
    if (lane == 0) fred[w] = sm;
    __syncthreads();
    sm = fmaxf(fmaxf(fmaxf(fred[0], fred[1]), fmaxf(fred[2], fred[3])),
               fmaxf(fmaxf(fred[4], fred[5]), fmaxf(fred[6], fred[7])));
    if (t < 64) {
      const int r = row0 + t;
      float es = 0.f, iz = 0.f;
      if (r < PP) {
        const float ldr = ld1[r];
        const float m = lk(fmaxf(sm, ls1[r]) + ldr);
        es = __expf(lk(ls1[r] + ldr) - m);
        iz = 1.f / (zP[r] + es);
      }
      esA[t] = es; izA[t] = iz;
    }
    __syncthreads();
  }
  // ---- GEMM with role-split staging (A: mixed-source, B: W1 splits) ----
  const bool isA = t < 256;
  const int tt = t & 255;
  const int srow = tt >> 2, su = tt & 3;
  const int lw = srow * 40 + su * 8;
  const int ar = row0 + srow;
  const bool isP = isA && (ar < PP);
  const size_t aoff = (size_t)ar * DD + su * 8;
  const size_t boff = (size_t)(col0 + srow) * DD + su * 8;
  const int fra = wr * 16 + (lane & 15);
  const int frb = wc * 32 + (lane & 15);
  const int fu  = (lane >> 4) * 8;
  const float esr = isP ? esA[srow] : 0.f;
  const float izr = isP ? izA[srow] : 0.f;
  f32x4 qa0, qa1, qb0, qb1;
  auto loadS = [&](int k) {
    if (isA) {
      if (isP) {
        qa0 = *(const f32x4*)(M1pf + aoff + k);
        qa1 = *(const f32x4*)(M1pf + aoff + k + 4);
        qb0 = *(const f32x4*)(prox + aoff + k);
        qb1 = *(const f32x4*)(prox + aoff + k + 4);
      } else {
        qa0 = *(const f32x4*)(M1h + aoff + k);
        qa1 = *(const f32x4*)(M1l + aoff + k);
      }
    } else {
      qa0 = *(const f32x4*)(W1th + boff + k);
      qa1 = *(const f32x4*)(W1tl + boff + k);
    }
  };
  auto storeS = [&](f16* wb) {
    if (isA) {
      if (isP) {
        f16x8 hh, ll;
#pragma unroll
        for (int j = 0; j < 8; ++j) {
          const float pv = (j < 4) ? qa0[j] : qa1[j - 4];
          const float xv = (j < 4) ? qb0[j] : qb1[j - 4];
          const float v = (pv + esr * xv) * izr;
          hh[j] = hif(v); ll[j] = lof(v);
        }
        *(f16x8*)(wb + lw) = hh;
        *(f16x8*)(wb + 2560 + lw) = ll;
      } else {
        *(f32x4*)(wb + lw) = qa0;
        *(f32x4*)(wb + 2560 + lw) = qa1;
      }
    } else {
      *(f32x4*)(wb + 5120 + lw) = qa0;
      *(f32x4*)(wb + 7680 + lw) = qa1;
    }
  };
  f32x4 acc[2] = {};
  loadS(0);
  storeS(lds);
  loadS(32);
  __syncthreads();
  int cur = 0;
  for (int kt = 32; kt <= DD; kt += 32) {
    f16* rb = lds + cur * 10240;
    f16* wb = lds + (cur ^ 1) * 10240;
    f16x8 ah  = *(const f16x8*)(rb + fra * 40 + fu);
    f16x8 al  = *(const f16x8*)(rb + 2560 + fra * 40 + fu);
    f16x8 bh0 = *(const f16x8*)(rb + 5120 + frb * 40 + fu);
    f16x8 bl0 = *(const f16x8*)(rb + 7680 + frb * 40 + fu);
    f16x8 bh1 = *(const f16x8*)(rb + 5120 + (frb + 16) * 40 + fu);
    f16x8 bl1 = *(const f16x8*)(rb + 7680 + (frb + 16) * 40 + fu);
    if (kt < DD) {
      storeS(wb);
      if (kt + 32 < DD) loadS(kt + 32);
    }
    acc[0] = MFMA16(ah, bh0, acc[0]);
    acc[0] = MFMA16(al, bh0, acc[0]);
    acc[0] = MFMA16(ah, bl0, acc[0]);
    acc[1] = MFMA16(ah, bh1, acc[1]);
    acc[1] = MFMA16(al, bh1, acc[1]);
    acc[1] = MFMA16(ah, bl1, acc[1]);
    __syncthreads();
    cur ^= 1;
  }
  // ---- epilogue ----
  const int c0 = col0 + wc * 32 + (lane & 15);
  const int c1 = c0 + 16;
  const float vs0 = v2s[c0], vs1 = v2s[c1];
  const float vd0 = v2d[c0], vd1 = v2d[c1];
  const float bb0 = b1[c0],  bb1 = b1[c1];
#pragma unroll
  for (int q = 0; q < 4; ++q) {
    const int r = row0 + wr * 16 + (lane >> 4) * 4 + q;
    if (r >= NN) continue;
    float ps = 0.f, pd = 0.f;
#pragma unroll
    for (int n = 0; n < 2; ++n) {
      const int c = (n == 0) ? c0 : c1;
      const float v = fmaxf(acc[n][q] + (n == 0 ? bb0 : bb1), 0.f);
      h1[(size_t)r * DD + c] = v;
      ps += v * (n == 0 ? vs0 : vs1);
      pd += v * (n == 0 ? vd0 : vd1);
      if (r < 128) {
        const size_t o = (size_t)c * 128 + r;
        f16 hh = (f16)0.f, ll = (f16)0.f;
        if (r < PP) { hh = hif(v); ll = lof(v); }
        h1pth[o] = hh; h1ptl[o] = ll;
      }
    }
#pragma unroll
    for (int off = 1; off < 16; off <<= 1) {
      ps += __shfl_xor(ps, off);
      pd += __shfl_xor(pd, off);
    }
    if ((lane & 15) == 0) {
      atomicAdd(&ls2[r], ps);
      atomicAdd(&ld2[r], pd);
    }
  }
}

// ===== K5: layer-2 aggregation (softmax fused; sample dsts only) ===========
__global__ __launch_bounds__(GT) void agg2x_k(
    const float* __restrict__ ls2, const float* __restrict__ ld2,
    const f16* __restrict__ h1pth, const f16* __restrict__ h1ptl,
    const float* __restrict__ h1,
    f16* __restrict__ M2h, f16* __restrict__ M2l)
{
  __shared__ __align__(16) f16 lds[20480];
  __shared__ float fred[384];
  const int b = blockIdx.x;
  const int row0 = (b >> 3) * 64, col0 = (b & 7) * 64;
  agg_core(ls2, PP, ld2 + PP, ls2 + PP, h1pth, h1ptl, 128, row0, col0, NS,
           h1 + (size_t)PP * DD, M2h, M2l, lds, fred);
}

// ===== K6: h2 = relu(M2@W2 + b2) -> d_out (fp32) + split for fc ============
__global__ __launch_bounds__(GT) void h2_k(
    const f16* __restrict__ M2h, const f16* __restrict__ M2l,
    const f16* __restrict__ W2th, const f16* __restrict__ W2tl,
    const float* __restrict__ b2, float* __restrict__ h2s,
    f16* __restrict__ h2h, f16* __restrict__ h2l)
{
  __shared__ __align__(16) f16 lds[20480];
  f32x4 acc[2] = {};
  const int t = threadIdx.x, lane = t & 63, w = t >> 6;
  const int wr = w >> 1, wc = w & 1;
  const int b = blockIdx.x;
  const int row0 = (b >> 3) * 64, col0 = (b & 7) * 64;
  mgemm_core(M2h, M2l, W2th, W2tl, DD, row0, col0, lds, acc);
#pragma unroll
  for (int q = 0; q < 4; ++q) {
    const int r = row0 + wr * 16 + (lane >> 4) * 4 + q;
#pragma unroll
    for (int n = 0; n < 2; ++n) {
      const int c = col0 + wc * 32 + n * 16 + (lane & 15);
      const float v = fmaxf(acc[n][q] + b2[c], 0.f);
      const size_t o = (size_t)r * DD + c;
      h2s[o] = v;
      h2h[o] = hif(v); h2l[o] = lof(v);
    }
  }
}

// ===== K7: preds = h2 @ fcw + fcb ==========================================
__global__ __launch_bounds__(GT) void fc_k(
    const f16* __restrict__ h2h, const f16* __restrict__ h2l,
    const f16* __restrict__ fwth, const f16* __restrict__ fwtl,
    const float* __restrict__ fcb, float* __restrict__ out)
{
  __shared__ __align__(16) f16 lds[20480];
  f32x4 acc[2] = {};
  const int t = threadIdx.x, lane = t & 63, w = t >> 6;
  const int wr = w >> 1, wc = w & 1;
  const int b = blockIdx.x;
  const int row0 = (b >> 1) * 64, col0 = (b & 1) * 64;
  mgemm_core(h2h, h2l, fwth, fwtl, DD, row0, col0, lds, acc);
#pragma unroll
  for (int q = 0; q < 4; ++q) {
    const int r = row0 + wr * 16 + (lane >> 4) * 4 + q;
#pragma unroll
    for (int n = 0; n < 2; ++n) {
      const int c = col0 + wc * 32 + n * 16 + (lane & 15);
      if (c < CC) out[(size_t)r * CC + c] = acc[n][q] + fcb[c];
    }
  }
}

extern "C" void kernel_launch(void* const* d_in, const int* in_sizes, int n_in,
                              void* d_out, int out_size, void* d_ws, size_t ws_size,
                              hipStream_t stream)
{
  const float* x    = (const float*)d_in[0];
  const float* prox = (const float*)d_in[1];
  const float* W1   = (const float*)d_in[2];
  const float* as1  = (const float*)d_in[3];
  const float* ad1  = (const float*)d_in[4];
  const float* b1   = (const float*)d_in[5];
  const float* W2   = (const float*)d_in[6];
  const float* as2  = (const float*)d_in[7];
  const float* ad2  = (const float*)d_in[8];
  const float* b2   = (const float*)d_in[9];
  const float* fcw  = (const float*)d_in[10];
  const float* fcb  = (const float*)d_in[11];
  float* out = (float*)d_out;

  // fp32 workspace
  float* F = (float*)d_ws;
  float* h1   = F; F += (size_t)NN * DD;
  float* ls1  = F; F += 1152;
  float* ld1  = F; F += 1152;
  float* ls2  = F; F += 1152;
  float* ld2  = F; F += 1152;
  float* v1s  = F; F += DD;
  float* v1d  = F; F += DD;
  float* v2s  = F; F += DD;
  float* v2d  = F; F += DD;
  float* M1pf = F; F += (size_t)128 * DD;  // proxy split-K partials (fp32)
  float* zP   = F; F += 128;               // proxy denominator partials
  // f16 split workspace (all bases 16B aligned; sizes multiples of 8 halves)
  f16* H = (f16*)F;
  f16* M1h  = H; H += (size_t)1152 * DD;   // rows: 100 prox(unused) + 1024 samp
  f16* M1l  = H; H += (size_t)1152 * DD;
  f16* M2h  = H; H += (size_t)NS * DD;
  f16* M2l  = H; H += (size_t)NS * DD;
  f16* xth  = H; H += (size_t)DD * NS;     // x^T  [512][1024]
  f16* xtl  = H; H += (size_t)DD * NS;
  f16* pth  = H; H += (size_t)DD * 128;    // prox^T [512][128] (k-pad zeroed)
  f16* ptl  = H; H += (size_t)DD * 128;
  f16* W1th = H; H += (size_t)DD * DD;     // W1^T [512][512]
  f16* W1tl = H; H += (size_t)DD * DD;
  f16* W2th = H; H += (size_t)DD * DD;
  f16* W2tl = H; H += (size_t)DD * DD;
  f16* fwth = H; H += (size_t)128 * DD;    // fcw^T [128][512] (k-pad zeroed)
  f16* fwtl = H; H += (size_t)128 * DD;
  f16* h2h  = H; H += (size_t)NS * DD;
  f16* h2l  = H; H += (size_t)NS * DD;
  f16* h1pth = H; H += (size_t)DD * 128;   // h1 proxy rows ^T [512][128]
  f16* h1ptl = H; H += (size_t)DD * 128;
  float* h2s = out + (size_t)NS * CC;      // layer-2 sample out in d_out

  // K1: weight matvecs + zero ls2/ld2 + zero M1pf/zP
  prep1_k<<<dim3(273), dim3(NTHR), 0, stream>>>(W1, W2, as1, ad1, as2, ad2,
                                                v1s, v1d, v2s, v2d, ls2, ld2,
                                                M1pf, zP);
  // K2: transposes/splits + layer-1 logits
  prep2_k<<<dim3(569), dim3(NTHR), 0, stream>>>(x, prox, W1, W2, fcw, v1s, v1d,
      xth, xtl, pth, ptl, W1th, W1tl, W2th, W2tl, fwth, fwtl, ls1, ld1);
  // K3: layer-1 aggregation (samples fused-SM + proxy split-K partials)
  agg1x_k<<<dim3(192), dim3(GT), 0, stream>>>(ls1, ld1, pth, ptl, xth, xtl,
                                              x, M1pf, zP, M1h, M1l);
  // K4: h1 (proxy finalize inline) + proxy^T splits + atomic layer-2 logits
  h1_k<<<dim3(144), dim3(GT), 0, stream>>>(M1h, M1l, M1pf, zP, ls1, ld1, prox,
                                           W1th, W1tl, b1, v2s, v2d,
                                           h1, h1pth, h1ptl, ls2, ld2);
  // K5: layer-2 aggregation (softmax fused) -> M2 splits
  agg2x_k<<<dim3(128), dim3(GT), 0, stream>>>(ls2, ld2, h1pth, h1ptl, h1,
                                              M2h, M2l);
  // K6: h2 = relu(M2@W2+b2) -> d_out (+ split)
  h2_k<<<dim3(128), dim3(GT), 0, stream>>>(M2h, M2l, W2th, W2tl, b2,
                                           h2s, h2h, h2l);
  // K7: preds = h2 @ fcw + fcb
  fc_k<<<dim3(32), dim3(GT), 0, stream>>>(h2h, h2l, fwth, fwtl, fcb, out);
}

// Round 13
// 138.482 us; speedup vs baseline: 4.1989x; 1.0130x over previous
//
#include <hip/hip_runtime.h>

// Problem constants (complete bipartite proxy<->sample + self-loops)
#define PP 100    // proxies
#define NS 1024   // samples
#define NN 1124   // total nodes
#define DD 512    // feature dim
#define CC 100    // fc out dim
#define NTHR 256  // prep kernels
#define GT  512   // GEMM kernels (8 waves: 4 row x 2 col of 16x32)

typedef _Float16 f16;
typedef _Float16 f16x8 __attribute__((ext_vector_type(8)));
typedef float    f32x4 __attribute__((ext_vector_type(4)));

__device__ __forceinline__ float lk(float v) { return v > 0.f ? v : 0.2f * v; }
__device__ __forceinline__ f16 hif(float v) { return (f16)v; }
__device__ __forceinline__ f16 lof(float v) { return (f16)(v - (float)((f16)v)); }

#define MFMA16(a, b, c) __builtin_amdgcn_mfma_f32_16x16x32_f16(a, b, c, 0, 0, 0)

// LDS (BK=64): rows of 72 halves (64 + 8 pad). Sections within one buffer:
// Ash=0, Asl=4608, Bsh=9216, Bsl=13824; buffer size 18432 halves.
// Double-buffered: buf k at lds + k*18432 (36864 halves = 72 KiB total).
// 512-thread role split: t<256 stages A (row tt>>2, 16-half unit tt&3),
// t>=256 stages B. Waves: wr=w>>1 rows [wr*16..), wc=w&1 cols [wc*32..);
// per wave acc[2], 12 MFMA per K-step (two k-slices of 32).
#define LROW   72
#define SEC_AL 4608
#define SEC_BH 9216
#define SEC_BL 13824
#define BUFSZ  18432

// =================== MFMA split-f16 GEMM core (512 thr, BK=64) =============
__device__ __forceinline__ void mgemm_core(
    const f16* __restrict__ Ah, const f16* __restrict__ Al,
    const f16* __restrict__ Bth, const f16* __restrict__ Btl,
    int K, int row0, int col0, f16* __restrict__ lds, f32x4 acc[2])
{
  const int t = threadIdx.x;
  const int lane = t & 63, w = t >> 6;
  const int wr = w >> 1, wc = w & 1;
  const bool isA = t < 256;
  const int tt = t & 255;
  const int srow = tt >> 2, su = tt & 3;
  const int lw = srow * LROW + su * 16;
  const int sec0 = isA ? 0 : SEC_BH, sec1 = isA ? SEC_AL : SEC_BL;
  const f16* g0 = isA ? Ah : Bth;
  const f16* g1 = isA ? Al : Btl;
  const size_t goff = (size_t)((isA ? row0 : col0) + srow) * K + su * 16;
  const int fra = wr * 16 + (lane & 15);
  const int frb = wc * 32 + (lane & 15);
  const int fu  = (lane >> 4) * 8;
  f32x4 p0 = *(const f32x4*)(g0 + goff);
  f32x4 p1 = *(const f32x4*)(g0 + goff + 8);
  f32x4 p2 = *(const f32x4*)(g1 + goff);
  f32x4 p3 = *(const f32x4*)(g1 + goff + 8);
  *(f32x4*)(lds + sec0 + lw)     = p0;
  *(f32x4*)(lds + sec0 + lw + 8) = p1;
  *(f32x4*)(lds + sec1 + lw)     = p2;
  *(f32x4*)(lds + sec1 + lw + 8) = p3;
  if (K > 64) {
    p0 = *(const f32x4*)(g0 + goff + 64);
    p1 = *(const f32x4*)(g0 + goff + 72);
    p2 = *(const f32x4*)(g1 + goff + 64);
    p3 = *(const f32x4*)(g1 + goff + 72);
  }
  __syncthreads();
  int cur = 0;
  for (int kt = 64; kt <= K; kt += 64) {
    f16* rb = lds + cur * BUFSZ;
    f16* wb = lds + (cur ^ 1) * BUFSZ;
    f16x8 ah0  = *(const f16x8*)(rb + fra * LROW + fu);
    f16x8 ah1  = *(const f16x8*)(rb + fra * LROW + 32 + fu);
    f16x8 al0  = *(const f16x8*)(rb + SEC_AL + fra * LROW + fu);
    f16x8 al1  = *(const f16x8*)(rb + SEC_AL + fra * LROW + 32 + fu);
    f16x8 bh00 = *(const f16x8*)(rb + SEC_BH + frb * LROW + fu);
    f16x8 bh01 = *(const f16x8*)(rb + SEC_BH + frb * LROW + 32 + fu);
    f16x8 bl00 = *(const f16x8*)(rb + SEC_BL + frb * LROW + fu);
    f16x8 bl01 = *(const f16x8*)(rb + SEC_BL + frb * LROW + 32 + fu);
    f16x8 bh10 = *(const f16x8*)(rb + SEC_BH + (frb + 16) * LROW + fu);
    f16x8 bh11 = *(const f16x8*)(rb + SEC_BH + (frb + 16) * LROW + 32 + fu);
    f16x8 bl10 = *(const f16x8*)(rb + SEC_BL + (frb + 16) * LROW + fu);
    f16x8 bl11 = *(const f16x8*)(rb + SEC_BL + (frb + 16) * LROW + 32 + fu);
    if (kt < K) {
      *(f32x4*)(wb + sec0 + lw)     = p0;
      *(f32x4*)(wb + sec0 + lw + 8) = p1;
      *(f32x4*)(wb + sec1 + lw)     = p2;
      *(f32x4*)(wb + sec1 + lw + 8) = p3;
      if (kt + 64 < K) {
        p0 = *(const f32x4*)(g0 + goff + kt + 64);
        p1 = *(const f32x4*)(g0 + goff + kt + 72);
        p2 = *(const f32x4*)(g1 + goff + kt + 64);
        p3 = *(const f32x4*)(g1 + goff + kt + 72);
      }
    }
    acc[0] = MFMA16(ah0, bh00, acc[0]);
    acc[0] = MFMA16(al0, bh00, acc[0]);
    acc[0] = MFMA16(ah0, bl00, acc[0]);
    acc[0] = MFMA16(ah1, bh01, acc[0]);
    acc[0] = MFMA16(al1, bh01, acc[0]);
    acc[0] = MFMA16(ah1, bl01, acc[0]);
    acc[1] = MFMA16(ah0, bh10, acc[1]);
    acc[1] = MFMA16(al0, bh10, acc[1]);
    acc[1] = MFMA16(ah0, bl10, acc[1]);
    acc[1] = MFMA16(ah1, bh11, acc[1]);
    acc[1] = MFMA16(al1, bh11, acc[1]);
    acc[1] = MFMA16(ah1, bl11, acc[1]);
    __syncthreads();
    cur ^= 1;
  }
}

// ============ fused softmax+aggregation GEMM (short-K, 512 thr, BK=64) =====
__device__ __forceinline__ void agg_core(
    const float* __restrict__ lsrc, int kvalid,
    const float* __restrict__ ldb, const float* __restrict__ lsb,
    const f16* __restrict__ Bth, const f16* __restrict__ Btl,
    int K, int row0, int col0, int rvalid,
    const float* __restrict__ selfv,
    f16* __restrict__ outh, f16* __restrict__ outl,
    f16* __restrict__ lds, float* __restrict__ fred)
{
  const int t = threadIdx.x, lane = t & 63, w = t >> 6;
  const int wr = w >> 1, wc = w & 1;
  float* zred = fred;          // [256]
  float* res  = fred + 256;    // [64] self exps
  float* riz  = fred + 320;    // [64] 1/denominator
  float sm = -1e30f;
  for (int k = t; k < kvalid; k += GT) sm = fmaxf(sm, lsrc[k]);
#pragma unroll
  for (int off = 1; off < 64; off <<= 1) sm = fmaxf(sm, __shfl_xor(sm, off));
  if (lane == 0) zred[w] = sm;
  __syncthreads();
  sm = fmaxf(fmaxf(fmaxf(zred[0], zred[1]), fmaxf(zred[2], zred[3])),
             fmaxf(fmaxf(zred[4], zred[5]), fmaxf(zred[6], zred[7])));
  __syncthreads();
  const bool isA = t < 256;
  const int tt = t & 255;
  const int srow = tt >> 2, su = tt & 3;
  const int lw = srow * LROW + su * 16;
  bool rok = false; float ldr = 0.f, mr = 0.f;
  if (isA && (row0 + srow) < rvalid) {
    rok = true;
    ldr = ldb[row0 + srow];
    mr  = lk(fmaxf(sm, lsb[row0 + srow]) + ldr);
  }
  const size_t boff = (size_t)(col0 + srow) * K + su * 16;
  const int fra = wr * 16 + (lane & 15);
  const int frb = wc * 32 + (lane & 15);
  const int fu  = (lane >> 4) * 8;
  f32x4 acc[2] = {};
  float zacc = 0.f;
  f32x4 p0, p1, p2, p3;
  auto prefetch = [&](int k) {
    if (isA) {
      p0 = *(const f32x4*)(lsrc + k + su * 16);
      p1 = *(const f32x4*)(lsrc + k + su * 16 + 4);
      p2 = *(const f32x4*)(lsrc + k + su * 16 + 8);
      p3 = *(const f32x4*)(lsrc + k + su * 16 + 12);
    } else {
      p0 = *(const f32x4*)(Bth + boff + k);
      p1 = *(const f32x4*)(Bth + boff + k + 8);
      p2 = *(const f32x4*)(Btl + boff + k);
      p3 = *(const f32x4*)(Btl + boff + k + 8);
    }
  };
  auto stage = [&](f16* buf, int kbase) {
    if (isA) {
      f16x8 h0, l0, h1v, l1v;
#pragma unroll
      for (int j = 0; j < 16; ++j) {
        const int k = kbase + su * 16 + j;
        const float lv = (j < 4) ? p0[j] : (j < 8) ? p1[j - 4]
                       : (j < 12) ? p2[j - 8] : p3[j - 12];
        float f = 0.f;
        if (rok && k < kvalid) f = __expf(lk(lv + ldr) - mr);
        zacc += f;
        if (j < 8) { h0[j] = hif(f); l0[j] = lof(f); }
        else       { h1v[j - 8] = hif(f); l1v[j - 8] = lof(f); }
      }
      *(f16x8*)(buf + lw)              = h0;
      *(f16x8*)(buf + lw + 8)          = h1v;
      *(f16x8*)(buf + SEC_AL + lw)     = l0;
      *(f16x8*)(buf + SEC_AL + lw + 8) = l1v;
    } else {
      *(f32x4*)(buf + SEC_BH + lw)     = p0;
      *(f32x4*)(buf + SEC_BH + lw + 8) = p1;
      *(f32x4*)(buf + SEC_BL + lw)     = p2;
      *(f32x4*)(buf + SEC_BL + lw + 8) = p3;
    }
  };
  prefetch(0);
  stage(lds, 0);
  if (K > 64) prefetch(64);
  __syncthreads();
  int cur = 0;
  for (int kt = 64; kt <= K; kt += 64) {
    f16* rb = lds + cur * BUFSZ;
    f16* wb = lds + (cur ^ 1) * BUFSZ;
    f16x8 ah0  = *(const f16x8*)(rb + fra * LROW + fu);
    f16x8 ah1  = *(const f16x8*)(rb + fra * LROW + 32 + fu);
    f16x8 al0  = *(const f16x8*)(rb + SEC_AL + fra * LROW + fu);
    f16x8 al1  = *(const f16x8*)(rb + SEC_AL + fra * LROW + 32 + fu);
    f16x8 bh00 = *(const f16x8*)(rb + SEC_BH + frb * LROW + fu);
    f16x8 bh01 = *(const f16x8*)(rb + SEC_BH + frb * LROW + 32 + fu);
    f16x8 bl00 = *(const f16x8*)(rb + SEC_BL + frb * LROW + fu);
    f16x8 bl01 = *(const f16x8*)(rb + SEC_BL + frb * LROW + 32 + fu);
    f16x8 bh10 = *(const f16x8*)(rb + SEC_BH + (frb + 16) * LROW + fu);
    f16x8 bh11 = *(const f16x8*)(rb + SEC_BH + (frb + 16) * LROW + 32 + fu);
    f16x8 bl10 = *(const f16x8*)(rb + SEC_BL + (frb + 16) * LROW + fu);
    f16x8 bl11 = *(const f16x8*)(rb + SEC_BL + (frb + 16) * LROW + 32 + fu);
    if (kt < K) {
      stage(wb, kt);
      if (kt + 64 < K) prefetch(kt + 64);
    }
    acc[0] = MFMA16(ah0, bh00, acc[0]);
    acc[0] = MFMA16(al0, bh00, acc[0]);
    acc[0] = MFMA16(ah0, bl00, acc[0]);
    acc[0] = MFMA16(ah1, bh01, acc[0]);
    acc[0] = MFMA16(al1, bh01, acc[0]);
    acc[0] = MFMA16(ah1, bl01, acc[0]);
    acc[1] = MFMA16(ah0, bh10, acc[1]);
    acc[1] = MFMA16(al0, bh10, acc[1]);
    acc[1] = MFMA16(ah0, bl10, acc[1]);
    acc[1] = MFMA16(ah1, bh11, acc[1]);
    acc[1] = MFMA16(al1, bh11, acc[1]);
    acc[1] = MFMA16(ah1, bl11, acc[1]);
    __syncthreads();
    cur ^= 1;
  }
  if (t < 256) zred[t] = zacc;
  __syncthreads();
  if (t < 64) {
    float z = zred[t * 4] + zred[t * 4 + 1] + zred[t * 4 + 2] + zred[t * 4 + 3];
    float es = 0.f, iz = 0.f;
    if (row0 + t < rvalid) {
      const float l2 = ldb[row0 + t], s2 = lsb[row0 + t];
      const float m2 = lk(fmaxf(sm, s2) + l2);
      es = __expf(lk(s2 + l2) - m2);
      iz = 1.f / (z + es);
    }
    res[t] = es; riz[t] = iz;
  }
  __syncthreads();
#pragma unroll
  for (int q = 0; q < 4; ++q) {
    const int rl = wr * 16 + (lane >> 4) * 4 + q;
    const int gr = row0 + rl;
    if (gr >= rvalid) continue;
    const float es = res[rl], iz = riz[rl];
#pragma unroll
    for (int n = 0; n < 2; ++n) {
      const int c = col0 + wc * 32 + n * 16 + (lane & 15);
      const float v = (acc[n][q] + es * selfv[(size_t)gr * DD + c]) * iz;
      outh[(size_t)gr * DD + c] = hif(v);
      outl[(size_t)gr * DD + c] = lof(v);
    }
  }
}

// ======== 64x64 direct transpose+split tile (no LDS, one pass) =============
__device__ __forceinline__ void cvt_tile(
    const float* __restrict__ in, int R, int Cin,
    f16* __restrict__ oh, f16* __restrict__ ol, int ldo,
    int ti, int tj)
{
  const int t = threadIdx.x;
  const int gj0 = tj * 64 + (t & 31) * 2;
  const int i8  = (t >> 5) * 8;
  const bool c0 = gj0 < Cin, c1 = (gj0 + 1) < Cin;
  f16x8 vh0, vl0, vh1, vl1;
#pragma unroll
  for (int e = 0; e < 8; ++e) {
    const int gi = ti * 64 + i8 + e;
    float a = 0.f, b = 0.f;
    if (gi < R) {
      if (c0 && c1) {
        const float2 v = *(const float2*)(in + (size_t)gi * Cin + gj0);
        a = v.x; b = v.y;
      } else if (c0) {
        a = in[(size_t)gi * Cin + gj0];
      }
    }
    vh0[e] = hif(a); vl0[e] = lof(a);
    vh1[e] = hif(b); vl1[e] = lof(b);
  }
  const size_t o0 = (size_t)gj0 * ldo + ti * 64 + i8;
  *(f16x8*)(oh + o0) = vh0;
  *(f16x8*)(ol + o0) = vl0;
  const size_t o1 = o0 + ldo;
  *(f16x8*)(oh + o1) = vh1;
  *(f16x8*)(ol + o1) = vl1;
}

// ===== K1: weight matvecs + zero ls2/ld2 + zero M1pf/zP ====================
__global__ __launch_bounds__(NTHR) void prep1_k(
    const float* __restrict__ W1, const float* __restrict__ W2,
    const float* __restrict__ as1, const float* __restrict__ ad1,
    const float* __restrict__ as2, const float* __restrict__ ad2,
    float* __restrict__ v1s, float* __restrict__ v1d,
    float* __restrict__ v2s, float* __restrict__ v2d,
    float* __restrict__ ls2, float* __restrict__ ld2,
    float* __restrict__ M1pf, float* __restrict__ zP)
{
  const int u = blockIdx.x;
  if (u < 256) {
    const int wid  = u * 4 + (threadIdx.x >> 6);
    const int lane = threadIdx.x & 63;
    const int r = wid & 511;
    const bool l1 = (wid < 512);
    const float* W = l1 ? W1 : W2;
    const float4* a4 = (const float4*)(l1 ? as1 : as2);
    const float4* b4 = (const float4*)(l1 ? ad1 : ad2);
    const float4* w4 = (const float4*)(W + (size_t)r * DD);
    float4 w0 = w4[lane], w1 = w4[lane + 64];
    float4 a0 = a4[lane], a1 = a4[lane + 64];
    float4 b0 = b4[lane], b1 = b4[lane + 64];
    float s1 = w0.x * a0.x + w0.y * a0.y + w0.z * a0.z + w0.w * a0.w
             + w1.x * a1.x + w1.y * a1.y + w1.z * a1.z + w1.w * a1.w;
    float s2 = w0.x * b0.x + w0.y * b0.y + w0.z * b0.z + w0.w * b0.w
             + w1.x * b1.x + w1.y * b1.y + w1.z * b1.z + w1.w * b1.w;
#pragma unroll
    for (int off = 32; off > 0; off >>= 1) {
      s1 += __shfl_down(s1, off);
      s2 += __shfl_down(s2, off);
    }
    if (lane == 0) {
      (l1 ? v1s : v2s)[r] = s1;
      (l1 ? v1d : v2d)[r] = s2;
    }
  } else if (u == 256) {
    for (int i = threadIdx.x; i < 1152; i += NTHR) { ls2[i] = 0.f; ld2[i] = 0.f; }
    if (threadIdx.x < 128) zP[threadIdx.x] = 0.f;
  } else {
    float4* p4 = (float4*)M1pf + (size_t)(u - 257) * 800;
#pragma unroll
    for (int p = 0; p < 4; ++p) {
      const int i = threadIdx.x + p * 256;
      if (i < 800) p4[i] = make_float4(0.f, 0.f, 0.f, 0.f);
    }
  }
}

// ===== K2: transposes/splits + layer-1 logits ==============================
__global__ __launch_bounds__(NTHR) void prep2_k(
    const float* __restrict__ x, const float* __restrict__ prox,
    const float* __restrict__ W1, const float* __restrict__ W2,
    const float* __restrict__ fcw,
    const float* __restrict__ v1s, const float* __restrict__ v1d,
    f16* xth, f16* xtl, f16* pth, f16* ptl,
    f16* W1th, f16* W1tl, f16* W2th, f16* W2tl, f16* fwth, f16* fwtl,
    float* __restrict__ ls1, float* __restrict__ ld1)
{
  const int b = blockIdx.x;
  if (b < 64) {
    cvt_tile(W1, 512, 512, W1th, W1tl, 512, b >> 3, b & 7);
  } else if (b < 128) {
    cvt_tile(W2, 512, 512, W2th, W2tl, 512, (b - 64) >> 3, (b - 64) & 7);
  } else if (b < 256) {
    cvt_tile(x, NS, 512, xth, xtl, NS, (b - 128) >> 3, (b - 128) & 7);
  } else if (b < 272) {
    cvt_tile(prox, PP, 512, pth, ptl, 128, (b - 256) >> 3, (b - 256) & 7);
  } else if (b < 288) {
    cvt_tile(fcw, 512, CC, fwth, fwtl, 512, (b - 272) >> 1, (b - 272) & 1);
  } else {
    const int r    = (b - 288) * 4 + (threadIdx.x >> 6);
    const int lane = threadIdx.x & 63;
    if (r >= NN) return;
    const float* row = (r < PP) ? prox + (size_t)r * DD
                                : x + (size_t)(r - PP) * DD;
    const float4* r4 = (const float4*)row;
    const float4* s4 = (const float4*)v1s;
    const float4* d4 = (const float4*)v1d;
    float4 v0 = r4[lane], v1 = r4[lane + 64];
    float4 a0 = s4[lane], a1 = s4[lane + 64];
    float4 b0 = d4[lane], b1 = d4[lane + 64];
    float s1 = v0.x * a0.x + v0.y * a0.y + v0.z * a0.z + v0.w * a0.w
             + v1.x * a1.x + v1.y * a1.y + v1.z * a1.z + v1.w * a1.w;
    float s2 = v0.x * b0.x + v0.y * b0.y + v0.z * b0.z + v0.w * b0.w
             + v1.x * b1.x + v1.y * b1.y + v1.z * b1.z + v1.w * b1.w;
#pragma unroll
    for (int off = 32; off > 0; off >>= 1) {
      s1 += __shfl_down(s1, off);
      s2 += __shfl_down(s2, off);
    }
    if (lane == 0) { ls1[r] = s1; ld1[r] = s2; }
  }
}

// ===== K3: layer-1 aggregation (512 thr, BK=64) ============================
// blocks [0,128): sample dsts (fused softmax, K=128)
// blocks [128,192): proxy split-K partials (16 tiles x 4 chunks of 256)
__global__ __launch_bounds__(GT) void agg1x_k(
    const float* __restrict__ ls1, const float* __restrict__ ld1,
    const f16* __restrict__ pth, const f16* __restrict__ ptl,
    const f16* __restrict__ xth, const f16* __restrict__ xtl,
    const float* __restrict__ x,
    float* __restrict__ M1pf, float* __restrict__ zP,
    f16* __restrict__ M1h, f16* __restrict__ M1l)
{
  __shared__ __align__(16) f16 lds[36864];
  __shared__ float fred[384];
  const int b = blockIdx.x;
  if (b < 128) {
    const int row0 = (b >> 3) * 64, col0 = (b & 7) * 64;
    agg_core(ls1, PP, ld1 + PP, ls1 + PP, pth, ptl, 128, row0, col0, NS,
             x, M1h + (size_t)PP * DD, M1l + (size_t)PP * DD, lds, fred);
    return;
  }
  // ---- proxy split-K partial ----
  const int t = threadIdx.x, lane = t & 63, w = t >> 6;
  const int wr = w >> 1, wc = w & 1;
  const int b2 = b - 128;
  const int tile = b2 >> 2, chunk = b2 & 3;
  const int row0 = (tile >> 3) * 64, col0 = (tile & 7) * 64;
  const int k0 = chunk * 256;
  const float* lsrc = ls1 + PP;
  float sm = -1e30f;
  for (int k = t; k < NS; k += GT) sm = fmaxf(sm, lsrc[k]);
#pragma unroll
  for (int off = 1; off < 64; off <<= 1) sm = fmaxf(sm, __shfl_xor(sm, off));
  if (lane == 0) fred[w] = sm;
  __syncthreads();
  sm = fmaxf(fmaxf(fmaxf(fred[0], fred[1]), fmaxf(fred[2], fred[3])),
             fmaxf(fmaxf(fred[4], fred[5]), fmaxf(fred[6], fred[7])));
  __syncthreads();
  const bool isA = t < 256;
  const int tt = t & 255;
  const int srow = tt >> 2, su = tt & 3;
  const int lw = srow * LROW + su * 16;
  bool rok = false; float ldr = 0.f, mr = 0.f;
  if (isA && (row0 + srow) < PP) {
    rok = true;
    ldr = ld1[row0 + srow];
    mr  = lk(fmaxf(sm, ls1[row0 + srow]) + ldr);
  }
  const size_t boff = (size_t)(col0 + srow) * NS + k0 + su * 16;
  const int fra = wr * 16 + (lane & 15);
  const int frb = wc * 32 + (lane & 15);
  const int fu  = (lane >> 4) * 8;
  f32x4 acc[2] = {};
  float zacc = 0.f;
  f32x4 p0, p1, p2, p3;
  auto prefetch = [&](int k) {
    if (isA) {
      p0 = *(const f32x4*)(lsrc + k0 + k + su * 16);
      p1 = *(const f32x4*)(lsrc + k0 + k + su * 16 + 4);
      p2 = *(const f32x4*)(lsrc + k0 + k + su * 16 + 8);
      p3 = *(const f32x4*)(lsrc + k0 + k + su * 16 + 12);
    } else {
      p0 = *(const f32x4*)(xth + boff + k);
      p1 = *(const f32x4*)(xth + boff + k + 8);
      p2 = *(const f32x4*)(xtl + boff + k);
      p3 = *(const f32x4*)(xtl + boff + k + 8);
    }
  };
  auto stage = [&](f16* buf) {
    if (isA) {
      f16x8 h0, l0, h1v, l1v;
#pragma unroll
      for (int j = 0; j < 16; ++j) {
        const float lv = (j < 4) ? p0[j] : (j < 8) ? p1[j - 4]
                       : (j < 12) ? p2[j - 8] : p3[j - 12];
        float f = 0.f;
        if (rok) f = __expf(lk(lv + ldr) - mr);
        zacc += f;
        if (j < 8) { h0[j] = hif(f); l0[j] = lof(f); }
        else       { h1v[j - 8] = hif(f); l1v[j - 8] = lof(f); }
      }
      *(f16x8*)(buf + lw)              = h0;
      *(f16x8*)(buf + lw + 8)          = h1v;
      *(f16x8*)(buf + SEC_AL + lw)     = l0;
      *(f16x8*)(buf + SEC_AL + lw + 8) = l1v;
    } else {
      *(f32x4*)(buf + SEC_BH + lw)     = p0;
      *(f32x4*)(buf + SEC_BH + lw + 8) = p1;
      *(f32x4*)(buf + SEC_BL + lw)     = p2;
      *(f32x4*)(buf + SEC_BL + lw + 8) = p3;
    }
  };
  prefetch(0);
  stage(lds);
  prefetch(64);
  __syncthreads();
  int cur = 0;
  for (int kt = 64; kt <= 256; kt += 64) {
    f16* rb = lds + cur * BUFSZ;
    f16* wb = lds + (cur ^ 1) * BUFSZ;
    f16x8 ah0  = *(const f16x8*)(rb + fra * LROW + fu);
    f16x8 ah1  = *(const f16x8*)(rb + fra * LROW + 32 + fu);
    f16x8 al0  = *(const f16x8*)(rb + SEC_AL + fra * LROW + fu);
    f16x8 al1  = *(const f16x8*)(rb + SEC_AL + fra * LROW + 32 + fu);
    f16x8 bh00 = *(const f16x8*)(rb + SEC_BH + frb * LROW + fu);
    f16x8 bh01 = *(const f16x8*)(rb + SEC_BH + frb * LROW + 32 + fu);
    f16x8 bl00 = *(const f16x8*)(rb + SEC_BL + frb * LROW + fu);
    f16x8 bl01 = *(const f16x8*)(rb + SEC_BL + frb * LROW + 32 + fu);
    f16x8 bh10 = *(const f16x8*)(rb + SEC_BH + (frb + 16) * LROW + fu);
    f16x8 bh11 = *(const f16x8*)(rb + SEC_BH + (frb + 16) * LROW + 32 + fu);
    f16x8 bl10 = *(const f16x8*)(rb + SEC_BL + (frb + 16) * LROW + fu);
    f16x8 bl11 = *(const f16x8*)(rb + SEC_BL + (frb + 16) * LROW + 32 + fu);
    if (kt < 256) {
      stage(wb);
      if (kt + 64 < 256) prefetch(kt + 64);
    }
    acc[0] = MFMA16(ah0, bh00, acc[0]);
    acc[0] = MFMA16(al0, bh00, acc[0]);
    acc[0] = MFMA16(ah0, bl00, acc[0]);
    acc[0] = MFMA16(ah1, bh01, acc[0]);
    acc[0] = MFMA16(al1, bh01, acc[0]);
    acc[0] = MFMA16(ah1, bl01, acc[0]);
    acc[1] = MFMA16(ah0, bh10, acc[1]);
    acc[1] = MFMA16(al0, bh10, acc[1]);
    acc[1] = MFMA16(ah0, bl10, acc[1]);
    acc[1] = MFMA16(ah1, bh11, acc[1]);
    acc[1] = MFMA16(al1, bh11, acc[1]);
    acc[1] = MFMA16(ah1, bl11, acc[1]);
    __syncthreads();
    cur ^= 1;
  }
  // z depends only on (row, chunk) — add exactly once per chunk: col0==0 only
  if (col0 == 0) {
    if (t < 256) fred[t] = zacc;
    __syncthreads();
    if (t < 64) {
      const int r = row0 + t;
      if (r < PP) {
        float z = fred[t * 4] + fred[t * 4 + 1] + fred[t * 4 + 2] + fred[t * 4 + 3];
        atomicAdd(&zP[r], z);
      }
    }
  }
#pragma unroll
  for (int q = 0; q < 4; ++q) {
    const int gr = row0 + wr * 16 + (lane >> 4) * 4 + q;
    if (gr >= PP) continue;
#pragma unroll
    for (int n = 0; n < 2; ++n) {
      const int c = col0 + wc * 32 + n * 16 + (lane & 15);
      atomicAdd(&M1pf[(size_t)gr * DD + c], acc[n][q]);
    }
  }
}

// ===== K4: h1 = relu(M1@W1 + b1) (512 thr, BK=64); proxy finalize inline;
//           emit proxy^T splits; atomic layer-2 logits =====================
__global__ __launch_bounds__(GT) void h1_k(
    const f16* __restrict__ M1h, const f16* __restrict__ M1l,
    const float* __restrict__ M1pf, const float* __restrict__ zP,
    const float* __restrict__ ls1, const float* __restrict__ ld1,
    const float* __restrict__ prox,
    const f16* __restrict__ W1th, const f16* __restrict__ W1tl,
    const float* __restrict__ b1,
    const float* __restrict__ v2s, const float* __restrict__ v2d,
    float* __restrict__ h1, f16* __restrict__ h1pth, f16* __restrict__ h1ptl,
    float* __restrict__ ls2, float* __restrict__ ld2)
{
  __shared__ __align__(16) f16 lds[36864];
  __shared__ float fred[384];
  float* esA = fred + 256;   // [64]
  float* izA = fred + 320;   // [64]
  const int t = threadIdx.x, lane = t & 63, w = t >> 6;
  const int wr = w >> 1, wc = w & 1;
  const int b = blockIdx.x;
  const int row0 = (b >> 3) * 64, col0 = (b & 7) * 64;
  const bool hasP = (row0 < 128);
  if (hasP) {
    float sm = -1e30f;
    for (int k = t; k < NS; k += GT) sm = fmaxf(sm, ls1[PP + k]);
#pragma unroll
    for (int off = 1; off < 64; off <<= 1) sm = fmaxf(sm, __shfl_xor(sm, off));
    if (lane == 0) fred[w] = sm;
    __syncthreads();
    sm = fmaxf(fmaxf(fmaxf(fred[0], fred[1]), fmaxf(fred[2], fred[3])),
               fmaxf(fmaxf(fred[4], fred[5]), fmaxf(fred[6], fred[7])));
    if (t < 64) {
      const int r = row0 + t;
      float es = 0.f, iz = 0.f;
      if (r < PP) {
        const float ldr = ld1[r];
        const float m = lk(fmaxf(sm, ls1[r]) + ldr);
        es = __expf(lk(ls1[r] + ldr) - m);
        iz = 1.f / (zP[r] + es);
      }
      esA[t] = es; izA[t] = iz;
    }
    __syncthreads();
  }
  // ---- GEMM with role-split staging (A: mixed-source, B: W1 splits) ----
  const bool isA = t < 256;
  const int tt = t & 255;
  const int srow = tt >> 2, su = tt & 3;
  const int lw = srow * LROW + su * 16;
  const int ar = row0 + srow;
  const bool isP = isA && (ar < PP);
  const size_t aoff = (size_t)ar * DD + su * 16;
  const size_t boff = (size_t)(col0 + srow) * DD + su * 16;
  const int fra = wr * 16 + (lane & 15);
  const int frb = wc * 32 + (lane & 15);
  const int fu  = (lane >> 4) * 8;
  const float esr = isP ? esA[srow] : 0.f;
  const float izr = isP ? izA[srow] : 0.f;
  f32x4 qa0, qa1, qa2, qa3, qb0, qb1, qb2, qb3;
  auto loadS = [&](int k) {
    if (isA) {
      if (isP) {
        qa0 = *(const f32x4*)(M1pf + aoff + k);
        qa1 = *(const f32x4*)(M1pf + aoff + k + 4);
        qa2 = *(const f32x4*)(M1pf + aoff + k + 8);
        qa3 = *(const f32x4*)(M1pf + aoff + k + 12);
        qb0 = *(const f32x4*)(prox + aoff + k);
        qb1 = *(const f32x4*)(prox + aoff + k + 4);
        qb2 = *(const f32x4*)(prox + aoff + k + 8);
        qb3 = *(const f32x4*)(prox + aoff + k + 12);
      } else {
        qa0 = *(const f32x4*)(M1h + aoff + k);
        qa1 = *(const f32x4*)(M1h + aoff + k + 8);
        qa2 = *(const f32x4*)(M1l + aoff + k);
        qa3 = *(const f32x4*)(M1l + aoff + k + 8);
      }
    } else {
      qa0 = *(const f32x4*)(W1th + boff + k);
      qa1 = *(const f32x4*)(W1th + boff + k + 8);
      qa2 = *(const f32x4*)(W1tl + boff + k);
      qa3 = *(const f32x4*)(W1tl + boff + k + 8);
    }
  };
  auto storeS = [&](f16* wb) {
    if (isA) {
      if (isP) {
        f16x8 h0, l0, h1v, l1v;
#pragma unroll
        for (int j = 0; j < 16; ++j) {
          const float pv = (j < 4) ? qa0[j] : (j < 8) ? qa1[j - 4]
                         : (j < 12) ? qa2[j - 8] : qa3[j - 12];
          const float xv = (j < 4) ? qb0[j] : (j < 8) ? qb1[j - 4]
                         : (j < 12) ? qb2[j - 8] : qb3[j - 12];
          const float v = (pv + esr * xv) * izr;
          if (j < 8) { h0[j] = hif(v); l0[j] = lof(v); }
          else       { h1v[j - 8] = hif(v); l1v[j - 8] = lof(v); }
        }
        *(f16x8*)(wb + lw)              = h0;
        *(f16x8*)(wb + lw + 8)          = h1v;
        *(f16x8*)(wb + SEC_AL + lw)     = l0;
        *(f16x8*)(wb + SEC_AL + lw + 8) = l1v;
      } else {
        *(f32x4*)(wb + lw)              = qa0;
        *(f32x4*)(wb + lw + 8)          = qa1;
        *(f32x4*)(wb + SEC_AL + lw)     = qa2;
        *(f32x4*)(wb + SEC_AL + lw + 8) = qa3;
      }
    } else {
      *(f32x4*)(wb + SEC_BH + lw)     = qa0;
      *(f32x4*)(wb + SEC_BH + lw + 8) = qa1;
      *(f32x4*)(wb + SEC_BL + lw)     = qa2;
      *(f32x4*)(wb + SEC_BL + lw + 8) = qa3;
    }
  };
  f32x4 acc[2] = {};
  loadS(0);
  storeS(lds);
  loadS(64);
  __syncthreads();
  int cur = 0;
  for (int kt = 64; kt <= DD; kt += 64) {
    f16* rb = lds + cur * BUFSZ;
    f16* wb = lds + (cur ^ 1) * BUFSZ;
    f16x8 ah0  = *(const f16x8*)(rb + fra * LROW + fu);
    f16x8 ah1  = *(const f16x8*)(rb + fra * LROW + 32 + fu);
    f16x8 al0  = *(const f16x8*)(rb + SEC_AL + fra * LROW + fu);
    f16x8 al1  = *(const f16x8*)(rb + SEC_AL + fra * LROW + 32 + fu);
    f16x8 bh00 = *(const f16x8*)(rb + SEC_BH + frb * LROW + fu);
    f16x8 bh01 = *(const f16x8*)(rb + SEC_BH + frb * LROW + 32 + fu);
    f16x8 bl00 = *(const f16x8*)(rb + SEC_BL + frb * LROW + fu);
    f16x8 bl01 = *(const f16x8*)(rb + SEC_BL + frb * LROW + 32 + fu);
    f16x8 bh10 = *(const f16x8*)(rb + SEC_BH + (frb + 16) * LROW + fu);
    f16x8 bh11 = *(const f16x8*)(rb + SEC_BH + (frb + 16) * LROW + 32 + fu);
    f16x8 bl10 = *(const f16x8*)(rb + SEC_BL + (frb + 16) * LROW + fu);
    f16x8 bl11 = *(const f16x8*)(rb + SEC_BL + (frb + 16) * LROW + 32 + fu);
    if (kt < DD) {
      storeS(wb);
      if (kt + 64 < DD) loadS(kt + 64);
    }
    acc[0] = MFMA16(ah0, bh00, acc[0]);
    acc[0] = MFMA16(al0, bh00, acc[0]);
    acc[0] = MFMA16(ah0, bl00, acc[0]);
    acc[0] = MFMA16(ah1, bh01, acc[0]);
    acc[0] = MFMA16(al1, bh01, acc[0]);
    acc[0] = MFMA16(ah1, bl01, acc[0]);
    acc[1] = MFMA16(ah0, bh10, acc[1]);
    acc[1] = MFMA16(al0, bh10, acc[1]);
    acc[1] = MFMA16(ah0, bl10, acc[1]);
    acc[1] = MFMA16(ah1, bh11, acc[1]);
    acc[1] = MFMA16(al1, bh11, acc[1]);
    acc[1] = MFMA16(ah1, bl11, acc[1]);
    __syncthreads();
    cur ^= 1;
  }
  // ---- epilogue ----
  const int c0 = col0 + wc * 32 + (lane & 15);
  const int c1 = c0 + 16;
  const float vs0 = v2s[c0], vs1 = v2s[c1];
  const float vd0 = v2d[c0], vd1 = v2d[c1];
  const float bb0 = b1[c0],  bb1 = b1[c1];
#pragma unroll
  for (int q = 0; q < 4; ++q) {
    const int r = row0 + wr * 16 + (lane >> 4) * 4 + q;
    if (r >= NN) continue;
    float ps = 0.f, pd = 0.f;
#pragma unroll
    for (int n = 0; n < 2; ++n) {
      const int c = (n == 0) ? c0 : c1;
      const float v = fmaxf(acc[n][q] + (n == 0 ? bb0 : bb1), 0.f);
      h1[(size_t)r * DD + c] = v;
      ps += v * (n == 0 ? vs0 : vs1);
      pd += v * (n == 0 ? vd0 : vd1);
      if (r < 128) {
        const size_t o = (size_t)c * 128 + r;
        f16 hh = (f16)0.f, ll = (f16)0.f;
        if (r < PP) { hh = hif(v); ll = lof(v); }
        h1pth[o] = hh; h1ptl[o] = ll;
      }
    }
#pragma unroll
    for (int off = 1; off < 16; off <<= 1) {
      ps += __shfl_xor(ps, off);
      pd += __shfl_xor(pd, off);
    }
    if ((lane & 15) == 0) {
      atomicAdd(&ls2[r], ps);
      atomicAdd(&ld2[r], pd);
    }
  }
}

// ===== K5: layer-2 aggregation (softmax fused; sample dsts only) ===========
__global__ __launch_bounds__(GT) void agg2x_k(
    const float* __restrict__ ls2, const float* __restrict__ ld2,
    const f16* __restrict__ h1pth, const f16* __restrict__ h1ptl,
    const float* __restrict__ h1,
    f16* __restrict__ M2h, f16* __restrict__ M2l)
{
  __shared__ __align__(16) f16 lds[36864];
  __shared__ float fred[384];
  const int b = blockIdx.x;
  const int row0 = (b >> 3) * 64, col0 = (b & 7) * 64;
  agg_core(ls2, PP, ld2 + PP, ls2 + PP, h1pth, h1ptl, 128, row0, col0, NS,
           h1 + (size_t)PP * DD, M2h, M2l, lds, fred);
}

// ===== K6: h2 = relu(M2@W2 + b2) -> d_out (fp32) + split for fc ============
__global__ __launch_bounds__(GT) void h2_k(
    const f16* __restrict__ M2h, const f16* __restrict__ M2l,
    const f16* __restrict__ W2th, const f16* __restrict__ W2tl,
    const float* __restrict__ b2, float* __restrict__ h2s,
    f16* __restrict__ h2h, f16* __restrict__ h2l)
{
  __shared__ __align__(16) f16 lds[36864];
  f32x4 acc[2] = {};
  const int t = threadIdx.x, lane = t & 63, w = t >> 6;
  const int wr = w >> 1, wc = w & 1;
  const int b = blockIdx.x;
  const int row0 = (b >> 3) * 64, col0 = (b & 7) * 64;
  mgemm_core(M2h, M2l, W2th, W2tl, DD, row0, col0, lds, acc);
#pragma unroll
  for (int q = 0; q < 4; ++q) {
    const int r = row0 + wr * 16 + (lane >> 4) * 4 + q;
#pragma unroll
    for (int n = 0; n < 2; ++n) {
      const int c = col0 + wc * 32 + n * 16 + (lane & 15);
      const float v = fmaxf(acc[n][q] + b2[c], 0.f);
      const size_t o = (size_t)r * DD + c;
      h2s[o] = v;
      h2h[o] = hif(v); h2l[o] = lof(v);
    }
  }
}

// ===== K7: preds = h2 @ fcw + fcb ==========================================
__global__ __launch_bounds__(GT) void fc_k(
    const f16* __restrict__ h2h, const f16* __restrict__ h2l,
    const f16* __restrict__ fwth, const f16* __restrict__ fwtl,
    const float* __restrict__ fcb, float* __restrict__ out)
{
  __shared__ __align__(16) f16 lds[36864];
  f32x4 acc[2] = {};
  const int t = threadIdx.x, lane = t & 63, w = t >> 6;
  const int wr = w >> 1, wc = w & 1;
  const int b = blockIdx.x;
  const int row0 = (b >> 1) * 64, col0 = (b & 1) * 64;
  mgemm_core(h2h, h2l, fwth, fwtl, DD, row0, col0, lds, acc);
#pragma unroll
  for (int q = 0; q < 4; ++q) {
    const int r = row0 + wr * 16 + (lane >> 4) * 4 + q;
#pragma unroll
    for (int n = 0; n < 2; ++n) {
      const int c = col0 + wc * 32 + n * 16 + (lane & 15);
      if (c < CC) out[(size_t)r * CC + c] = acc[n][q] + fcb[c];
    }
  }
}

extern "C" void kernel_launch(void* const* d_in, const int* in_sizes, int n_in,
                              void* d_out, int out_size, void* d_ws, size_t ws_size,
                              hipStream_t stream)
{
  const float* x    = (const float*)d_in[0];
  const float* prox = (const float*)d_in[1];
  const float* W1   = (const float*)d_in[2];
  const float* as1  = (const float*)d_in[3];
  const float* ad1  = (const float*)d_in[4];
  const float* b1   = (const float*)d_in[5];
  const float* W2   = (const float*)d_in[6];
  const float* as2  = (const float*)d_in[7];
  const float* ad2  = (const float*)d_in[8];
  const float* b2   = (const float*)d_in[9];
  const float* fcw  = (const float*)d_in[10];
  const float* fcb  = (const float*)d_in[11];
  float* out = (float*)d_out;

  // fp32 workspace
  float* F = (float*)d_ws;
  float* h1   = F; F += (size_t)NN * DD;
  float* ls1  = F; F += 1152;
  float* ld1  = F; F += 1152;
  float* ls2  = F; F += 1152;
  float* ld2  = F; F += 1152;
  float* v1s  = F; F += DD;
  float* v1d  = F; F += DD;
  float* v2s  = F; F += DD;
  float* v2d  = F; F += DD;
  float* M1pf = F; F += (size_t)128 * DD;  // proxy split-K partials (fp32)
  float* zP   = F; F += 128;               // proxy denominator partials
  // f16 split workspace (all bases 16B aligned; sizes multiples of 8 halves)
  f16* H = (f16*)F;
  f16* M1h  = H; H += (size_t)1152 * DD;   // rows: 100 prox(unused) + 1024 samp
  f16* M1l  = H; H += (size_t)1152 * DD;
  f16* M2h  = H; H += (size_t)NS * DD;
  f16* M2l  = H; H += (size_t)NS * DD;
  f16* xth  = H; H += (size_t)DD * NS;     // x^T  [512][1024]
  f16* xtl  = H; H += (size_t)DD * NS;
  f16* pth  = H; H += (size_t)DD * 128;    // prox^T [512][128] (k-pad zeroed)
  f16* ptl  = H; H += (size_t)DD * 128;
  f16* W1th = H; H += (size_t)DD * DD;     // W1^T [512][512]
  f16* W1tl = H; H += (size_t)DD * DD;
  f16* W2th = H; H += (size_t)DD * DD;
  f16* W2tl = H; H += (size_t)DD * DD;
  f16* fwth = H; H += (size_t)128 * DD;    // fcw^T [128][512] (k-pad zeroed)
  f16* fwtl = H; H += (size_t)128 * DD;
  f16* h2h  = H; H += (size_t)NS * DD;
  f16* h2l  = H; H += (size_t)NS * DD;
  f16* h1pth = H; H += (size_t)DD * 128;   // h1 proxy rows ^T [512][128]
  f16* h1ptl = H; H += (size_t)DD * 128;
  float* h2s = out + (size_t)NS * CC;      // layer-2 sample out in d_out

  // K1: weight matvecs + zero ls2/ld2 + zero M1pf/zP
  prep1_k<<<dim3(273), dim3(NTHR), 0, stream>>>(W1, W2, as1, ad1, as2, ad2,
                                                v1s, v1d, v2s, v2d, ls2, ld2,
                                                M1pf, zP);
  // K2: transposes/splits + layer-1 logits
  prep2_k<<<dim3(569), dim3(NTHR), 0, stream>>>(x, prox, W1, W2, fcw, v1s, v1d,
      xth, xtl, pth, ptl, W1th, W1tl, W2th, W2tl, fwth, fwtl, ls1, ld1);
  // K3: layer-1 aggregation (samples fused-SM + proxy split-K partials)
  agg1x_k<<<dim3(192), dim3(GT), 0, stream>>>(ls1, ld1, pth, ptl, xth, xtl,
                                              x, M1pf, zP, M1h, M1l);
  // K4: h1 (proxy finalize inline) + proxy^T splits + atomic layer-2 logits
  h1_k<<<dim3(144), dim3(GT), 0, stream>>>(M1h, M1l, M1pf, zP, ls1, ld1, prox,
                                           W1th, W1tl, b1, v2s, v2d,
                                           h1, h1pth, h1ptl, ls2, ld2);
  // K5: layer-2 aggregation (softmax fused) -> M2 splits
  agg2x_k<<<dim3(128), dim3(GT), 0, stream>>>(ls2, ld2, h1pth, h1ptl, h1,
                                              M2h, M2l);
  // K6: h2 = relu(M2@W2+b2) -> d_out (+ split)
  h2_k<<<dim3(128), dim3(GT), 0, stream>>>(M2h, M2l, W2th, W2tl, b2,
                                           h2s, h2h, h2l);
  // K7: preds = h2 @ fcw + fcb
  fc_k<<<dim3(32), dim3(GT), 0, stream>>>(h2h, h2l, fwth, fwtl, fcb, out);
}